// Round 5
// baseline (6702.827 us; speedup 1.0000x reference)
//
#include <hip/hip_runtime.h>
#include <hip/hip_bf16.h>
#include <math.h>

#define BB 4
#define NN 4096
#define CC 256
#define KK 16
#define AA 256
#define NPTS (BB*NN)            // 16384
#define BNKTOT (NPTS*KK)        // 262144
#define EPSF 1e-5f
#define MINVF (1.0f/262144.0f)

// stats / consts float offsets
#define ST_BND_SUM 0
#define ST_BND_SQ  8
#define ST_G1_SUM  16
#define ST_G1_SQ   272
#define ST_G2_SUM  528
#define ST_G2_SQ   784
#define CO_BND_S   0
#define CO_BND_B   4
#define CO_G1_S    16
#define CO_G1_B    272
#define CO_G2_S    528
#define CO_G2_B    784

__device__ inline float waveReduceAdd(float v) {
    #pragma unroll
    for (int o = 32; o > 0; o >>= 1) v += __shfl_down(v, o);
    return v;
}

// ---------------- K1: q/k/v projections ----------------
// grid (NPTS/64, 3), block 256. blockIdx.y selects which weight.
// (256,4): VGPR cap 128 so acc[64] stays in registers (bare (256) caps at
// 8 waves/SIMD -> 64 VGPRs -> acc spilled to scratch).
__global__ __launch_bounds__(256, 4) void qkv_kernel(
    const float* __restrict__ feat,
    const float* __restrict__ wq, const float* __restrict__ bq,
    const float* __restrict__ wk, const float* __restrict__ bk,
    const float* __restrict__ wv, const float* __restrict__ bv,
    float* __restrict__ oq, float* __restrict__ ok, float* __restrict__ ov)
{
    const float* W; const float* bias; float* out;
    if (blockIdx.y == 0)      { W = wq; bias = bq; out = oq; }
    else if (blockIdx.y == 1) { W = wk; bias = bk; out = ok; }
    else                      { W = wv; bias = bv; out = ov; }

    const int p0 = blockIdx.x * 64;
    const int t  = threadIdx.x;          // output channel c
    __shared__ __align__(16) float fs[64][65];

    float acc[64];
    #pragma unroll
    for (int p = 0; p < 64; ++p) acc[p] = 0.f;

    for (int it = 0; it < 4; ++it) {
        // stage 64 pts x 64 inputs
        const int tp = t >> 2;
        #pragma unroll
        for (int q = 0; q < 4; ++q) {
            const int ch = (t & 3) + q * 4;             // 0..15 float4 chunks
            float4 v = *(const float4*)&feat[(size_t)(p0 + tp) * CC + it * 64 + ch * 4];
            fs[tp][ch*4+0] = v.x; fs[tp][ch*4+1] = v.y; fs[tp][ch*4+2] = v.z; fs[tp][ch*4+3] = v.w;
        }
        __syncthreads();
        #pragma unroll 4
        for (int i = 0; i < 64; ++i) {
            const float w = W[(size_t)(it * 64 + i) * CC + t];
            #pragma unroll
            for (int p = 0; p < 64; ++p) acc[p] = fmaf(fs[p][i], w, acc[p]);
        }
        __syncthreads();
    }
    const float bv_ = bias[t];
    #pragma unroll
    for (int p = 0; p < 64; ++p) out[(size_t)(p0 + p) * CC + t] = acc[p] + bv_;
}

// ---------------- K2: KNN top-16 (query x candidate-chunk parallel) ----------------
// grid 512 blocks x 256 threads. Each block: 32 queries x 8 stride-8 chunks.
// (256,2): VGPR cap 256 so bd[16]/bi[16] stay in registers.
__global__ __launch_bounds__(256, 2) void knn_kernel(
    const float* __restrict__ xyz, int* __restrict__ idxout)
{
    const int t = threadIdx.x;
    const int q = t >> 3;                      // 0..31 query slot
    const int c = t & 7;                       // 0..7 chunk
    const int b = blockIdx.x >> 7;             // 128 blocks per batch
    const int n = ((blockIdx.x & 127) << 5) + q;
    const float* xb = xyz + (size_t)b * NN * 3;

    const float qx = xb[n*3+0], qy = xb[n*3+1], qz = xb[n*3+2];
    const float sqn = qx*qx + qy*qy + qz*qz;

    __shared__ float4 tile[512];
    __shared__ float pl_d[8][17][33];          // [chunk][slot(pad17)][query(pad33)]
    __shared__ int   pl_i[8][17][33];

    float bd[16]; int bi[16];
    #pragma unroll
    for (int s = 0; s < 16; ++s) { bd[s] = 1e30f; bi[s] = 0; }

    for (int t0 = 0; t0 < NN; t0 += 512) {
        #pragma unroll
        for (int r = 0; r < 2; ++r) {
            const int j = t + r * 256;
            const float x = xb[(t0 + j)*3 + 0];
            const float y = xb[(t0 + j)*3 + 1];
            const float z = xb[(t0 + j)*3 + 2];
            tile[j] = make_float4(x, y, z, x*x + y*y + z*z);
        }
        __syncthreads();
        for (int j0 = 0; j0 < 512; j0 += 8) {
            const int j = j0 + c;
            const float4 p = tile[j];
            const float d = sqn + p.w - 2.0f * (qx*p.x + qy*p.y + qz*p.z);
            if (d < bd[15]) {
                const int m = t0 + j;
                bool placed = false;
                #pragma unroll
                for (int s = 15; s > 0; --s) {
                    if (!placed) {
                        if (bd[s-1] > d) { bd[s] = bd[s-1]; bi[s] = bi[s-1]; }
                        else             { bd[s] = d; bi[s] = m; placed = true; }
                    }
                }
                if (!placed) { bd[0] = d; bi[0] = m; }
            }
        }
        __syncthreads();
    }

    // dump partial sorted lists to LDS
    #pragma unroll
    for (int s = 0; s < 16; ++s) { pl_d[c][s][q] = bd[s]; pl_i[c][s][q] = bi[s]; }
    __syncthreads();

    // exact 8-way merge, one query per thread (threads 0..31)
    if (t < 32) {
        const int qq = t;
        float hd[8]; int hi[8]; int p[8];
        #pragma unroll
        for (int cc = 0; cc < 8; ++cc) {
            hd[cc] = pl_d[cc][0][qq]; hi[cc] = pl_i[cc][0][qq]; p[cc] = 1;
        }
        const int nq = ((blockIdx.x & 127) << 5) + qq;
        int* op = idxout + ((size_t)b * NN + nq) * KK;
        #pragma unroll
        for (int s = 0; s < 16; ++s) {
            float bdv = hd[0]; int biv = hi[0]; int bc = 0;
            #pragma unroll
            for (int cc = 1; cc < 8; ++cc) {
                const bool better = (hd[cc] < bdv) || (hd[cc] == bdv && hi[cc] < biv);
                if (better) { bdv = hd[cc]; biv = hi[cc]; bc = cc; }
            }
            op[s] = biv;
            #pragma unroll
            for (int cc = 0; cc < 8; ++cc) {
                if (bc == cc) {
                    const int pp = p[cc];
                    const bool ok = pp < 16;
                    hd[cc] = ok ? pl_d[cc][pp][qq] : 1e38f;   // [16] read stays in pad
                    hi[cc] = ok ? pl_i[cc][pp][qq] : 0;
                    p[cc] = pp + 1;
                }
            }
        }
    }
}

// ---------------- K3: t = rel@d1_w + d1_b, bn_d stats ----------------
__global__ __launch_bounds__(256) void fc_delta_kernel(
    const float* __restrict__ xyz, const int* __restrict__ idx,
    const float* __restrict__ d1w, const float* __restrict__ d1b,
    float* __restrict__ t3, float* __restrict__ stats)
{
    const int g = blockIdx.x * 256 + threadIdx.x;   // 0..262143
    const int b = g >> 16;
    const int rem = g & 65535;
    const int n = rem >> 4;
    const int mi = idx[g];
    const float* xb = xyz + (size_t)b * NN * 3;
    const float rx = xb[n*3+0] - xb[mi*3+0];
    const float ry = xb[n*3+1] - xb[mi*3+1];
    const float rz = xb[n*3+2] - xb[mi*3+2];
    float tv[3];
    #pragma unroll
    for (int j = 0; j < 3; ++j) {
        tv[j] = fmaf(rx, d1w[0*3+j], fmaf(ry, d1w[1*3+j], fmaf(rz, d1w[2*3+j], d1b[j])));
        t3[(size_t)g*3 + j] = tv[j];
    }
    const int lane = threadIdx.x & 63;
    #pragma unroll
    for (int j = 0; j < 3; ++j) {
        float s  = waveReduceAdd(tv[j]);
        float sq = waveReduceAdd(tv[j]*tv[j]);
        if (lane == 0) {
            atomicAdd(&stats[ST_BND_SUM + j], s);
            atomicAdd(&stats[ST_BND_SQ + j], sq);
        }
    }
}

// ---------------- finalize bn_d ----------------
__global__ void finalize_bnd(const float* __restrict__ stats,
                             const float* __restrict__ g, const float* __restrict__ b,
                             float* __restrict__ consts)
{
    const int t = threadIdx.x;
    if (t < 3) {
        const float m = stats[ST_BND_SUM + t] * MINVF;
        const float v = stats[ST_BND_SQ + t] * MINVF - m * m;
        const float s = g[t] / sqrtf(v + EPSF);
        consts[CO_BND_S + t] = s;
        consts[CO_BND_B + t] = b[t] - m * s;
    }
}

// ---------------- K5: g_bn1 stats ----------------
// grid 1024 (b, 16-point chunk), block 256 (thread = channel c)
__global__ __launch_bounds__(256, 4) void bn1_stats_kernel(
    const float* __restrict__ qproj, const float* __restrict__ kproj,
    const float* __restrict__ t3, const int* __restrict__ idx,
    const float* __restrict__ consts,
    const float* __restrict__ d2w, const float* __restrict__ d2b,
    float* __restrict__ stats)
{
    const int b   = blockIdx.x >> 8;
    const int pt0 = (blockIdx.x & 255) * 16;
    const int t = threadIdx.x;

    __shared__ float a3[768];
    __shared__ int idxs[256];

    const float bs[3]  = {consts[CO_BND_S+0], consts[CO_BND_S+1], consts[CO_BND_S+2]};
    const float bsh[3] = {consts[CO_BND_B+0], consts[CO_BND_B+1], consts[CO_BND_B+2]};
    const float* t3b = t3 + (size_t)(b * NN + pt0) * KK * 3;
    #pragma unroll
    for (int q = 0; q < 3; ++q) {
        const int f = t + q * 256;
        const int j = f % 3;
        a3[f] = fmaxf(fmaf(t3b[f], bs[j], bsh[j]), 0.f);
    }
    idxs[t] = idx[(size_t)(b * NN + pt0) * KK + t];
    __syncthreads();

    const int c = t;
    const float d20 = d2w[c], d21 = d2w[CC + c], d22 = d2w[2*CC + c], d2bc = d2b[c];
    float s = 0.f, sq = 0.f;
    for (int p = 0; p < 16; ++p) {
        const float qv = qproj[(size_t)(b * NN + pt0 + p) * CC + c];
        #pragma unroll
        for (int k = 0; k < 16; ++k) {
            const int mi = idxs[p*16 + k];
            const float kv = kproj[((size_t)b * NN + mi) * CC + c];
            const int f = (p*16 + k) * 3;
            const float pe = fmaf(a3[f], d20, fmaf(a3[f+1], d21, fmaf(a3[f+2], d22, d2bc)));
            const float h = qv - kv + pe;
            s += h; sq = fmaf(h, h, sq);
        }
    }
    atomicAdd(&stats[ST_G1_SUM + c], s);
    atomicAdd(&stats[ST_G1_SQ + c], sq);
}

// ---------------- finalize g_bn (shared by bn1 / bn2) ----------------
__global__ void finalize_g(const float* __restrict__ ssum, const float* __restrict__ ssq,
                           const float* __restrict__ g, const float* __restrict__ b,
                           float* __restrict__ os, float* __restrict__ ob)
{
    const int c = threadIdx.x;
    const float m = ssum[c] * MINVF;
    const float v = ssq[c] * MINVF - m * m;
    const float s = g[c] / sqrtf(v + EPSF);
    os[c] = s;
    ob[c] = b[c] - m * s;
}

// ---------------- K7: stage3 — h2 = relu(bn1(h)) @ g1_w + g1_b; bn2 stats ----------------
// (256,4): VGPR cap 128 so acc[16] + staging stay in registers
// (bare (256) gave VGPR_Count=28 -> scratch-spilled accumulators).
template<bool STORE>
__global__ __launch_bounds__(256, 4) void stage3_kernel(
    const float* __restrict__ qproj, const float* __restrict__ kproj,
    const float* __restrict__ t3, const int* __restrict__ idx,
    const float* __restrict__ consts, float* __restrict__ stats,
    const float* __restrict__ d2w, const float* __restrict__ d2b,
    const float* __restrict__ g1w, const float* __restrict__ g1b,
    __hip_bfloat16* __restrict__ h2)
{
    const size_t pt = blockIdx.x;            // b*N + n
    const int b = (int)(pt >> 12);
    const int t = threadIdx.x;

    __shared__ float a3[48];
    __shared__ int idxs[16];
    __shared__ __align__(16) float hr[16][256];

    if (t < 48) {
        const int j = t % 3;
        a3[t] = fmaxf(fmaf(t3[pt*48 + t], consts[CO_BND_S + j], consts[CO_BND_B + j]), 0.f);
    }
    if (t < 16) idxs[t] = idx[pt*16 + t];
    __syncthreads();

    {   // phase 1: h -> bn1 -> relu into LDS
        const int c = t;
        const float d20 = d2w[c], d21 = d2w[CC + c], d22 = d2w[2*CC + c], d2bc = d2b[c];
        const float g1s = consts[CO_G1_S + c], g1sh = consts[CO_G1_B + c];
        const float qv = qproj[pt * CC + c];
        #pragma unroll
        for (int k = 0; k < 16; ++k) {
            const int mi = idxs[k];
            const float kv = kproj[((size_t)b * NN + mi) * CC + c];
            const float pe = fmaf(a3[k*3], d20, fmaf(a3[k*3+1], d21, fmaf(a3[k*3+2], d22, d2bc)));
            const float h = qv - kv + pe;
            hr[k][c] = fmaxf(fmaf(h, g1s, g1sh), 0.f);
        }
    }
    __syncthreads();

    // phase 2: GEMM1 (16x256 @ 256x256), thread = output channel a
    float acc[16];
    const float gb = g1b[t];
    #pragma unroll
    for (int k = 0; k < 16; ++k) acc[k] = gb;
    #pragma unroll 4
    for (int c4 = 0; c4 < 64; ++c4) {
        const float* wp = g1w + (size_t)(c4*4) * AA + t;
        const float w0 = wp[0], w1 = wp[AA], w2 = wp[2*AA], w3 = wp[3*AA];
        #pragma unroll
        for (int k = 0; k < 16; ++k) {
            const float4 hv = *(const float4*)&hr[k][c4*4];
            acc[k] = fmaf(hv.x, w0, fmaf(hv.y, w1, fmaf(hv.z, w2, fmaf(hv.w, w3, acc[k]))));
        }
    }

    float s = 0.f, sq = 0.f;
    #pragma unroll
    for (int k = 0; k < 16; ++k) { s += acc[k]; sq = fmaf(acc[k], acc[k], sq); }
    atomicAdd(&stats[ST_G2_SUM + t], s);
    atomicAdd(&stats[ST_G2_SQ + t], sq);

    if (STORE) {
        #pragma unroll
        for (int k = 0; k < 16; ++k)
            h2[(pt*16 + k) * AA + t] = __float2bfloat16(acc[k]);
    }
}

// ---------------- K9: stage4 — GEMM2, softmax, combine ----------------
// (256,4): VGPR cap 128 — bare (256) compiled to VGPR_Count=28 with lg[16]
// spilled inside the 64-iter GEMM loop (705us, VALUBusy 104%, HBM 2.9%).
template<bool LOAD>
__global__ __launch_bounds__(256, 4) void stage4_kernel(
    const float* __restrict__ qproj, const float* __restrict__ kproj,
    const float* __restrict__ vproj,
    const float* __restrict__ t3, const int* __restrict__ idx,
    const float* __restrict__ consts,
    const float* __restrict__ d2w, const float* __restrict__ d2b,
    const float* __restrict__ g1w, const float* __restrict__ g1b,
    const float* __restrict__ g2w, const float* __restrict__ g2b,
    const __hip_bfloat16* __restrict__ h2, float* __restrict__ out)
{
    const size_t pt = blockIdx.x;
    const int b = (int)(pt >> 12);
    const int t = threadIdx.x;

    __shared__ float a3[48];
    __shared__ int idxs[16];
    __shared__ __align__(16) float r2[16][256];

    if (t < 48) {
        const int j = t % 3;
        a3[t] = fmaxf(fmaf(t3[pt*48 + t], consts[CO_BND_S + j], consts[CO_BND_B + j]), 0.f);
    }
    if (t < 16) idxs[t] = idx[pt*16 + t];
    __syncthreads();

    const float g2s = consts[CO_G2_S + t], g2sh = consts[CO_G2_B + t];

    if constexpr (LOAD) {
        #pragma unroll
        for (int k = 0; k < 16; ++k) {
            const float v = __bfloat162float(h2[(pt*16 + k) * AA + t]);
            r2[k][t] = fmaxf(fmaf(v, g2s, g2sh), 0.f);
        }
        __syncthreads();
    } else {
        __shared__ __align__(16) float hr[16][256];
        {
            const int c = t;
            const float d20 = d2w[c], d21 = d2w[CC + c], d22 = d2w[2*CC + c], d2bc = d2b[c];
            const float g1s = consts[CO_G1_S + c], g1sh = consts[CO_G1_B + c];
            const float qv = qproj[pt * CC + c];
            #pragma unroll
            for (int k = 0; k < 16; ++k) {
                const int mi = idxs[k];
                const float kv = kproj[((size_t)b * NN + mi) * CC + c];
                const float pe = fmaf(a3[k*3], d20, fmaf(a3[k*3+1], d21, fmaf(a3[k*3+2], d22, d2bc)));
                const float h = qv - kv + pe;
                hr[k][c] = fmaxf(fmaf(h, g1s, g1sh), 0.f);
            }
        }
        __syncthreads();
        float acc[16];
        const float gb = g1b[t];
        #pragma unroll
        for (int k = 0; k < 16; ++k) acc[k] = gb;
        #pragma unroll 4
        for (int c4 = 0; c4 < 64; ++c4) {
            const float* wp = g1w + (size_t)(c4*4) * AA + t;
            const float w0 = wp[0], w1 = wp[AA], w2 = wp[2*AA], w3 = wp[3*AA];
            #pragma unroll
            for (int k = 0; k < 16; ++k) {
                const float4 hv = *(const float4*)&hr[k][c4*4];
                acc[k] = fmaf(hv.x, w0, fmaf(hv.y, w1, fmaf(hv.z, w2, fmaf(hv.w, w3, acc[k]))));
            }
        }
        __syncthreads();   // hr no longer needed
        #pragma unroll
        for (int k = 0; k < 16; ++k) r2[k][t] = fmaxf(fmaf(acc[k], g2s, g2sh), 0.f);
        __syncthreads();
    }

    // GEMM2: logits[k][a], thread = a
    float lg[16];
    const float gb2 = g2b[t];
    #pragma unroll
    for (int k = 0; k < 16; ++k) lg[k] = gb2;
    #pragma unroll 4
    for (int c4 = 0; c4 < 64; ++c4) {
        const float* wp = g2w + (size_t)(c4*4) * AA + t;
        const float w0 = wp[0], w1 = wp[AA], w2 = wp[2*AA], w3 = wp[3*AA];
        #pragma unroll
        for (int k = 0; k < 16; ++k) {
            const float4 hv = *(const float4*)&r2[k][c4*4];
            lg[k] = fmaf(hv.x, w0, fmaf(hv.y, w1, fmaf(hv.z, w2, fmaf(hv.w, w3, lg[k]))));
        }
    }

    // softmax over k (all in registers)
    float mx = lg[0];
    #pragma unroll
    for (int k = 1; k < 16; ++k) mx = fmaxf(mx, lg[k]);
    float sum = 0.f;
    #pragma unroll
    for (int k = 0; k < 16; ++k) { lg[k] = expf(lg[k] - mx); sum += lg[k]; }
    const float inv = 1.0f / sum;

    // combine: out = sum_k (v + pos_enc) * attn
    const float d20 = d2w[t], d21 = d2w[CC + t], d22 = d2w[2*CC + t], d2bc = d2b[t];
    float o = 0.f;
    #pragma unroll
    for (int k = 0; k < 16; ++k) {
        const int mi = idxs[k];
        const float vv = vproj[((size_t)b * NN + mi) * CC + t];
        const float pe = fmaf(a3[k*3], d20, fmaf(a3[k*3+1], d21, fmaf(a3[k*3+2], d22, d2bc)));
        o = fmaf(vv + pe, lg[k] * inv, o);
    }
    out[pt * CC + t] = o;
}

// ---------------- host ----------------
extern "C" void kernel_launch(void* const* d_in, const int* in_sizes, int n_in,
                              void* d_out, int out_size, void* d_ws, size_t ws_size,
                              hipStream_t stream)
{
    const float* xyz   = (const float*)d_in[0];
    const float* feat  = (const float*)d_in[1];
    const float* wq    = (const float*)d_in[2];
    const float* bq    = (const float*)d_in[3];
    const float* wk    = (const float*)d_in[4];
    const float* bk    = (const float*)d_in[5];
    const float* wv    = (const float*)d_in[6];
    const float* bv    = (const float*)d_in[7];
    const float* d1w   = (const float*)d_in[8];
    const float* d1b   = (const float*)d_in[9];
    const float* bndg  = (const float*)d_in[10];
    const float* bndb  = (const float*)d_in[11];
    const float* d2w   = (const float*)d_in[12];
    const float* d2b   = (const float*)d_in[13];
    const float* g1g   = (const float*)d_in[14];
    const float* g1bb  = (const float*)d_in[15];
    const float* g1w   = (const float*)d_in[16];
    const float* g1b   = (const float*)d_in[17];
    const float* g2g   = (const float*)d_in[18];
    const float* g2bb  = (const float*)d_in[19];
    const float* g2w   = (const float*)d_in[20];
    const float* g2b   = (const float*)d_in[21];
    float* out = (float*)d_out;

    // workspace layout
    float* qproj = (float*)d_ws;
    float* kproj = qproj + (size_t)NPTS * CC;
    float* vproj = kproj + (size_t)NPTS * CC;
    float* t3    = vproj + (size_t)NPTS * CC;
    float* stats = t3 + (size_t)BNKTOT * 3;
    float* consts = stats + 2048;
    int*   idxb  = (int*)(consts + 2048);
    __hip_bfloat16* h2 = (__hip_bfloat16*)(idxb + BNKTOT);
    const size_t need_store = (size_t)((char*)h2 - (char*)d_ws) + (size_t)BNKTOT * AA * 2;
    const bool store = ws_size >= need_store;

    hipMemsetAsync(stats, 0, 2048 * sizeof(float), stream);

    dim3 gq(NPTS / 64, 3);
    qkv_kernel<<<gq, 256, 0, stream>>>(feat, wq, bq, wk, bk, wv, bv, qproj, kproj, vproj);

    knn_kernel<<<512, 256, 0, stream>>>(xyz, idxb);

    fc_delta_kernel<<<BNKTOT / 256, 256, 0, stream>>>(xyz, idxb, d1w, d1b, t3, stats);

    finalize_bnd<<<1, 64, 0, stream>>>(stats, bndg, bndb, consts);

    bn1_stats_kernel<<<1024, 256, 0, stream>>>(qproj, kproj, t3, idxb, consts, d2w, d2b, stats);

    finalize_g<<<1, 256, 0, stream>>>(stats + ST_G1_SUM, stats + ST_G1_SQ, g1g, g1bb,
                                      consts + CO_G1_S, consts + CO_G1_B);

    if (store)
        stage3_kernel<true><<<NPTS, 256, 0, stream>>>(qproj, kproj, t3, idxb, consts, stats,
                                                      d2w, d2b, g1w, g1b, h2);
    else
        stage3_kernel<false><<<NPTS, 256, 0, stream>>>(qproj, kproj, t3, idxb, consts, stats,
                                                       d2w, d2b, g1w, g1b, h2);

    finalize_g<<<1, 256, 0, stream>>>(stats + ST_G2_SUM, stats + ST_G2_SQ, g2g, g2bb,
                                      consts + CO_G2_S, consts + CO_G2_B);

    if (store)
        stage4_kernel<true><<<NPTS, 256, 0, stream>>>(qproj, kproj, vproj, t3, idxb, consts,
                                                      d2w, d2b, g1w, g1b, g2w, g2b, h2, out);
    else
        stage4_kernel<false><<<NPTS, 256, 0, stream>>>(qproj, kproj, vproj, t3, idxb, consts,
                                                       d2w, d2b, g1w, g1b, g2w, g2b, h2, out);
}

// Round 6
// 2620.028 us; speedup vs baseline: 2.5583x; 2.5583x over previous
//
#include <hip/hip_runtime.h>
#include <hip/hip_bf16.h>
#include <math.h>

#define BB 4
#define NN 4096
#define CC 256
#define KK 16
#define AA 256
#define NPTS (BB*NN)            // 16384
#define BNKTOT (NPTS*KK)        // 262144
#define EPSF 1e-5f
#define MINVF (1.0f/262144.0f)

// stats / consts float offsets
#define ST_BND_SUM 0
#define ST_BND_SQ  8
#define ST_G1_SUM  16
#define ST_G1_SQ   272
#define ST_G2_SUM  528
#define ST_G2_SQ   784
#define CO_BND_S   0
#define CO_BND_B   4
#define CO_G1_S    16
#define CO_G1_B    272
#define CO_G2_S    528
#define CO_G2_B    784

__device__ inline float waveReduceAdd(float v) {
    #pragma unroll
    for (int o = 32; o > 0; o >>= 1) v += __shfl_down(v, o);
    return v;
}

// ---------------- K1: q/k/v projections ----------------
// grid (NPTS/64, 3), block 256. blockIdx.y selects which weight.
// (256,2): VGPR cap 256. (256,4) made the compiler allocate exactly 64 VGPRs
// -> acc[64] scratch-spilled -> 24 GB HBM traffic, 4580us (round-5 profile).
__global__ __launch_bounds__(256, 2) void qkv_kernel(
    const float* __restrict__ feat,
    const float* __restrict__ wq, const float* __restrict__ bq,
    const float* __restrict__ wk, const float* __restrict__ bk,
    const float* __restrict__ wv, const float* __restrict__ bv,
    float* __restrict__ oq, float* __restrict__ ok, float* __restrict__ ov)
{
    const float* W; const float* bias; float* out;
    if (blockIdx.y == 0)      { W = wq; bias = bq; out = oq; }
    else if (blockIdx.y == 1) { W = wk; bias = bk; out = ok; }
    else                      { W = wv; bias = bv; out = ov; }

    const int p0 = blockIdx.x * 64;
    const int t  = threadIdx.x;          // output channel c
    __shared__ __align__(16) float fs[64][65];

    float acc[64];
    #pragma unroll
    for (int p = 0; p < 64; ++p) acc[p] = 0.f;

    for (int it = 0; it < 4; ++it) {
        // stage 64 pts x 64 inputs
        const int tp = t >> 2;
        #pragma unroll
        for (int q = 0; q < 4; ++q) {
            const int ch = (t & 3) + q * 4;             // 0..15 float4 chunks
            float4 v = *(const float4*)&feat[(size_t)(p0 + tp) * CC + it * 64 + ch * 4];
            fs[tp][ch*4+0] = v.x; fs[tp][ch*4+1] = v.y; fs[tp][ch*4+2] = v.z; fs[tp][ch*4+3] = v.w;
        }
        __syncthreads();
        #pragma unroll 4
        for (int i = 0; i < 64; ++i) {
            const float w = W[(size_t)(it * 64 + i) * CC + t];
            #pragma unroll
            for (int p = 0; p < 64; ++p) acc[p] = fmaf(fs[p][i], w, acc[p]);
        }
        __syncthreads();
    }
    const float bv_ = bias[t];
    #pragma unroll
    for (int p = 0; p < 64; ++p) out[(size_t)(p0 + p) * CC + t] = acc[p] + bv_;
}

// ---------------- K2: KNN top-16 (query x candidate-chunk parallel) ----------------
// grid 512 blocks x 256 threads. Each block: 32 queries x 8 stride-8 chunks.
// (256,2): VGPR cap 256 so bd[16]/bi[16] stay in registers.
__global__ __launch_bounds__(256, 2) void knn_kernel(
    const float* __restrict__ xyz, int* __restrict__ idxout)
{
    const int t = threadIdx.x;
    const int q = t >> 3;                      // 0..31 query slot
    const int c = t & 7;                       // 0..7 chunk
    const int b = blockIdx.x >> 7;             // 128 blocks per batch
    const int n = ((blockIdx.x & 127) << 5) + q;
    const float* xb = xyz + (size_t)b * NN * 3;

    const float qx = xb[n*3+0], qy = xb[n*3+1], qz = xb[n*3+2];
    const float sqn = qx*qx + qy*qy + qz*qz;

    __shared__ float4 tile[512];
    __shared__ float pl_d[8][17][33];          // [chunk][slot(pad17)][query(pad33)]
    __shared__ int   pl_i[8][17][33];

    float bd[16]; int bi[16];
    #pragma unroll
    for (int s = 0; s < 16; ++s) { bd[s] = 1e30f; bi[s] = 0; }

    for (int t0 = 0; t0 < NN; t0 += 512) {
        #pragma unroll
        for (int r = 0; r < 2; ++r) {
            const int j = t + r * 256;
            const float x = xb[(t0 + j)*3 + 0];
            const float y = xb[(t0 + j)*3 + 1];
            const float z = xb[(t0 + j)*3 + 2];
            tile[j] = make_float4(x, y, z, x*x + y*y + z*z);
        }
        __syncthreads();
        for (int j0 = 0; j0 < 512; j0 += 8) {
            const int j = j0 + c;
            const float4 p = tile[j];
            const float d = sqn + p.w - 2.0f * (qx*p.x + qy*p.y + qz*p.z);
            if (d < bd[15]) {
                const int m = t0 + j;
                bool placed = false;
                #pragma unroll
                for (int s = 15; s > 0; --s) {
                    if (!placed) {
                        if (bd[s-1] > d) { bd[s] = bd[s-1]; bi[s] = bi[s-1]; }
                        else             { bd[s] = d; bi[s] = m; placed = true; }
                    }
                }
                if (!placed) { bd[0] = d; bi[0] = m; }
            }
        }
        __syncthreads();
    }

    // dump partial sorted lists to LDS
    #pragma unroll
    for (int s = 0; s < 16; ++s) { pl_d[c][s][q] = bd[s]; pl_i[c][s][q] = bi[s]; }
    __syncthreads();

    // exact 8-way merge, one query per thread (threads 0..31)
    if (t < 32) {
        const int qq = t;
        float hd[8]; int hi[8]; int p[8];
        #pragma unroll
        for (int cc = 0; cc < 8; ++cc) {
            hd[cc] = pl_d[cc][0][qq]; hi[cc] = pl_i[cc][0][qq]; p[cc] = 1;
        }
        const int nq = ((blockIdx.x & 127) << 5) + qq;
        int* op = idxout + ((size_t)b * NN + nq) * KK;
        #pragma unroll
        for (int s = 0; s < 16; ++s) {
            float bdv = hd[0]; int biv = hi[0]; int bc = 0;
            #pragma unroll
            for (int cc = 1; cc < 8; ++cc) {
                const bool better = (hd[cc] < bdv) || (hd[cc] == bdv && hi[cc] < biv);
                if (better) { bdv = hd[cc]; biv = hi[cc]; bc = cc; }
            }
            op[s] = biv;
            #pragma unroll
            for (int cc = 0; cc < 8; ++cc) {
                if (bc == cc) {
                    const int pp = p[cc];
                    const bool ok = pp < 16;
                    hd[cc] = ok ? pl_d[cc][pp][qq] : 1e38f;   // [16] read stays in pad
                    hi[cc] = ok ? pl_i[cc][pp][qq] : 0;
                    p[cc] = pp + 1;
                }
            }
        }
    }
}

// ---------------- K3: t = rel@d1_w + d1_b, bn_d stats ----------------
__global__ __launch_bounds__(256) void fc_delta_kernel(
    const float* __restrict__ xyz, const int* __restrict__ idx,
    const float* __restrict__ d1w, const float* __restrict__ d1b,
    float* __restrict__ t3, float* __restrict__ stats)
{
    const int g = blockIdx.x * 256 + threadIdx.x;   // 0..262143
    const int b = g >> 16;
    const int rem = g & 65535;
    const int n = rem >> 4;
    const int mi = idx[g];
    const float* xb = xyz + (size_t)b * NN * 3;
    const float rx = xb[n*3+0] - xb[mi*3+0];
    const float ry = xb[n*3+1] - xb[mi*3+1];
    const float rz = xb[n*3+2] - xb[mi*3+2];
    float tv[3];
    #pragma unroll
    for (int j = 0; j < 3; ++j) {
        tv[j] = fmaf(rx, d1w[0*3+j], fmaf(ry, d1w[1*3+j], fmaf(rz, d1w[2*3+j], d1b[j])));
        t3[(size_t)g*3 + j] = tv[j];
    }
    const int lane = threadIdx.x & 63;
    #pragma unroll
    for (int j = 0; j < 3; ++j) {
        float s  = waveReduceAdd(tv[j]);
        float sq = waveReduceAdd(tv[j]*tv[j]);
        if (lane == 0) {
            atomicAdd(&stats[ST_BND_SUM + j], s);
            atomicAdd(&stats[ST_BND_SQ + j], sq);
        }
    }
}

// ---------------- finalize bn_d ----------------
__global__ void finalize_bnd(const float* __restrict__ stats,
                             const float* __restrict__ g, const float* __restrict__ b,
                             float* __restrict__ consts)
{
    const int t = threadIdx.x;
    if (t < 3) {
        const float m = stats[ST_BND_SUM + t] * MINVF;
        const float v = stats[ST_BND_SQ + t] * MINVF - m * m;
        const float s = g[t] / sqrtf(v + EPSF);
        consts[CO_BND_S + t] = s;
        consts[CO_BND_B + t] = b[t] - m * s;
    }
}

// ---------------- K5: g_bn1 stats ----------------
// grid 1024 (b, 16-point chunk), block 256 (thread = channel c)
__global__ __launch_bounds__(256, 4) void bn1_stats_kernel(
    const float* __restrict__ qproj, const float* __restrict__ kproj,
    const float* __restrict__ t3, const int* __restrict__ idx,
    const float* __restrict__ consts,
    const float* __restrict__ d2w, const float* __restrict__ d2b,
    float* __restrict__ stats)
{
    const int b   = blockIdx.x >> 8;
    const int pt0 = (blockIdx.x & 255) * 16;
    const int t = threadIdx.x;

    __shared__ float a3[768];
    __shared__ int idxs[256];

    const float bs[3]  = {consts[CO_BND_S+0], consts[CO_BND_S+1], consts[CO_BND_S+2]};
    const float bsh[3] = {consts[CO_BND_B+0], consts[CO_BND_B+1], consts[CO_BND_B+2]};
    const float* t3b = t3 + (size_t)(b * NN + pt0) * KK * 3;
    #pragma unroll
    for (int q = 0; q < 3; ++q) {
        const int f = t + q * 256;
        const int j = f % 3;
        a3[f] = fmaxf(fmaf(t3b[f], bs[j], bsh[j]), 0.f);
    }
    idxs[t] = idx[(size_t)(b * NN + pt0) * KK + t];
    __syncthreads();

    const int c = t;
    const float d20 = d2w[c], d21 = d2w[CC + c], d22 = d2w[2*CC + c], d2bc = d2b[c];
    float s = 0.f, sq = 0.f;
    for (int p = 0; p < 16; ++p) {
        const float qv = qproj[(size_t)(b * NN + pt0 + p) * CC + c];
        #pragma unroll
        for (int k = 0; k < 16; ++k) {
            const int mi = idxs[p*16 + k];
            const float kv = kproj[((size_t)b * NN + mi) * CC + c];
            const int f = (p*16 + k) * 3;
            const float pe = fmaf(a3[f], d20, fmaf(a3[f+1], d21, fmaf(a3[f+2], d22, d2bc)));
            const float h = qv - kv + pe;
            s += h; sq = fmaf(h, h, sq);
        }
    }
    atomicAdd(&stats[ST_G1_SUM + c], s);
    atomicAdd(&stats[ST_G1_SQ + c], sq);
}

// ---------------- finalize g_bn (shared by bn1 / bn2) ----------------
__global__ void finalize_g(const float* __restrict__ ssum, const float* __restrict__ ssq,
                           const float* __restrict__ g, const float* __restrict__ b,
                           float* __restrict__ os, float* __restrict__ ob)
{
    const int c = threadIdx.x;
    const float m = ssum[c] * MINVF;
    const float v = ssq[c] * MINVF - m * m;
    const float s = g[c] / sqrtf(v + EPSF);
    os[c] = s;
    ob[c] = b[c] - m * s;
}

// ---------------- K7: stage3 — h2 = relu(bn1(h)) @ g1_w + g1_b; bn2 stats ----------------
// (256,4): VGPR cap 128 so acc[16] + staging stay in registers
// (bare (256) gave VGPR_Count=28 -> scratch-spilled accumulators).
template<bool STORE>
__global__ __launch_bounds__(256, 4) void stage3_kernel(
    const float* __restrict__ qproj, const float* __restrict__ kproj,
    const float* __restrict__ t3, const int* __restrict__ idx,
    const float* __restrict__ consts, float* __restrict__ stats,
    const float* __restrict__ d2w, const float* __restrict__ d2b,
    const float* __restrict__ g1w, const float* __restrict__ g1b,
    __hip_bfloat16* __restrict__ h2)
{
    const size_t pt = blockIdx.x;            // b*N + n
    const int b = (int)(pt >> 12);
    const int t = threadIdx.x;

    __shared__ float a3[48];
    __shared__ int idxs[16];
    __shared__ __align__(16) float hr[16][256];

    if (t < 48) {
        const int j = t % 3;
        a3[t] = fmaxf(fmaf(t3[pt*48 + t], consts[CO_BND_S + j], consts[CO_BND_B + j]), 0.f);
    }
    if (t < 16) idxs[t] = idx[pt*16 + t];
    __syncthreads();

    {   // phase 1: h -> bn1 -> relu into LDS
        const int c = t;
        const float d20 = d2w[c], d21 = d2w[CC + c], d22 = d2w[2*CC + c], d2bc = d2b[c];
        const float g1s = consts[CO_G1_S + c], g1sh = consts[CO_G1_B + c];
        const float qv = qproj[pt * CC + c];
        #pragma unroll
        for (int k = 0; k < 16; ++k) {
            const int mi = idxs[k];
            const float kv = kproj[((size_t)b * NN + mi) * CC + c];
            const float pe = fmaf(a3[k*3], d20, fmaf(a3[k*3+1], d21, fmaf(a3[k*3+2], d22, d2bc)));
            const float h = qv - kv + pe;
            hr[k][c] = fmaxf(fmaf(h, g1s, g1sh), 0.f);
        }
    }
    __syncthreads();

    // phase 2: GEMM1 (16x256 @ 256x256), thread = output channel a
    float acc[16];
    const float gb = g1b[t];
    #pragma unroll
    for (int k = 0; k < 16; ++k) acc[k] = gb;
    #pragma unroll 4
    for (int c4 = 0; c4 < 64; ++c4) {
        const float* wp = g1w + (size_t)(c4*4) * AA + t;
        const float w0 = wp[0], w1 = wp[AA], w2 = wp[2*AA], w3 = wp[3*AA];
        #pragma unroll
        for (int k = 0; k < 16; ++k) {
            const float4 hv = *(const float4*)&hr[k][c4*4];
            acc[k] = fmaf(hv.x, w0, fmaf(hv.y, w1, fmaf(hv.z, w2, fmaf(hv.w, w3, acc[k]))));
        }
    }

    float s = 0.f, sq = 0.f;
    #pragma unroll
    for (int k = 0; k < 16; ++k) { s += acc[k]; sq = fmaf(acc[k], acc[k], sq); }
    atomicAdd(&stats[ST_G2_SUM + t], s);
    atomicAdd(&stats[ST_G2_SQ + t], sq);

    if (STORE) {
        #pragma unroll
        for (int k = 0; k < 16; ++k)
            h2[(pt*16 + k) * AA + t] = __float2bfloat16(acc[k]);
    }
}

// ---------------- K9: stage4 — GEMM2, softmax, combine ----------------
// (256,4): VGPR cap 128 — bare (256) compiled to VGPR_Count=28 with lg[16]
// spilled inside the 64-iter GEMM loop (705us, VALUBusy 104%, HBM 2.9%).
template<bool LOAD>
__global__ __launch_bounds__(256, 4) void stage4_kernel(
    const float* __restrict__ qproj, const float* __restrict__ kproj,
    const float* __restrict__ vproj,
    const float* __restrict__ t3, const int* __restrict__ idx,
    const float* __restrict__ consts,
    const float* __restrict__ d2w, const float* __restrict__ d2b,
    const float* __restrict__ g1w, const float* __restrict__ g1b,
    const float* __restrict__ g2w, const float* __restrict__ g2b,
    const __hip_bfloat16* __restrict__ h2, float* __restrict__ out)
{
    const size_t pt = blockIdx.x;
    const int b = (int)(pt >> 12);
    const int t = threadIdx.x;

    __shared__ float a3[48];
    __shared__ int idxs[16];
    __shared__ __align__(16) float r2[16][256];

    if (t < 48) {
        const int j = t % 3;
        a3[t] = fmaxf(fmaf(t3[pt*48 + t], consts[CO_BND_S + j], consts[CO_BND_B + j]), 0.f);
    }
    if (t < 16) idxs[t] = idx[pt*16 + t];
    __syncthreads();

    const float g2s = consts[CO_G2_S + t], g2sh = consts[CO_G2_B + t];

    if constexpr (LOAD) {
        #pragma unroll
        for (int k = 0; k < 16; ++k) {
            const float v = __bfloat162float(h2[(pt*16 + k) * AA + t]);
            r2[k][t] = fmaxf(fmaf(v, g2s, g2sh), 0.f);
        }
        __syncthreads();
    } else {
        __shared__ __align__(16) float hr[16][256];
        {
            const int c = t;
            const float d20 = d2w[c], d21 = d2w[CC + c], d22 = d2w[2*CC + c], d2bc = d2b[c];
            const float g1s = consts[CO_G1_S + c], g1sh = consts[CO_G1_B + c];
            const float qv = qproj[pt * CC + c];
            #pragma unroll
            for (int k = 0; k < 16; ++k) {
                const int mi = idxs[k];
                const float kv = kproj[((size_t)b * NN + mi) * CC + c];
                const float pe = fmaf(a3[k*3], d20, fmaf(a3[k*3+1], d21, fmaf(a3[k*3+2], d22, d2bc)));
                const float h = qv - kv + pe;
                hr[k][c] = fmaxf(fmaf(h, g1s, g1sh), 0.f);
            }
        }
        __syncthreads();
        float acc[16];
        const float gb = g1b[t];
        #pragma unroll
        for (int k = 0; k < 16; ++k) acc[k] = gb;
        #pragma unroll 4
        for (int c4 = 0; c4 < 64; ++c4) {
            const float* wp = g1w + (size_t)(c4*4) * AA + t;
            const float w0 = wp[0], w1 = wp[AA], w2 = wp[2*AA], w3 = wp[3*AA];
            #pragma unroll
            for (int k = 0; k < 16; ++k) {
                const float4 hv = *(const float4*)&hr[k][c4*4];
                acc[k] = fmaf(hv.x, w0, fmaf(hv.y, w1, fmaf(hv.z, w2, fmaf(hv.w, w3, acc[k]))));
            }
        }
        __syncthreads();   // hr no longer needed
        #pragma unroll
        for (int k = 0; k < 16; ++k) r2[k][t] = fmaxf(fmaf(acc[k], g2s, g2sh), 0.f);
        __syncthreads();
    }

    // GEMM2: logits[k][a], thread = a
    float lg[16];
    const float gb2 = g2b[t];
    #pragma unroll
    for (int k = 0; k < 16; ++k) lg[k] = gb2;
    #pragma unroll 4
    for (int c4 = 0; c4 < 64; ++c4) {
        const float* wp = g2w + (size_t)(c4*4) * AA + t;
        const float w0 = wp[0], w1 = wp[AA], w2 = wp[2*AA], w3 = wp[3*AA];
        #pragma unroll
        for (int k = 0; k < 16; ++k) {
            const float4 hv = *(const float4*)&r2[k][c4*4];
            lg[k] = fmaf(hv.x, w0, fmaf(hv.y, w1, fmaf(hv.z, w2, fmaf(hv.w, w3, lg[k]))));
        }
    }

    // softmax over k (all in registers)
    float mx = lg[0];
    #pragma unroll
    for (int k = 1; k < 16; ++k) mx = fmaxf(mx, lg[k]);
    float sum = 0.f;
    #pragma unroll
    for (int k = 0; k < 16; ++k) { lg[k] = expf(lg[k] - mx); sum += lg[k]; }
    const float inv = 1.0f / sum;

    // combine: out = sum_k (v + pos_enc) * attn
    const float d20 = d2w[t], d21 = d2w[CC + t], d22 = d2w[2*CC + t], d2bc = d2b[t];
    float o = 0.f;
    #pragma unroll
    for (int k = 0; k < 16; ++k) {
        const int mi = idxs[k];
        const float vv = vproj[((size_t)b * NN + mi) * CC + t];
        const float pe = fmaf(a3[k*3], d20, fmaf(a3[k*3+1], d21, fmaf(a3[k*3+2], d22, d2bc)));
        o = fmaf(vv + pe, lg[k] * inv, o);
    }
    out[pt * CC + t] = o;
}

// ---------------- host ----------------
extern "C" void kernel_launch(void* const* d_in, const int* in_sizes, int n_in,
                              void* d_out, int out_size, void* d_ws, size_t ws_size,
                              hipStream_t stream)
{
    const float* xyz   = (const float*)d_in[0];
    const float* feat  = (const float*)d_in[1];
    const float* wq    = (const float*)d_in[2];
    const float* bq    = (const float*)d_in[3];
    const float* wk    = (const float*)d_in[4];
    const float* bk    = (const float*)d_in[5];
    const float* wv    = (const float*)d_in[6];
    const float* bv    = (const float*)d_in[7];
    const float* d1w   = (const float*)d_in[8];
    const float* d1b   = (const float*)d_in[9];
    const float* bndg  = (const float*)d_in[10];
    const float* bndb  = (const float*)d_in[11];
    const float* d2w   = (const float*)d_in[12];
    const float* d2b   = (const float*)d_in[13];
    const float* g1g   = (const float*)d_in[14];
    const float* g1bb  = (const float*)d_in[15];
    const float* g1w   = (const float*)d_in[16];
    const float* g1b   = (const float*)d_in[17];
    const float* g2g   = (const float*)d_in[18];
    const float* g2bb  = (const float*)d_in[19];
    const float* g2w   = (const float*)d_in[20];
    const float* g2b   = (const float*)d_in[21];
    float* out = (float*)d_out;

    // workspace layout
    float* qproj = (float*)d_ws;
    float* kproj = qproj + (size_t)NPTS * CC;
    float* vproj = kproj + (size_t)NPTS * CC;
    float* t3    = vproj + (size_t)NPTS * CC;
    float* stats = t3 + (size_t)BNKTOT * 3;
    float* consts = stats + 2048;
    int*   idxb  = (int*)(consts + 2048);
    __hip_bfloat16* h2 = (__hip_bfloat16*)(idxb + BNKTOT);
    const size_t need_store = (size_t)((char*)h2 - (char*)d_ws) + (size_t)BNKTOT * AA * 2;
    const bool store = ws_size >= need_store;

    hipMemsetAsync(stats, 0, 2048 * sizeof(float), stream);

    dim3 gq(NPTS / 64, 3);
    qkv_kernel<<<gq, 256, 0, stream>>>(feat, wq, bq, wk, bk, wv, bv, qproj, kproj, vproj);

    knn_kernel<<<512, 256, 0, stream>>>(xyz, idxb);

    fc_delta_kernel<<<BNKTOT / 256, 256, 0, stream>>>(xyz, idxb, d1w, d1b, t3, stats);

    finalize_bnd<<<1, 64, 0, stream>>>(stats, bndg, bndb, consts);

    bn1_stats_kernel<<<1024, 256, 0, stream>>>(qproj, kproj, t3, idxb, consts, d2w, d2b, stats);

    finalize_g<<<1, 256, 0, stream>>>(stats + ST_G1_SUM, stats + ST_G1_SQ, g1g, g1bb,
                                      consts + CO_G1_S, consts + CO_G1_B);

    if (store)
        stage3_kernel<true><<<NPTS, 256, 0, stream>>>(qproj, kproj, t3, idxb, consts, stats,
                                                      d2w, d2b, g1w, g1b, h2);
    else
        stage3_kernel<false><<<NPTS, 256, 0, stream>>>(qproj, kproj, t3, idxb, consts, stats,
                                                       d2w, d2b, g1w, g1b, h2);

    finalize_g<<<1, 256, 0, stream>>>(stats + ST_G2_SUM, stats + ST_G2_SQ, g2g, g2bb,
                                      consts + CO_G2_S, consts + CO_G2_B);

    if (store)
        stage4_kernel<true><<<NPTS, 256, 0, stream>>>(qproj, kproj, vproj, t3, idxb, consts,
                                                      d2w, d2b, g1w, g1b, g2w, g2b, h2, out);
    else
        stage4_kernel<false><<<NPTS, 256, 0, stream>>>(qproj, kproj, vproj, t3, idxb, consts,
                                                       d2w, d2b, g1w, g1b, g2w, g2b, h2, out);
}

// Round 7
// 2578.149 us; speedup vs baseline: 2.5999x; 1.0162x over previous
//
#include <hip/hip_runtime.h>
#include <hip/hip_bf16.h>
#include <math.h>

#define BB 4
#define NN 4096
#define CC 256
#define KK 16
#define AA 256
#define NPTS (BB*NN)            // 16384
#define BNKTOT (NPTS*KK)        // 262144
#define EPSF 1e-5f
#define MINVF (1.0f/262144.0f)

// stats / consts float offsets
#define ST_BND_SUM 0
#define ST_BND_SQ  8
#define ST_G1_SUM  16
#define ST_G1_SQ   272
#define ST_G2_SUM  528
#define ST_G2_SQ   784
#define CO_BND_S   0
#define CO_BND_B   4
#define CO_G1_S    16
#define CO_G1_B    272
#define CO_G2_S    528
#define CO_G2_B    784

__device__ inline float waveReduceAdd(float v) {
    #pragma unroll
    for (int o = 32; o > 0; o >>= 1) v += __shfl_down(v, o);
    return v;
}

// ---------------- K1: q/k/v projections ----------------
// (256,2): VGPR cap 256. (256,4) made the compiler allocate exactly 64 VGPRs
// -> acc[64] scratch-spilled -> 24 GB HBM traffic, 4580us (round-5 profile).
__global__ __launch_bounds__(256, 2) void qkv_kernel(
    const float* __restrict__ feat,
    const float* __restrict__ wq, const float* __restrict__ bq,
    const float* __restrict__ wk, const float* __restrict__ bk,
    const float* __restrict__ wv, const float* __restrict__ bv,
    float* __restrict__ oq, float* __restrict__ ok, float* __restrict__ ov)
{
    const float* W; const float* bias; float* out;
    if (blockIdx.y == 0)      { W = wq; bias = bq; out = oq; }
    else if (blockIdx.y == 1) { W = wk; bias = bk; out = ok; }
    else                      { W = wv; bias = bv; out = ov; }

    const int p0 = blockIdx.x * 64;
    const int t  = threadIdx.x;          // output channel c
    __shared__ __align__(16) float fs[64][65];

    float acc[64];
    #pragma unroll
    for (int p = 0; p < 64; ++p) acc[p] = 0.f;

    for (int it = 0; it < 4; ++it) {
        // stage 64 pts x 64 inputs
        const int tp = t >> 2;
        #pragma unroll
        for (int q = 0; q < 4; ++q) {
            const int ch = (t & 3) + q * 4;             // 0..15 float4 chunks
            float4 v = *(const float4*)&feat[(size_t)(p0 + tp) * CC + it * 64 + ch * 4];
            fs[tp][ch*4+0] = v.x; fs[tp][ch*4+1] = v.y; fs[tp][ch*4+2] = v.z; fs[tp][ch*4+3] = v.w;
        }
        __syncthreads();
        #pragma unroll 4
        for (int i = 0; i < 64; ++i) {
            const float w = W[(size_t)(it * 64 + i) * CC + t];
            #pragma unroll
            for (int p = 0; p < 64; ++p) acc[p] = fmaf(fs[p][i], w, acc[p]);
        }
        __syncthreads();
    }
    const float bv_ = bias[t];
    #pragma unroll
    for (int p = 0; p < 64; ++p) out[(size_t)(p0 + p) * CC + t] = acc[p] + bv_;
}

// ---------------- K2: KNN top-16 (query x candidate-chunk parallel) ----------------
// grid 512 blocks x 256 threads. Each block: 32 queries x 8 stride-8 chunks.
// (256,2): VGPR cap 256 so bd[16]/bi[16] stay in registers.
__global__ __launch_bounds__(256, 2) void knn_kernel(
    const float* __restrict__ xyz, int* __restrict__ idxout)
{
    const int t = threadIdx.x;
    const int q = t >> 3;                      // 0..31 query slot
    const int c = t & 7;                       // 0..7 chunk
    const int b = blockIdx.x >> 7;             // 128 blocks per batch
    const int n = ((blockIdx.x & 127) << 5) + q;
    const float* xb = xyz + (size_t)b * NN * 3;

    const float qx = xb[n*3+0], qy = xb[n*3+1], qz = xb[n*3+2];
    const float sqn = qx*qx + qy*qy + qz*qz;

    __shared__ float4 tile[512];
    __shared__ float pl_d[8][17][33];          // [chunk][slot(pad17)][query(pad33)]
    __shared__ int   pl_i[8][17][33];

    float bd[16]; int bi[16];
    #pragma unroll
    for (int s = 0; s < 16; ++s) { bd[s] = 1e30f; bi[s] = 0; }

    for (int t0 = 0; t0 < NN; t0 += 512) {
        #pragma unroll
        for (int r = 0; r < 2; ++r) {
            const int j = t + r * 256;
            const float x = xb[(t0 + j)*3 + 0];
            const float y = xb[(t0 + j)*3 + 1];
            const float z = xb[(t0 + j)*3 + 2];
            tile[j] = make_float4(x, y, z, x*x + y*y + z*z);
        }
        __syncthreads();
        for (int j0 = 0; j0 < 512; j0 += 8) {
            const int j = j0 + c;
            const float4 p = tile[j];
            const float d = sqn + p.w - 2.0f * (qx*p.x + qy*p.y + qz*p.z);
            if (d < bd[15]) {
                const int m = t0 + j;
                bool placed = false;
                #pragma unroll
                for (int s = 15; s > 0; --s) {
                    if (!placed) {
                        if (bd[s-1] > d) { bd[s] = bd[s-1]; bi[s] = bi[s-1]; }
                        else             { bd[s] = d; bi[s] = m; placed = true; }
                    }
                }
                if (!placed) { bd[0] = d; bi[0] = m; }
            }
        }
        __syncthreads();
    }

    // dump partial sorted lists to LDS
    #pragma unroll
    for (int s = 0; s < 16; ++s) { pl_d[c][s][q] = bd[s]; pl_i[c][s][q] = bi[s]; }
    __syncthreads();

    // exact 8-way merge, one query per thread (threads 0..31)
    if (t < 32) {
        const int qq = t;
        float hd[8]; int hi[8]; int p[8];
        #pragma unroll
        for (int cc = 0; cc < 8; ++cc) {
            hd[cc] = pl_d[cc][0][qq]; hi[cc] = pl_i[cc][0][qq]; p[cc] = 1;
        }
        const int nq = ((blockIdx.x & 127) << 5) + qq;
        int* op = idxout + ((size_t)b * NN + nq) * KK;
        #pragma unroll
        for (int s = 0; s < 16; ++s) {
            float bdv = hd[0]; int biv = hi[0]; int bc = 0;
            #pragma unroll
            for (int cc = 1; cc < 8; ++cc) {
                const bool better = (hd[cc] < bdv) || (hd[cc] == bdv && hi[cc] < biv);
                if (better) { bdv = hd[cc]; biv = hi[cc]; bc = cc; }
            }
            op[s] = biv;
            #pragma unroll
            for (int cc = 0; cc < 8; ++cc) {
                if (bc == cc) {
                    const int pp = p[cc];
                    const bool ok = pp < 16;
                    hd[cc] = ok ? pl_d[cc][pp][qq] : 1e38f;   // [16] read stays in pad
                    hi[cc] = ok ? pl_i[cc][pp][qq] : 0;
                    p[cc] = pp + 1;
                }
            }
        }
    }
}

// ---------------- K3: t = rel@d1_w + d1_b, bn_d stats ----------------
__global__ __launch_bounds__(256) void fc_delta_kernel(
    const float* __restrict__ xyz, const int* __restrict__ idx,
    const float* __restrict__ d1w, const float* __restrict__ d1b,
    float* __restrict__ t3, float* __restrict__ stats)
{
    const int g = blockIdx.x * 256 + threadIdx.x;   // 0..262143
    const int b = g >> 16;
    const int rem = g & 65535;
    const int n = rem >> 4;
    const int mi = idx[g];
    const float* xb = xyz + (size_t)b * NN * 3;
    const float rx = xb[n*3+0] - xb[mi*3+0];
    const float ry = xb[n*3+1] - xb[mi*3+1];
    const float rz = xb[n*3+2] - xb[mi*3+2];
    float tv[3];
    #pragma unroll
    for (int j = 0; j < 3; ++j) {
        tv[j] = fmaf(rx, d1w[0*3+j], fmaf(ry, d1w[1*3+j], fmaf(rz, d1w[2*3+j], d1b[j])));
        t3[(size_t)g*3 + j] = tv[j];
    }
    const int lane = threadIdx.x & 63;
    #pragma unroll
    for (int j = 0; j < 3; ++j) {
        float s  = waveReduceAdd(tv[j]);
        float sq = waveReduceAdd(tv[j]*tv[j]);
        if (lane == 0) {
            atomicAdd(&stats[ST_BND_SUM + j], s);
            atomicAdd(&stats[ST_BND_SQ + j], sq);
        }
    }
}

// ---------------- finalize bn_d ----------------
__global__ void finalize_bnd(const float* __restrict__ stats,
                             const float* __restrict__ g, const float* __restrict__ b,
                             float* __restrict__ consts)
{
    const int t = threadIdx.x;
    if (t < 3) {
        const float m = stats[ST_BND_SUM + t] * MINVF;
        const float v = stats[ST_BND_SQ + t] * MINVF - m * m;
        const float s = g[t] / sqrtf(v + EPSF);
        consts[CO_BND_S + t] = s;
        consts[CO_BND_B + t] = b[t] - m * s;
    }
}

// ---------------- K5: g_bn1 stats ----------------
// grid 1024 (b, 16-point chunk), block 256 (thread = channel c)
// (256,2): free the register allocator (min-waves=4 demonstrably keeps the
// occupancy heuristic at tiny VGPR counts on this compiler).
__global__ __launch_bounds__(256, 2) void bn1_stats_kernel(
    const float* __restrict__ qproj, const float* __restrict__ kproj,
    const float* __restrict__ t3, const int* __restrict__ idx,
    const float* __restrict__ consts,
    const float* __restrict__ d2w, const float* __restrict__ d2b,
    float* __restrict__ stats)
{
    const int b   = blockIdx.x >> 8;
    const int pt0 = (blockIdx.x & 255) * 16;
    const int t = threadIdx.x;

    __shared__ float a3[768];
    __shared__ int idxs[256];

    const float bs[3]  = {consts[CO_BND_S+0], consts[CO_BND_S+1], consts[CO_BND_S+2]};
    const float bsh[3] = {consts[CO_BND_B+0], consts[CO_BND_B+1], consts[CO_BND_B+2]};
    const float* t3b = t3 + (size_t)(b * NN + pt0) * KK * 3;
    #pragma unroll
    for (int q = 0; q < 3; ++q) {
        const int f = t + q * 256;
        const int j = f % 3;
        a3[f] = fmaxf(fmaf(t3b[f], bs[j], bsh[j]), 0.f);
    }
    idxs[t] = idx[(size_t)(b * NN + pt0) * KK + t];
    __syncthreads();

    const int c = t;
    const float d20 = d2w[c], d21 = d2w[CC + c], d22 = d2w[2*CC + c], d2bc = d2b[c];
    float s = 0.f, sq = 0.f;
    for (int p = 0; p < 16; ++p) {
        const float qv = qproj[(size_t)(b * NN + pt0 + p) * CC + c];
        #pragma unroll
        for (int k = 0; k < 16; ++k) {
            const int mi = idxs[p*16 + k];
            const float kv = kproj[((size_t)b * NN + mi) * CC + c];
            const int f = (p*16 + k) * 3;
            const float pe = fmaf(a3[f], d20, fmaf(a3[f+1], d21, fmaf(a3[f+2], d22, d2bc)));
            const float h = qv - kv + pe;
            s += h; sq = fmaf(h, h, sq);
        }
    }
    atomicAdd(&stats[ST_G1_SUM + c], s);
    atomicAdd(&stats[ST_G1_SQ + c], sq);
}

// ---------------- finalize g_bn (shared by bn1 / bn2) ----------------
__global__ void finalize_g(const float* __restrict__ ssum, const float* __restrict__ ssq,
                           const float* __restrict__ g, const float* __restrict__ b,
                           float* __restrict__ os, float* __restrict__ ob)
{
    const int c = threadIdx.x;
    const float m = ssum[c] * MINVF;
    const float v = ssq[c] * MINVF - m * m;
    const float s = g[c] / sqrtf(v + EPSF);
    os[c] = s;
    ob[c] = b[c] - m * s;
}

// ---------------- K7: stage3 — h2 = relu(bn1(h)) @ g1_w + g1_b; bn2 stats ----------------
// (256,2): (256,4) left VGPR at 32 (round-6 profile: no change vs bare).
// min-waves=2 is the setting that actually frees the allocator (qkv, knn).
template<bool STORE>
__global__ __launch_bounds__(256, 2) void stage3_kernel(
    const float* __restrict__ qproj, const float* __restrict__ kproj,
    const float* __restrict__ t3, const int* __restrict__ idx,
    const float* __restrict__ consts, float* __restrict__ stats,
    const float* __restrict__ d2w, const float* __restrict__ d2b,
    const float* __restrict__ g1w, const float* __restrict__ g1b,
    __hip_bfloat16* __restrict__ h2)
{
    const size_t pt = blockIdx.x;            // b*N + n
    const int b = (int)(pt >> 12);
    const int t = threadIdx.x;

    __shared__ float a3[48];
    __shared__ int idxs[16];
    __shared__ __align__(16) float hr[16][256];

    if (t < 48) {
        const int j = t % 3;
        a3[t] = fmaxf(fmaf(t3[pt*48 + t], consts[CO_BND_S + j], consts[CO_BND_B + j]), 0.f);
    }
    if (t < 16) idxs[t] = idx[pt*16 + t];
    __syncthreads();

    {   // phase 1: h -> bn1 -> relu into LDS
        const int c = t;
        const float d20 = d2w[c], d21 = d2w[CC + c], d22 = d2w[2*CC + c], d2bc = d2b[c];
        const float g1s = consts[CO_G1_S + c], g1sh = consts[CO_G1_B + c];
        const float qv = qproj[pt * CC + c];
        #pragma unroll
        for (int k = 0; k < 16; ++k) {
            const int mi = idxs[k];
            const float kv = kproj[((size_t)b * NN + mi) * CC + c];
            const float pe = fmaf(a3[k*3], d20, fmaf(a3[k*3+1], d21, fmaf(a3[k*3+2], d22, d2bc)));
            const float h = qv - kv + pe;
            hr[k][c] = fmaxf(fmaf(h, g1s, g1sh), 0.f);
        }
    }
    __syncthreads();

    // phase 2: GEMM1 (16x256 @ 256x256), thread = output channel a
    float acc[16];
    const float gb = g1b[t];
    #pragma unroll
    for (int k = 0; k < 16; ++k) acc[k] = gb;
    #pragma unroll 4
    for (int c4 = 0; c4 < 64; ++c4) {
        const float* wp = g1w + (size_t)(c4*4) * AA + t;
        const float w0 = wp[0], w1 = wp[AA], w2 = wp[2*AA], w3 = wp[3*AA];
        #pragma unroll
        for (int k = 0; k < 16; ++k) {
            const float4 hv = *(const float4*)&hr[k][c4*4];
            acc[k] = fmaf(hv.x, w0, fmaf(hv.y, w1, fmaf(hv.z, w2, fmaf(hv.w, w3, acc[k]))));
        }
    }

    float s = 0.f, sq = 0.f;
    #pragma unroll
    for (int k = 0; k < 16; ++k) { s += acc[k]; sq = fmaf(acc[k], acc[k], sq); }
    atomicAdd(&stats[ST_G2_SUM + t], s);
    atomicAdd(&stats[ST_G2_SQ + t], sq);

    if (STORE) {
        #pragma unroll
        for (int k = 0; k < 16; ++k)
            h2[(pt*16 + k) * AA + t] = __float2bfloat16(acc[k]);
    }
}

// ---------------- K9: stage4 — GEMM2, softmax, combine ----------------
// (256,2): (256,4) left VGPR at 32 / 725us (round-6). min-waves=2 frees
// the allocator (validated on qkv and knn).
template<bool LOAD>
__global__ __launch_bounds__(256, 2) void stage4_kernel(
    const float* __restrict__ qproj, const float* __restrict__ kproj,
    const float* __restrict__ vproj,
    const float* __restrict__ t3, const int* __restrict__ idx,
    const float* __restrict__ consts,
    const float* __restrict__ d2w, const float* __restrict__ d2b,
    const float* __restrict__ g1w, const float* __restrict__ g1b,
    const float* __restrict__ g2w, const float* __restrict__ g2b,
    const __hip_bfloat16* __restrict__ h2, float* __restrict__ out)
{
    const size_t pt = blockIdx.x;
    const int b = (int)(pt >> 12);
    const int t = threadIdx.x;

    __shared__ float a3[48];
    __shared__ int idxs[16];
    __shared__ __align__(16) float r2[16][256];

    if (t < 48) {
        const int j = t % 3;
        a3[t] = fmaxf(fmaf(t3[pt*48 + t], consts[CO_BND_S + j], consts[CO_BND_B + j]), 0.f);
    }
    if (t < 16) idxs[t] = idx[pt*16 + t];
    __syncthreads();

    const float g2s = consts[CO_G2_S + t], g2sh = consts[CO_G2_B + t];

    if constexpr (LOAD) {
        #pragma unroll
        for (int k = 0; k < 16; ++k) {
            const float v = __bfloat162float(h2[(pt*16 + k) * AA + t]);
            r2[k][t] = fmaxf(fmaf(v, g2s, g2sh), 0.f);
        }
        __syncthreads();
    } else {
        __shared__ __align__(16) float hr[16][256];
        {
            const int c = t;
            const float d20 = d2w[c], d21 = d2w[CC + c], d22 = d2w[2*CC + c], d2bc = d2b[c];
            const float g1s = consts[CO_G1_S + c], g1sh = consts[CO_G1_B + c];
            const float qv = qproj[pt * CC + c];
            #pragma unroll
            for (int k = 0; k < 16; ++k) {
                const int mi = idxs[k];
                const float kv = kproj[((size_t)b * NN + mi) * CC + c];
                const float pe = fmaf(a3[k*3], d20, fmaf(a3[k*3+1], d21, fmaf(a3[k*3+2], d22, d2bc)));
                const float h = qv - kv + pe;
                hr[k][c] = fmaxf(fmaf(h, g1s, g1sh), 0.f);
            }
        }
        __syncthreads();
        float acc[16];
        const float gb = g1b[t];
        #pragma unroll
        for (int k = 0; k < 16; ++k) acc[k] = gb;
        #pragma unroll 4
        for (int c4 = 0; c4 < 64; ++c4) {
            const float* wp = g1w + (size_t)(c4*4) * AA + t;
            const float w0 = wp[0], w1 = wp[AA], w2 = wp[2*AA], w3 = wp[3*AA];
            #pragma unroll
            for (int k = 0; k < 16; ++k) {
                const float4 hv = *(const float4*)&hr[k][c4*4];
                acc[k] = fmaf(hv.x, w0, fmaf(hv.y, w1, fmaf(hv.z, w2, fmaf(hv.w, w3, acc[k]))));
            }
        }
        __syncthreads();   // hr no longer needed
        #pragma unroll
        for (int k = 0; k < 16; ++k) r2[k][t] = fmaxf(fmaf(acc[k], g2s, g2sh), 0.f);
        __syncthreads();
    }

    // GEMM2: logits[k][a], thread = a
    float lg[16];
    const float gb2 = g2b[t];
    #pragma unroll
    for (int k = 0; k < 16; ++k) lg[k] = gb2;
    #pragma unroll 4
    for (int c4 = 0; c4 < 64; ++c4) {
        const float* wp = g2w + (size_t)(c4*4) * AA + t;
        const float w0 = wp[0], w1 = wp[AA], w2 = wp[2*AA], w3 = wp[3*AA];
        #pragma unroll
        for (int k = 0; k < 16; ++k) {
            const float4 hv = *(const float4*)&r2[k][c4*4];
            lg[k] = fmaf(hv.x, w0, fmaf(hv.y, w1, fmaf(hv.z, w2, fmaf(hv.w, w3, lg[k]))));
        }
    }

    // softmax over k (all in registers)
    float mx = lg[0];
    #pragma unroll
    for (int k = 1; k < 16; ++k) mx = fmaxf(mx, lg[k]);
    float sum = 0.f;
    #pragma unroll
    for (int k = 0; k < 16; ++k) { lg[k] = expf(lg[k] - mx); sum += lg[k]; }
    const float inv = 1.0f / sum;

    // combine: out = sum_k (v + pos_enc) * attn
    const float d20 = d2w[t], d21 = d2w[CC + t], d22 = d2w[2*CC + t], d2bc = d2b[t];
    float o = 0.f;
    #pragma unroll
    for (int k = 0; k < 16; ++k) {
        const int mi = idxs[k];
        const float vv = vproj[((size_t)b * NN + mi) * CC + t];
        const float pe = fmaf(a3[k*3], d20, fmaf(a3[k*3+1], d21, fmaf(a3[k*3+2], d22, d2bc)));
        o = fmaf(vv + pe, lg[k] * inv, o);
    }
    out[pt * CC + t] = o;
}

// ---------------- host ----------------
extern "C" void kernel_launch(void* const* d_in, const int* in_sizes, int n_in,
                              void* d_out, int out_size, void* d_ws, size_t ws_size,
                              hipStream_t stream)
{
    const float* xyz   = (const float*)d_in[0];
    const float* feat  = (const float*)d_in[1];
    const float* wq    = (const float*)d_in[2];
    const float* bq    = (const float*)d_in[3];
    const float* wk    = (const float*)d_in[4];
    const float* bk    = (const float*)d_in[5];
    const float* wv    = (const float*)d_in[6];
    const float* bv    = (const float*)d_in[7];
    const float* d1w   = (const float*)d_in[8];
    const float* d1b   = (const float*)d_in[9];
    const float* bndg  = (const float*)d_in[10];
    const float* bndb  = (const float*)d_in[11];
    const float* d2w   = (const float*)d_in[12];
    const float* d2b   = (const float*)d_in[13];
    const float* g1g   = (const float*)d_in[14];
    const float* g1bb  = (const float*)d_in[15];
    const float* g1w   = (const float*)d_in[16];
    const float* g1b   = (const float*)d_in[17];
    const float* g2g   = (const float*)d_in[18];
    const float* g2bb  = (const float*)d_in[19];
    const float* g2w   = (const float*)d_in[20];
    const float* g2b   = (const float*)d_in[21];
    float* out = (float*)d_out;

    // workspace layout
    float* qproj = (float*)d_ws;
    float* kproj = qproj + (size_t)NPTS * CC;
    float* vproj = kproj + (size_t)NPTS * CC;
    float* t3    = vproj + (size_t)NPTS * CC;
    float* stats = t3 + (size_t)BNKTOT * 3;
    float* consts = stats + 2048;
    int*   idxb  = (int*)(consts + 2048);
    __hip_bfloat16* h2 = (__hip_bfloat16*)(idxb + BNKTOT);
    const size_t need_store = (size_t)((char*)h2 - (char*)d_ws) + (size_t)BNKTOT * AA * 2;
    const bool store = ws_size >= need_store;

    hipMemsetAsync(stats, 0, 2048 * sizeof(float), stream);

    dim3 gq(NPTS / 64, 3);
    qkv_kernel<<<gq, 256, 0, stream>>>(feat, wq, bq, wk, bk, wv, bv, qproj, kproj, vproj);

    knn_kernel<<<512, 256, 0, stream>>>(xyz, idxb);

    fc_delta_kernel<<<BNKTOT / 256, 256, 0, stream>>>(xyz, idxb, d1w, d1b, t3, stats);

    finalize_bnd<<<1, 64, 0, stream>>>(stats, bndg, bndb, consts);

    bn1_stats_kernel<<<1024, 256, 0, stream>>>(qproj, kproj, t3, idxb, consts, d2w, d2b, stats);

    finalize_g<<<1, 256, 0, stream>>>(stats + ST_G1_SUM, stats + ST_G1_SQ, g1g, g1bb,
                                      consts + CO_G1_S, consts + CO_G1_B);

    if (store)
        stage3_kernel<true><<<NPTS, 256, 0, stream>>>(qproj, kproj, t3, idxb, consts, stats,
                                                      d2w, d2b, g1w, g1b, h2);
    else
        stage3_kernel<false><<<NPTS, 256, 0, stream>>>(qproj, kproj, t3, idxb, consts, stats,
                                                       d2w, d2b, g1w, g1b, h2);

    finalize_g<<<1, 256, 0, stream>>>(stats + ST_G2_SUM, stats + ST_G2_SQ, g2g, g2bb,
                                      consts + CO_G2_S, consts + CO_G2_B);

    if (store)
        stage4_kernel<true><<<NPTS, 256, 0, stream>>>(qproj, kproj, vproj, t3, idxb, consts,
                                                      d2w, d2b, g1w, g1b, g2w, g2b, h2, out);
    else
        stage4_kernel<false><<<NPTS, 256, 0, stream>>>(qproj, kproj, vproj, t3, idxb, consts,
                                                       d2w, d2b, g1w, g1b, g2w, g2b, h2, out);
}

// Round 8
// 1651.313 us; speedup vs baseline: 4.0591x; 1.5613x over previous
//
#include <hip/hip_runtime.h>
#include <hip/hip_bf16.h>
#include <math.h>

#define BB 4
#define NN 4096
#define CC 256
#define KK 16
#define AA 256
#define NPTS (BB*NN)            // 16384
#define BNKTOT (NPTS*KK)        // 262144
#define EPSF 1e-5f
#define MINVF (1.0f/262144.0f)

#define WPB 4                    // points per MFMA block
#define MROWS (WPB*KK)           // 64 rows
#define IMG_PER_KSTEP (256*40)   // ushorts: 256 n-rows x 40 (32 k + pad to 80B)
#define IMG_TOTAL (8*IMG_PER_KSTEP)

// stats / consts float offsets
#define ST_BND_SUM 0
#define ST_BND_SQ  8
#define ST_G1_SUM  16
#define ST_G1_SQ   272
#define ST_G2_SUM  528
#define ST_G2_SQ   784
#define CO_BND_S   0
#define CO_BND_B   4
#define CO_G1_S    16
#define CO_G1_B    272
#define CO_G2_S    528
#define CO_G2_B    784

typedef unsigned short u16;
typedef __attribute__((ext_vector_type(8))) short bf16x8;
typedef __attribute__((ext_vector_type(4))) float f32x4;

__device__ inline u16 f2bf(float x) {           // round-to-nearest-even bf16
    unsigned u = __float_as_uint(x);
    unsigned r = (u + 0x7FFFu + ((u >> 16) & 1u)) >> 16;
    return (u16)r;
}

__device__ inline float waveReduceAdd(float v) {
    #pragma unroll
    for (int o = 32; o > 0; o >>= 1) v += __shfl_down(v, o);
    return v;
}

// ---------------- K1: q/k/v projections ----------------
__global__ __launch_bounds__(256, 2) void qkv_kernel(
    const float* __restrict__ feat,
    const float* __restrict__ wq, const float* __restrict__ bq,
    const float* __restrict__ wk, const float* __restrict__ bk,
    const float* __restrict__ wv, const float* __restrict__ bv,
    float* __restrict__ oq, float* __restrict__ ok, float* __restrict__ ov)
{
    const float* W; const float* bias; float* out;
    if (blockIdx.y == 0)      { W = wq; bias = bq; out = oq; }
    else if (blockIdx.y == 1) { W = wk; bias = bk; out = ok; }
    else                      { W = wv; bias = bv; out = ov; }

    const int p0 = blockIdx.x * 64;
    const int t  = threadIdx.x;
    __shared__ __align__(16) float fs[64][65];

    float acc[64];
    #pragma unroll
    for (int p = 0; p < 64; ++p) acc[p] = 0.f;

    for (int it = 0; it < 4; ++it) {
        const int tp = t >> 2;
        #pragma unroll
        for (int q = 0; q < 4; ++q) {
            const int ch = (t & 3) + q * 4;
            float4 v = *(const float4*)&feat[(size_t)(p0 + tp) * CC + it * 64 + ch * 4];
            fs[tp][ch*4+0] = v.x; fs[tp][ch*4+1] = v.y; fs[tp][ch*4+2] = v.z; fs[tp][ch*4+3] = v.w;
        }
        __syncthreads();
        #pragma unroll 4
        for (int i = 0; i < 64; ++i) {
            const float w = W[(size_t)(it * 64 + i) * CC + t];
            #pragma unroll
            for (int p = 0; p < 64; ++p) acc[p] = fmaf(fs[p][i], w, acc[p]);
        }
        __syncthreads();
    }
    const float bv_ = bias[t];
    #pragma unroll
    for (int p = 0; p < 64; ++p) out[(size_t)(p0 + p) * CC + t] = acc[p] + bv_;
}

// ---------------- K2: KNN top-16 ----------------
__global__ __launch_bounds__(256, 2) void knn_kernel(
    const float* __restrict__ xyz, int* __restrict__ idxout)
{
    const int t = threadIdx.x;
    const int q = t >> 3;
    const int c = t & 7;
    const int b = blockIdx.x >> 7;
    const int n = ((blockIdx.x & 127) << 5) + q;
    const float* xb = xyz + (size_t)b * NN * 3;

    const float qx = xb[n*3+0], qy = xb[n*3+1], qz = xb[n*3+2];
    const float sqn = qx*qx + qy*qy + qz*qz;

    __shared__ float4 tile[512];
    __shared__ float pl_d[8][17][33];
    __shared__ int   pl_i[8][17][33];

    float bd[16]; int bi[16];
    #pragma unroll
    for (int s = 0; s < 16; ++s) { bd[s] = 1e30f; bi[s] = 0; }

    for (int t0 = 0; t0 < NN; t0 += 512) {
        #pragma unroll
        for (int r = 0; r < 2; ++r) {
            const int j = t + r * 256;
            const float x = xb[(t0 + j)*3 + 0];
            const float y = xb[(t0 + j)*3 + 1];
            const float z = xb[(t0 + j)*3 + 2];
            tile[j] = make_float4(x, y, z, x*x + y*y + z*z);
        }
        __syncthreads();
        for (int j0 = 0; j0 < 512; j0 += 8) {
            const int j = j0 + c;
            const float4 p = tile[j];
            const float d = sqn + p.w - 2.0f * (qx*p.x + qy*p.y + qz*p.z);
            if (d < bd[15]) {
                const int m = t0 + j;
                bool placed = false;
                #pragma unroll
                for (int s = 15; s > 0; --s) {
                    if (!placed) {
                        if (bd[s-1] > d) { bd[s] = bd[s-1]; bi[s] = bi[s-1]; }
                        else             { bd[s] = d; bi[s] = m; placed = true; }
                    }
                }
                if (!placed) { bd[0] = d; bi[0] = m; }
            }
        }
        __syncthreads();
    }

    #pragma unroll
    for (int s = 0; s < 16; ++s) { pl_d[c][s][q] = bd[s]; pl_i[c][s][q] = bi[s]; }
    __syncthreads();

    if (t < 32) {
        const int qq = t;
        float hd[8]; int hi[8]; int p[8];
        #pragma unroll
        for (int cc = 0; cc < 8; ++cc) {
            hd[cc] = pl_d[cc][0][qq]; hi[cc] = pl_i[cc][0][qq]; p[cc] = 1;
        }
        const int nq = ((blockIdx.x & 127) << 5) + qq;
        int* op = idxout + ((size_t)b * NN + nq) * KK;
        #pragma unroll
        for (int s = 0; s < 16; ++s) {
            float bdv = hd[0]; int biv = hi[0]; int bc = 0;
            #pragma unroll
            for (int cc = 1; cc < 8; ++cc) {
                const bool better = (hd[cc] < bdv) || (hd[cc] == bdv && hi[cc] < biv);
                if (better) { bdv = hd[cc]; biv = hi[cc]; bc = cc; }
            }
            op[s] = biv;
            #pragma unroll
            for (int cc = 0; cc < 8; ++cc) {
                if (bc == cc) {
                    const int pp = p[cc];
                    const bool ok = pp < 16;
                    hd[cc] = ok ? pl_d[cc][pp][qq] : 1e38f;
                    hi[cc] = ok ? pl_i[cc][pp][qq] : 0;
                    p[cc] = pp + 1;
                }
            }
        }
    }
}

// ---------------- K3: t = rel@d1_w + d1_b, bn_d stats ----------------
__global__ __launch_bounds__(256) void fc_delta_kernel(
    const float* __restrict__ xyz, const int* __restrict__ idx,
    const float* __restrict__ d1w, const float* __restrict__ d1b,
    float* __restrict__ t3, float* __restrict__ stats)
{
    const int g = blockIdx.x * 256 + threadIdx.x;
    const int b = g >> 16;
    const int rem = g & 65535;
    const int n = rem >> 4;
    const int mi = idx[g];
    const float* xb = xyz + (size_t)b * NN * 3;
    const float rx = xb[n*3+0] - xb[mi*3+0];
    const float ry = xb[n*3+1] - xb[mi*3+1];
    const float rz = xb[n*3+2] - xb[mi*3+2];
    float tv[3];
    #pragma unroll
    for (int j = 0; j < 3; ++j) {
        tv[j] = fmaf(rx, d1w[0*3+j], fmaf(ry, d1w[1*3+j], fmaf(rz, d1w[2*3+j], d1b[j])));
        t3[(size_t)g*3 + j] = tv[j];
    }
    const int lane = threadIdx.x & 63;
    #pragma unroll
    for (int j = 0; j < 3; ++j) {
        float s  = waveReduceAdd(tv[j]);
        float sq = waveReduceAdd(tv[j]*tv[j]);
        if (lane == 0) {
            atomicAdd(&stats[ST_BND_SUM + j], s);
            atomicAdd(&stats[ST_BND_SQ + j], sq);
        }
    }
}

// ---------------- finalize bn_d ----------------
__global__ void finalize_bnd(const float* __restrict__ stats,
                             const float* __restrict__ g, const float* __restrict__ b,
                             float* __restrict__ consts)
{
    const int t = threadIdx.x;
    if (t < 3) {
        const float m = stats[ST_BND_SUM + t] * MINVF;
        const float v = stats[ST_BND_SQ + t] * MINVF - m * m;
        const float s = g[t] / sqrtf(v + EPSF);
        consts[CO_BND_S + t] = s;
        consts[CO_BND_B + t] = b[t] - m * s;
    }
}

// ---------------- K5: g_bn1 stats ----------------
__global__ __launch_bounds__(256, 2) void bn1_stats_kernel(
    const float* __restrict__ qproj, const float* __restrict__ kproj,
    const float* __restrict__ t3, const int* __restrict__ idx,
    const float* __restrict__ consts,
    const float* __restrict__ d2w, const float* __restrict__ d2b,
    float* __restrict__ stats)
{
    const int b   = blockIdx.x >> 8;
    const int pt0 = (blockIdx.x & 255) * 16;
    const int t = threadIdx.x;

    __shared__ float a3[768];
    __shared__ int idxs[256];

    const float bs[3]  = {consts[CO_BND_S+0], consts[CO_BND_S+1], consts[CO_BND_S+2]};
    const float bsh[3] = {consts[CO_BND_B+0], consts[CO_BND_B+1], consts[CO_BND_B+2]};
    const float* t3b = t3 + (size_t)(b * NN + pt0) * KK * 3;
    #pragma unroll
    for (int q = 0; q < 3; ++q) {
        const int f = t + q * 256;
        const int j = f % 3;
        a3[f] = fmaxf(fmaf(t3b[f], bs[j], bsh[j]), 0.f);
    }
    idxs[t] = idx[(size_t)(b * NN + pt0) * KK + t];
    __syncthreads();

    const int c = t;
    const float d20 = d2w[c], d21 = d2w[CC + c], d22 = d2w[2*CC + c], d2bc = d2b[c];
    float s = 0.f, sq = 0.f;
    for (int p = 0; p < 16; ++p) {
        const float qv = qproj[(size_t)(b * NN + pt0 + p) * CC + c];
        #pragma unroll
        for (int k = 0; k < 16; ++k) {
            const int mi = idxs[p*16 + k];
            const float kv = kproj[((size_t)b * NN + mi) * CC + c];
            const int f = (p*16 + k) * 3;
            const float pe = fmaf(a3[f], d20, fmaf(a3[f+1], d21, fmaf(a3[f+2], d22, d2bc)));
            const float h = qv - kv + pe;
            s += h; sq = fmaf(h, h, sq);
        }
    }
    atomicAdd(&stats[ST_G1_SUM + c], s);
    atomicAdd(&stats[ST_G1_SQ + c], sq);
}

// ---------------- finalize g_bn ----------------
__global__ void finalize_g(const float* __restrict__ ssum, const float* __restrict__ ssq,
                           const float* __restrict__ g, const float* __restrict__ b,
                           float* __restrict__ os, float* __restrict__ ob)
{
    const int c = threadIdx.x;
    const float m = ssum[c] * MINVF;
    const float v = ssq[c] * MINVF - m * m;
    const float s = g[c] / sqrtf(v + EPSF);
    os[c] = s;
    ob[c] = b[c] - m * s;
}

// ---------------- prep: transpose weights to bf16 LDS-image layout ----------------
// img[kstep][n*40 + kr] = bf16(W[kstep*32 + kr][n]); 80B-padded rows -> b-frag
// ds_read_b128 lands on distinct bank groups (pad analysis: 20n mod 32 cycle).
__global__ __launch_bounds__(256) void prep_weights(
    const float* __restrict__ g1w, const float* __restrict__ g2w,
    u16* __restrict__ g1img, u16* __restrict__ g2img)
{
    const int s = blockIdx.x;
    const float* W = blockIdx.y ? g2w : g1w;
    u16* img = (blockIdx.y ? g2img : g1img) + (size_t)s * IMG_PER_KSTEP;
    const int n = threadIdx.x;
    #pragma unroll
    for (int i = 0; i < 32; ++i) {
        img[n*40 + i] = f2bf(W[(size_t)(s*32 + i) * AA + n]);
    }
}

// ---------------- K7': stage3 MFMA — attn1 = relu(bn1(h)) @ g1w + g1b ----------------
// 4 points/block, M=64 (4 mtiles), N=256 (4 ntiles/wave x 4 waves), K=256 (8 ksteps).
// A staged bf16 in LDS with XOR swizzle (idx ^= (r&7)<<3); B bulk-copied from the
// pre-transposed image. D layout (verified m89): col=lane&15, row=(lane>>4)*4+reg.
__global__ __launch_bounds__(256, 2) void stage3_mfma(
    const float* __restrict__ qproj, const float* __restrict__ kproj,
    const float* __restrict__ t3, const int* __restrict__ idx,
    const float* __restrict__ consts, float* __restrict__ stats,
    const float* __restrict__ d2w, const float* __restrict__ d2b,
    const u16* __restrict__ g1img, const float* __restrict__ g1b,
    __hip_bfloat16* __restrict__ h2)
{
    const int t = threadIdx.x;
    const int l = t & 63, w = t >> 6;
    const int pt0 = blockIdx.x * WPB;
    const int bI = pt0 >> 12;

    __shared__ __align__(16) u16 A_lds[MROWS * 256];     // 32KB
    __shared__ __align__(16) u16 B_lds[IMG_PER_KSTEP];   // 20KB
    __shared__ int   idxs[MROWS];
    __shared__ float a3s[MROWS * 3];

    if (t < MROWS) idxs[t] = idx[(size_t)pt0 * KK + t];
    if (t < MROWS * 3) {
        const int j = t % 3;
        a3s[t] = fmaxf(fmaf(t3[(size_t)pt0 * 48 + t], consts[CO_BND_S + j], consts[CO_BND_B + j]), 0.f);
    }
    __syncthreads();

    {   // stage A = relu(bn1(q - k + pe)) -> bf16 swizzled LDS; thread t owns channel c=t
        const float d20 = d2w[t], d21 = d2w[CC + t], d22 = d2w[2*CC + t], d2bc = d2b[t];
        const float g1s = consts[CO_G1_S + t], g1sh = consts[CO_G1_B + t];
        float qv[WPB];
        #pragma unroll
        for (int p = 0; p < WPB; ++p) qv[p] = qproj[(size_t)(pt0 + p) * CC + t];
        for (int r = 0; r < MROWS; ++r) {
            const int mi = idxs[r];
            const float kv = kproj[((size_t)bI * NN + mi) * CC + t];
            const float pe = fmaf(a3s[r*3], d20, fmaf(a3s[r*3+1], d21, fmaf(a3s[r*3+2], d22, d2bc)));
            const float h = qv[r >> 4] - kv + pe;
            const float av = fmaxf(fmaf(h, g1s, g1sh), 0.f);
            A_lds[(r * 256 + t) ^ ((r & 7) << 3)] = f2bf(av);
        }
    }
    __syncthreads();

    f32x4 acc[4][4];
    #pragma unroll
    for (int q = 0; q < 4; ++q) {
        const float gb = g1b[(w*4 + q) * 16 + (l & 15)];
        #pragma unroll
        for (int m = 0; m < 4; ++m) acc[m][q] = (f32x4){gb, gb, gb, gb};
    }

    for (int s = 0; s < 8; ++s) {
        #pragma unroll
        for (int i = 0; i < 5; ++i) {
            const int e = t + i * 256;
            *(uint4*)&B_lds[e * 8] = *(const uint4*)&g1img[(size_t)s * IMG_PER_KSTEP + e * 8];
        }
        __syncthreads();
        bf16x8 bf[4];
        #pragma unroll
        for (int q = 0; q < 4; ++q)
            bf[q] = *(const bf16x8*)&B_lds[((w*4 + q) * 16 + (l & 15)) * 40 + (l >> 4) * 8];
        #pragma unroll
        for (int m = 0; m < 4; ++m) {
            const int r = m * 16 + (l & 15);
            const bf16x8 af = *(const bf16x8*)&A_lds[((r * 256 + s * 32 + (l >> 4) * 8)) ^ ((r & 7) << 3)];
            #pragma unroll
            for (int q = 0; q < 4; ++q)
                acc[m][q] = __builtin_amdgcn_mfma_f32_16x16x32_bf16(af, bf[q], acc[m][q], 0, 0, 0);
        }
        __syncthreads();
    }

    // bn2 stats + h2 store
    #pragma unroll
    for (int q = 0; q < 4; ++q) {
        const int a = (w*4 + q) * 16 + (l & 15);
        float sc = 0.f, sq = 0.f;
        #pragma unroll
        for (int m = 0; m < 4; ++m) {
            #pragma unroll
            for (int j = 0; j < 4; ++j) {
                const float v = acc[m][q][j];
                sc += v; sq = fmaf(v, v, sq);
                h2[((size_t)(pt0 + m) * KK + ((l >> 4) * 4 + j)) * AA + a] = __float2bfloat16(v);
            }
        }
        sc += __shfl_xor(sc, 16); sc += __shfl_xor(sc, 32);
        sq += __shfl_xor(sq, 16); sq += __shfl_xor(sq, 32);
        if (l < 16) {
            atomicAdd(&stats[ST_G2_SUM + a], sc);
            atomicAdd(&stats[ST_G2_SQ + a], sq);
        }
    }
}

// ---------------- K9': stage4 MFMA — logits = relu(bn2(h2)) @ g2w + g2b; softmax; combine ----------------
__global__ __launch_bounds__(256, 2) void stage4_mfma(
    const float* __restrict__ vproj,
    const float* __restrict__ t3, const int* __restrict__ idx,
    const float* __restrict__ consts,
    const float* __restrict__ d2w, const float* __restrict__ d2b,
    const u16* __restrict__ g2img, const float* __restrict__ g2b,
    const __hip_bfloat16* __restrict__ h2, float* __restrict__ out)
{
    const int t = threadIdx.x;
    const int l = t & 63, w = t >> 6;
    const int pt0 = blockIdx.x * WPB;
    const int bI = pt0 >> 12;

    __shared__ __align__(16) u16 A_lds[MROWS * 256];
    __shared__ __align__(16) u16 B_lds[IMG_PER_KSTEP];
    __shared__ int   idxs[MROWS];
    __shared__ float a3s[MROWS * 3];

    if (t < MROWS) idxs[t] = idx[(size_t)pt0 * KK + t];
    if (t < MROWS * 3) {
        const int j = t % 3;
        a3s[t] = fmaxf(fmaf(t3[(size_t)pt0 * 48 + t], consts[CO_BND_S + j], consts[CO_BND_B + j]), 0.f);
    }
    __syncthreads();

    {   // stage A2 = relu(bn2(h2)) -> bf16 swizzled LDS
        const float g2s = consts[CO_G2_S + t], g2sh = consts[CO_G2_B + t];
        for (int r = 0; r < MROWS; ++r) {
            const float hv = __bfloat162float(h2[((size_t)pt0 * KK + r) * AA + t]);
            const float av = fmaxf(fmaf(hv, g2s, g2sh), 0.f);
            A_lds[(r * 256 + t) ^ ((r & 7) << 3)] = f2bf(av);
        }
    }
    __syncthreads();

    f32x4 acc[4][4];
    #pragma unroll
    for (int q = 0; q < 4; ++q) {
        const float gb = g2b[(w*4 + q) * 16 + (l & 15)];
        #pragma unroll
        for (int m = 0; m < 4; ++m) acc[m][q] = (f32x4){gb, gb, gb, gb};
    }

    for (int s = 0; s < 8; ++s) {
        #pragma unroll
        for (int i = 0; i < 5; ++i) {
            const int e = t + i * 256;
            *(uint4*)&B_lds[e * 8] = *(const uint4*)&g2img[(size_t)s * IMG_PER_KSTEP + e * 8];
        }
        __syncthreads();
        bf16x8 bf[4];
        #pragma unroll
        for (int q = 0; q < 4; ++q)
            bf[q] = *(const bf16x8*)&B_lds[((w*4 + q) * 16 + (l & 15)) * 40 + (l >> 4) * 8];
        #pragma unroll
        for (int m = 0; m < 4; ++m) {
            const int r = m * 16 + (l & 15);
            const bf16x8 af = *(const bf16x8*)&A_lds[((r * 256 + s * 32 + (l >> 4) * 8)) ^ ((r & 7) << 3)];
            #pragma unroll
            for (int q = 0; q < 4; ++q)
                acc[m][q] = __builtin_amdgcn_mfma_f32_16x16x32_bf16(af, bf[q], acc[m][q], 0, 0, 0);
        }
        __syncthreads();
    }

    // softmax over kk (16 rows of each mtile = one point) per column a, then combine
    #pragma unroll
    for (int q = 0; q < 4; ++q) {
        const int a = (w*4 + q) * 16 + (l & 15);
        const float dw0 = d2w[a], dw1 = d2w[CC + a], dw2 = d2w[2*CC + a], db = d2b[a];
        #pragma unroll
        for (int m = 0; m < 4; ++m) {
            f32x4 lg = acc[m][q];
            float mx = fmaxf(fmaxf(lg[0], lg[1]), fmaxf(lg[2], lg[3]));
            mx = fmaxf(mx, __shfl_xor(mx, 16));
            mx = fmaxf(mx, __shfl_xor(mx, 32));
            float e[4]; float ss = 0.f;
            #pragma unroll
            for (int j = 0; j < 4; ++j) { e[j] = expf(lg[j] - mx); ss += e[j]; }
            ss += __shfl_xor(ss, 16); ss += __shfl_xor(ss, 32);
            const float inv = 1.0f / ss;
            float part = 0.f;
            #pragma unroll
            for (int j = 0; j < 4; ++j) {
                const int kk = (l >> 4) * 4 + j;
                const int mi = idxs[m * 16 + kk];
                const float vv = vproj[((size_t)bI * NN + mi) * CC + a];
                const float pe = fmaf(a3s[(m*16+kk)*3], dw0,
                                 fmaf(a3s[(m*16+kk)*3+1], dw1,
                                 fmaf(a3s[(m*16+kk)*3+2], dw2, db)));
                part = fmaf(e[j] * inv, vv + pe, part);
            }
            part += __shfl_xor(part, 16); part += __shfl_xor(part, 32);
            if (l < 16) out[(size_t)(pt0 + m) * CC + a] = part;
        }
    }
}

// ---------------- fallback fp32 kernels (ws too small for h2+images) ----------------
__global__ __launch_bounds__(256, 2) void stage3_fp32(
    const float* __restrict__ qproj, const float* __restrict__ kproj,
    const float* __restrict__ t3, const int* __restrict__ idx,
    const float* __restrict__ consts, float* __restrict__ stats,
    const float* __restrict__ d2w, const float* __restrict__ d2b,
    const float* __restrict__ g1w, const float* __restrict__ g1b)
{
    const size_t pt = blockIdx.x;
    const int b = (int)(pt >> 12);
    const int t = threadIdx.x;
    __shared__ float a3[48];
    __shared__ int idxs[16];
    __shared__ __align__(16) float hr[16][256];
    if (t < 48) {
        const int j = t % 3;
        a3[t] = fmaxf(fmaf(t3[pt*48 + t], consts[CO_BND_S + j], consts[CO_BND_B + j]), 0.f);
    }
    if (t < 16) idxs[t] = idx[pt*16 + t];
    __syncthreads();
    {
        const float d20 = d2w[t], d21 = d2w[CC + t], d22 = d2w[2*CC + t], d2bc = d2b[t];
        const float g1s = consts[CO_G1_S + t], g1sh = consts[CO_G1_B + t];
        const float qv = qproj[pt * CC + t];
        #pragma unroll
        for (int k = 0; k < 16; ++k) {
            const int mi = idxs[k];
            const float kv = kproj[((size_t)b * NN + mi) * CC + t];
            const float pe = fmaf(a3[k*3], d20, fmaf(a3[k*3+1], d21, fmaf(a3[k*3+2], d22, d2bc)));
            hr[k][t] = fmaxf(fmaf(qv - kv + pe, g1s, g1sh), 0.f);
        }
    }
    __syncthreads();
    float acc[16];
    const float gb = g1b[t];
    #pragma unroll
    for (int k = 0; k < 16; ++k) acc[k] = gb;
    #pragma unroll 4
    for (int c4 = 0; c4 < 64; ++c4) {
        const float* wp = g1w + (size_t)(c4*4) * AA + t;
        const float w0 = wp[0], w1 = wp[AA], w2 = wp[2*AA], w3 = wp[3*AA];
        #pragma unroll
        for (int k = 0; k < 16; ++k) {
            const float4 hv = *(const float4*)&hr[k][c4*4];
            acc[k] = fmaf(hv.x, w0, fmaf(hv.y, w1, fmaf(hv.z, w2, fmaf(hv.w, w3, acc[k]))));
        }
    }
    float s = 0.f, sq = 0.f;
    #pragma unroll
    for (int k = 0; k < 16; ++k) { s += acc[k]; sq = fmaf(acc[k], acc[k], sq); }
    atomicAdd(&stats[ST_G2_SUM + t], s);
    atomicAdd(&stats[ST_G2_SQ + t], sq);
}

__global__ __launch_bounds__(256, 2) void stage4_fp32(
    const float* __restrict__ qproj, const float* __restrict__ kproj,
    const float* __restrict__ vproj,
    const float* __restrict__ t3, const int* __restrict__ idx,
    const float* __restrict__ consts,
    const float* __restrict__ d2w, const float* __restrict__ d2b,
    const float* __restrict__ g1w, const float* __restrict__ g1b,
    const float* __restrict__ g2w, const float* __restrict__ g2b,
    float* __restrict__ out)
{
    const size_t pt = blockIdx.x;
    const int b = (int)(pt >> 12);
    const int t = threadIdx.x;
    __shared__ float a3[48];
    __shared__ int idxs[16];
    __shared__ __align__(16) float r2[16][256];
    if (t < 48) {
        const int j = t % 3;
        a3[t] = fmaxf(fmaf(t3[pt*48 + t], consts[CO_BND_S + j], consts[CO_BND_B + j]), 0.f);
    }
    if (t < 16) idxs[t] = idx[pt*16 + t];
    __syncthreads();
    const float g2s = consts[CO_G2_S + t], g2sh = consts[CO_G2_B + t];
    {
        __shared__ __align__(16) float hr[16][256];
        {
            const float d20 = d2w[t], d21 = d2w[CC + t], d22 = d2w[2*CC + t], d2bc = d2b[t];
            const float g1s = consts[CO_G1_S + t], g1sh = consts[CO_G1_B + t];
            const float qv = qproj[pt * CC + t];
            #pragma unroll
            for (int k = 0; k < 16; ++k) {
                const int mi = idxs[k];
                const float kv = kproj[((size_t)b * NN + mi) * CC + t];
                const float pe = fmaf(a3[k*3], d20, fmaf(a3[k*3+1], d21, fmaf(a3[k*3+2], d22, d2bc)));
                hr[k][t] = fmaxf(fmaf(qv - kv + pe, g1s, g1sh), 0.f);
            }
        }
        __syncthreads();
        float acc[16];
        const float gb = g1b[t];
        #pragma unroll
        for (int k = 0; k < 16; ++k) acc[k] = gb;
        #pragma unroll 4
        for (int c4 = 0; c4 < 64; ++c4) {
            const float* wp = g1w + (size_t)(c4*4) * AA + t;
            const float w0 = wp[0], w1 = wp[AA], w2 = wp[2*AA], w3 = wp[3*AA];
            #pragma unroll
            for (int k = 0; k < 16; ++k) {
                const float4 hv = *(const float4*)&hr[k][c4*4];
                acc[k] = fmaf(hv.x, w0, fmaf(hv.y, w1, fmaf(hv.z, w2, fmaf(hv.w, w3, acc[k]))));
            }
        }
        __syncthreads();
        #pragma unroll
        for (int k = 0; k < 16; ++k) r2[k][t] = fmaxf(fmaf(acc[k], g2s, g2sh), 0.f);
        __syncthreads();
    }
    float lg[16];
    const float gb2 = g2b[t];
    #pragma unroll
    for (int k = 0; k < 16; ++k) lg[k] = gb2;
    #pragma unroll 4
    for (int c4 = 0; c4 < 64; ++c4) {
        const float* wp = g2w + (size_t)(c4*4) * AA + t;
        const float w0 = wp[0], w1 = wp[AA], w2 = wp[2*AA], w3 = wp[3*AA];
        #pragma unroll
        for (int k = 0; k < 16; ++k) {
            const float4 hv = *(const float4*)&r2[k][c4*4];
            lg[k] = fmaf(hv.x, w0, fmaf(hv.y, w1, fmaf(hv.z, w2, fmaf(hv.w, w3, lg[k]))));
        }
    }
    float mx = lg[0];
    #pragma unroll
    for (int k = 1; k < 16; ++k) mx = fmaxf(mx, lg[k]);
    float sum = 0.f;
    #pragma unroll
    for (int k = 0; k < 16; ++k) { lg[k] = expf(lg[k] - mx); sum += lg[k]; }
    const float inv = 1.0f / sum;
    const float d20 = d2w[t], d21 = d2w[CC + t], d22 = d2w[2*CC + t], d2bc = d2b[t];
    float o = 0.f;
    #pragma unroll
    for (int k = 0; k < 16; ++k) {
        const int mi = idxs[k];
        const float vv = vproj[((size_t)b * NN + mi) * CC + t];
        const float pe = fmaf(a3[k*3], d20, fmaf(a3[k*3+1], d21, fmaf(a3[k*3+2], d22, d2bc)));
        o = fmaf(vv + pe, lg[k] * inv, o);
    }
    out[pt * CC + t] = o;
}

// ---------------- host ----------------
extern "C" void kernel_launch(void* const* d_in, const int* in_sizes, int n_in,
                              void* d_out, int out_size, void* d_ws, size_t ws_size,
                              hipStream_t stream)
{
    const float* xyz   = (const float*)d_in[0];
    const float* feat  = (const float*)d_in[1];
    const float* wq    = (const float*)d_in[2];
    const float* bq    = (const float*)d_in[3];
    const float* wk    = (const float*)d_in[4];
    const float* bk    = (const float*)d_in[5];
    const float* wv    = (const float*)d_in[6];
    const float* bv    = (const float*)d_in[7];
    const float* d1w   = (const float*)d_in[8];
    const float* d1b   = (const float*)d_in[9];
    const float* bndg  = (const float*)d_in[10];
    const float* bndb  = (const float*)d_in[11];
    const float* d2w   = (const float*)d_in[12];
    const float* d2b   = (const float*)d_in[13];
    const float* g1g   = (const float*)d_in[14];
    const float* g1bb  = (const float*)d_in[15];
    const float* g1w   = (const float*)d_in[16];
    const float* g1b   = (const float*)d_in[17];
    const float* g2g   = (const float*)d_in[18];
    const float* g2bb  = (const float*)d_in[19];
    const float* g2w   = (const float*)d_in[20];
    const float* g2b   = (const float*)d_in[21];
    float* out = (float*)d_out;

    // workspace layout
    float* qproj = (float*)d_ws;
    float* kproj = qproj + (size_t)NPTS * CC;
    float* vproj = kproj + (size_t)NPTS * CC;
    float* t3    = vproj + (size_t)NPTS * CC;
    float* stats = t3 + (size_t)BNKTOT * 3;
    float* consts = stats + 2048;
    int*   idxb  = (int*)(consts + 2048);
    u16*   g1img = (u16*)(idxb + BNKTOT);
    u16*   g2img = g1img + IMG_TOTAL;
    __hip_bfloat16* h2 = (__hip_bfloat16*)(g2img + IMG_TOTAL);
    const size_t need_store = (size_t)((char*)h2 - (char*)d_ws) + (size_t)BNKTOT * AA * 2;
    const bool store = ws_size >= need_store;

    hipMemsetAsync(stats, 0, 2048 * sizeof(float), stream);

    dim3 gq(NPTS / 64, 3);
    qkv_kernel<<<gq, 256, 0, stream>>>(feat, wq, bq, wk, bk, wv, bv, qproj, kproj, vproj);

    knn_kernel<<<512, 256, 0, stream>>>(xyz, idxb);

    if (store)
        prep_weights<<<dim3(8, 2), 256, 0, stream>>>(g1w, g2w, g1img, g2img);

    fc_delta_kernel<<<BNKTOT / 256, 256, 0, stream>>>(xyz, idxb, d1w, d1b, t3, stats);

    finalize_bnd<<<1, 64, 0, stream>>>(stats, bndg, bndb, consts);

    bn1_stats_kernel<<<1024, 256, 0, stream>>>(qproj, kproj, t3, idxb, consts, d2w, d2b, stats);

    finalize_g<<<1, 256, 0, stream>>>(stats + ST_G1_SUM, stats + ST_G1_SQ, g1g, g1bb,
                                      consts + CO_G1_S, consts + CO_G1_B);

    if (store)
        stage3_mfma<<<NPTS / WPB, 256, 0, stream>>>(qproj, kproj, t3, idxb, consts, stats,
                                                    d2w, d2b, g1img, g1b, h2);
    else
        stage3_fp32<<<NPTS, 256, 0, stream>>>(qproj, kproj, t3, idxb, consts, stats,
                                              d2w, d2b, g1w, g1b);

    finalize_g<<<1, 256, 0, stream>>>(stats + ST_G2_SUM, stats + ST_G2_SQ, g2g, g2bb,
                                      consts + CO_G2_S, consts + CO_G2_B);

    if (store)
        stage4_mfma<<<NPTS / WPB, 256, 0, stream>>>(vproj, t3, idxb, consts,
                                                    d2w, d2b, g2img, g2b, h2, out);
    else
        stage4_fp32<<<NPTS, 256, 0, stream>>>(qproj, kproj, vproj, t3, idxb, consts,
                                              d2w, d2b, g1w, g1b, g2w, g2b, out);
}

// Round 9
// 1329.612 us; speedup vs baseline: 5.0412x; 1.2420x over previous
//
#include <hip/hip_runtime.h>
#include <hip/hip_bf16.h>
#include <math.h>

#define BB 4
#define NN 4096
#define CC 256
#define KK 16
#define AA 256
#define NPTS (BB*NN)            // 16384
#define BNKTOT (NPTS*KK)        // 262144
#define EPSF 1e-5f
#define MINVF (1.0f/262144.0f)

#define WPB 4                    // points per MFMA block (stage3/4)
#define MROWS (WPB*KK)           // 64 rows
#define IMG_PER_KSTEP (256*40)   // ushorts: 256 n-rows x 40 (32 k + pad to 80B)
#define IMG_TOTAL (8*IMG_PER_KSTEP)

// stats / consts float offsets
#define ST_BND_SUM 0
#define ST_BND_SQ  8
#define ST_G1_SUM  16
#define ST_G1_SQ   272
#define ST_G2_SUM  528
#define ST_G2_SQ   784
#define CO_BND_S   0
#define CO_BND_B   4
#define CO_G1_S    16
#define CO_G1_B    272
#define CO_G2_S    528
#define CO_G2_B    784

typedef unsigned short u16;
typedef __attribute__((ext_vector_type(8))) short bf16x8;
typedef __attribute__((ext_vector_type(4))) float f32x4;

__device__ inline u16 f2bf(float x) {           // round-to-nearest-even bf16
    unsigned u = __float_as_uint(x);
    unsigned r = (u + 0x7FFFu + ((u >> 16) & 1u)) >> 16;
    return (u16)r;
}

__device__ inline float waveReduceAdd(float v) {
    #pragma unroll
    for (int o = 32; o > 0; o >>= 1) v += __shfl_down(v, o);
    return v;
}

// ---------------- K1': qkv MFMA — {q,k,v} = feat @ W + b ----------------
// grid (NPTS/64, 3), block 256 = 4 waves. 64 rows x 256 cols per block,
// identical tile structure to stage3_mfma (proven round 8). Only the MFMA
// inputs are bf16-rounded; accumulation is fp32.
__global__ __launch_bounds__(256, 2) void qkv_mfma(
    const float* __restrict__ feat, const u16* __restrict__ wimg_all,
    const float* __restrict__ bq, const float* __restrict__ bk, const float* __restrict__ bv,
    float* __restrict__ oq, float* __restrict__ ok, float* __restrict__ ov)
{
    const int t = threadIdx.x;
    const int l = t & 63, w = t >> 6;
    const int p0 = blockIdx.x * 64;
    const u16* img = wimg_all + (size_t)blockIdx.y * IMG_TOTAL;
    const float* bias = blockIdx.y == 0 ? bq : (blockIdx.y == 1 ? bk : bv);
    float* out = blockIdx.y == 0 ? oq : (blockIdx.y == 1 ? ok : ov);

    __shared__ __align__(16) u16 A_lds[64 * 256];        // 32KB
    __shared__ __align__(16) u16 B_lds[IMG_PER_KSTEP];   // 20KB

    for (int r = 0; r < 64; ++r)
        A_lds[(r * 256 + t) ^ ((r & 7) << 3)] = f2bf(feat[(size_t)(p0 + r) * CC + t]);
    __syncthreads();

    f32x4 acc[4][4];
    #pragma unroll
    for (int q = 0; q < 4; ++q) {
        const float gb = bias[(w*4 + q) * 16 + (l & 15)];
        #pragma unroll
        for (int m = 0; m < 4; ++m) acc[m][q] = (f32x4){gb, gb, gb, gb};
    }

    for (int s = 0; s < 8; ++s) {
        #pragma unroll
        for (int i = 0; i < 5; ++i) {
            const int e = t + i * 256;
            *(uint4*)&B_lds[e * 8] = *(const uint4*)&img[(size_t)s * IMG_PER_KSTEP + e * 8];
        }
        __syncthreads();
        bf16x8 bf[4];
        #pragma unroll
        for (int q = 0; q < 4; ++q)
            bf[q] = *(const bf16x8*)&B_lds[((w*4 + q) * 16 + (l & 15)) * 40 + (l >> 4) * 8];
        #pragma unroll
        for (int m = 0; m < 4; ++m) {
            const int r = m * 16 + (l & 15);
            const bf16x8 af = *(const bf16x8*)&A_lds[((r * 256 + s * 32 + (l >> 4) * 8)) ^ ((r & 7) << 3)];
            #pragma unroll
            for (int q = 0; q < 4; ++q)
                acc[m][q] = __builtin_amdgcn_mfma_f32_16x16x32_bf16(af, bf[q], acc[m][q], 0, 0, 0);
        }
        __syncthreads();
    }

    #pragma unroll
    for (int q = 0; q < 4; ++q) {
        const int a = (w*4 + q) * 16 + (l & 15);
        #pragma unroll
        for (int m = 0; m < 4; ++m)
            #pragma unroll
            for (int j = 0; j < 4; ++j)
                out[(size_t)(p0 + m*16 + (l >> 4)*4 + j) * CC + a] = acc[m][q][j];
    }
}

// ---------------- K1 fallback: fp32 qkv ----------------
__global__ __launch_bounds__(256, 2) void qkv_kernel(
    const float* __restrict__ feat,
    const float* __restrict__ wq, const float* __restrict__ bq,
    const float* __restrict__ wk, const float* __restrict__ bk,
    const float* __restrict__ wv, const float* __restrict__ bv,
    float* __restrict__ oq, float* __restrict__ ok, float* __restrict__ ov)
{
    const float* W; const float* bias; float* out;
    if (blockIdx.y == 0)      { W = wq; bias = bq; out = oq; }
    else if (blockIdx.y == 1) { W = wk; bias = bk; out = ok; }
    else                      { W = wv; bias = bv; out = ov; }

    const int p0 = blockIdx.x * 64;
    const int t  = threadIdx.x;
    __shared__ __align__(16) float fs[64][65];

    float acc[64];
    #pragma unroll
    for (int p = 0; p < 64; ++p) acc[p] = 0.f;

    for (int it = 0; it < 4; ++it) {
        const int tp = t >> 2;
        #pragma unroll
        for (int q = 0; q < 4; ++q) {
            const int ch = (t & 3) + q * 4;
            float4 v = *(const float4*)&feat[(size_t)(p0 + tp) * CC + it * 64 + ch * 4];
            fs[tp][ch*4+0] = v.x; fs[tp][ch*4+1] = v.y; fs[tp][ch*4+2] = v.z; fs[tp][ch*4+3] = v.w;
        }
        __syncthreads();
        #pragma unroll 4
        for (int i = 0; i < 64; ++i) {
            const float w = W[(size_t)(it * 64 + i) * CC + t];
            #pragma unroll
            for (int p = 0; p < 64; ++p) acc[p] = fmaf(fs[p][i], w, acc[p]);
        }
        __syncthreads();
    }
    const float bv_ = bias[t];
    #pragma unroll
    for (int p = 0; p < 64; ++p) out[(size_t)(p0 + p) * CC + t] = acc[p] + bv_;
}

// ---------------- K2: KNN top-16 ----------------
// LDS: pl_* (36KB, live only after the loop) aliases tile (8KB, live only
// during it) -> 35.9KB/block -> 4 blocks/CU (was 44.5KB -> 2-3, occupancy 20%).
__global__ __launch_bounds__(256, 2) void knn_kernel(
    const float* __restrict__ xyz, int* __restrict__ idxout)
{
    const int t = threadIdx.x;
    const int q = t >> 3;
    const int c = t & 7;
    const int b = blockIdx.x >> 7;
    const int n = ((blockIdx.x & 127) << 5) + q;
    const float* xb = xyz + (size_t)b * NN * 3;

    const float qx = xb[n*3+0], qy = xb[n*3+1], qz = xb[n*3+2];
    const float sqn = qx*qx + qy*qy + qz*qz;

    __shared__ __align__(16) unsigned char smem[35904];
    float4* tile = (float4*)smem;                       // [512] during main loop
    float*  pl_d = (float*)smem;                        // [(c*17+s)*33+q] after loop
    int*    pl_i = (int*)(smem + 17952);

    float bd[16]; int bi[16];
    #pragma unroll
    for (int s = 0; s < 16; ++s) { bd[s] = 1e30f; bi[s] = 0; }

    for (int t0 = 0; t0 < NN; t0 += 512) {
        #pragma unroll
        for (int r = 0; r < 2; ++r) {
            const int j = t + r * 256;
            const float x = xb[(t0 + j)*3 + 0];
            const float y = xb[(t0 + j)*3 + 1];
            const float z = xb[(t0 + j)*3 + 2];
            tile[j] = make_float4(x, y, z, x*x + y*y + z*z);
        }
        __syncthreads();
        #pragma unroll 2
        for (int j0 = 0; j0 < 512; j0 += 8) {
            const int j = j0 + c;
            const float4 p = tile[j];
            const float d = sqn + p.w - 2.0f * (qx*p.x + qy*p.y + qz*p.z);
            if (d < bd[15]) {
                const int m = t0 + j;
                bool placed = false;
                #pragma unroll
                for (int s = 15; s > 0; --s) {
                    if (!placed) {
                        if (bd[s-1] > d) { bd[s] = bd[s-1]; bi[s] = bi[s-1]; }
                        else             { bd[s] = d; bi[s] = m; placed = true; }
                    }
                }
                if (!placed) { bd[0] = d; bi[0] = m; }
            }
        }
        __syncthreads();
    }

    // tile no longer read; alias region now holds partial lists
    #pragma unroll
    for (int s = 0; s < 16; ++s) {
        pl_d[(c*17 + s)*33 + q] = bd[s];
        pl_i[(c*17 + s)*33 + q] = bi[s];
    }
    __syncthreads();

    if (t < 32) {
        const int qq = t;
        float hd[8]; int hi[8]; int p[8];
        #pragma unroll
        for (int cc = 0; cc < 8; ++cc) {
            hd[cc] = pl_d[(cc*17)*33 + qq]; hi[cc] = pl_i[(cc*17)*33 + qq]; p[cc] = 1;
        }
        const int nq = ((blockIdx.x & 127) << 5) + qq;
        int* op = idxout + ((size_t)b * NN + nq) * KK;
        #pragma unroll
        for (int s = 0; s < 16; ++s) {
            float bdv = hd[0]; int biv = hi[0]; int bc = 0;
            #pragma unroll
            for (int cc = 1; cc < 8; ++cc) {
                const bool better = (hd[cc] < bdv) || (hd[cc] == bdv && hi[cc] < biv);
                if (better) { bdv = hd[cc]; biv = hi[cc]; bc = cc; }
            }
            op[s] = biv;
            #pragma unroll
            for (int cc = 0; cc < 8; ++cc) {
                if (bc == cc) {
                    const int pp = p[cc];
                    const bool ok = pp < 16;
                    hd[cc] = ok ? pl_d[(cc*17 + pp)*33 + qq] : 1e38f;
                    hi[cc] = ok ? pl_i[(cc*17 + pp)*33 + qq] : 0;
                    p[cc] = pp + 1;
                }
            }
        }
    }
}

// ---------------- K3: t = rel@d1_w + d1_b, bn_d stats ----------------
__global__ __launch_bounds__(256) void fc_delta_kernel(
    const float* __restrict__ xyz, const int* __restrict__ idx,
    const float* __restrict__ d1w, const float* __restrict__ d1b,
    float* __restrict__ t3, float* __restrict__ stats)
{
    const int g = blockIdx.x * 256 + threadIdx.x;
    const int b = g >> 16;
    const int rem = g & 65535;
    const int n = rem >> 4;
    const int mi = idx[g];
    const float* xb = xyz + (size_t)b * NN * 3;
    const float rx = xb[n*3+0] - xb[mi*3+0];
    const float ry = xb[n*3+1] - xb[mi*3+1];
    const float rz = xb[n*3+2] - xb[mi*3+2];
    float tv[3];
    #pragma unroll
    for (int j = 0; j < 3; ++j) {
        tv[j] = fmaf(rx, d1w[0*3+j], fmaf(ry, d1w[1*3+j], fmaf(rz, d1w[2*3+j], d1b[j])));
        t3[(size_t)g*3 + j] = tv[j];
    }
    const int lane = threadIdx.x & 63;
    #pragma unroll
    for (int j = 0; j < 3; ++j) {
        float s  = waveReduceAdd(tv[j]);
        float sq = waveReduceAdd(tv[j]*tv[j]);
        if (lane == 0) {
            atomicAdd(&stats[ST_BND_SUM + j], s);
            atomicAdd(&stats[ST_BND_SQ + j], sq);
        }
    }
}

// ---------------- finalize bn_d ----------------
__global__ void finalize_bnd(const float* __restrict__ stats,
                             const float* __restrict__ g, const float* __restrict__ b,
                             float* __restrict__ consts)
{
    const int t = threadIdx.x;
    if (t < 3) {
        const float m = stats[ST_BND_SUM + t] * MINVF;
        const float v = stats[ST_BND_SQ + t] * MINVF - m * m;
        const float s = g[t] / sqrtf(v + EPSF);
        consts[CO_BND_S + t] = s;
        consts[CO_BND_B + t] = b[t] - m * s;
    }
}

// ---------------- K5: g_bn1 stats ----------------
__global__ __launch_bounds__(256, 2) void bn1_stats_kernel(
    const float* __restrict__ qproj, const float* __restrict__ kproj,
    const float* __restrict__ t3, const int* __restrict__ idx,
    const float* __restrict__ consts,
    const float* __restrict__ d2w, const float* __restrict__ d2b,
    float* __restrict__ stats)
{
    const int b   = blockIdx.x >> 8;
    const int pt0 = (blockIdx.x & 255) * 16;
    const int t = threadIdx.x;

    __shared__ float a3[768];
    __shared__ int idxs[256];

    const float bs[3]  = {consts[CO_BND_S+0], consts[CO_BND_S+1], consts[CO_BND_S+2]};
    const float bsh[3] = {consts[CO_BND_B+0], consts[CO_BND_B+1], consts[CO_BND_B+2]};
    const float* t3b = t3 + (size_t)(b * NN + pt0) * KK * 3;
    #pragma unroll
    for (int q = 0; q < 3; ++q) {
        const int f = t + q * 256;
        const int j = f % 3;
        a3[f] = fmaxf(fmaf(t3b[f], bs[j], bsh[j]), 0.f);
    }
    idxs[t] = idx[(size_t)(b * NN + pt0) * KK + t];
    __syncthreads();

    const int c = t;
    const float d20 = d2w[c], d21 = d2w[CC + c], d22 = d2w[2*CC + c], d2bc = d2b[c];
    float s = 0.f, sq = 0.f;
    for (int p = 0; p < 16; ++p) {
        const float qv = qproj[(size_t)(b * NN + pt0 + p) * CC + c];
        #pragma unroll
        for (int k = 0; k < 16; ++k) {
            const int mi = idxs[p*16 + k];
            const float kv = kproj[((size_t)b * NN + mi) * CC + c];
            const int f = (p*16 + k) * 3;
            const float pe = fmaf(a3[f], d20, fmaf(a3[f+1], d21, fmaf(a3[f+2], d22, d2bc)));
            const float h = qv - kv + pe;
            s += h; sq = fmaf(h, h, sq);
        }
    }
    atomicAdd(&stats[ST_G1_SUM + c], s);
    atomicAdd(&stats[ST_G1_SQ + c], sq);
}

// ---------------- finalize g_bn ----------------
__global__ void finalize_g(const float* __restrict__ ssum, const float* __restrict__ ssq,
                           const float* __restrict__ g, const float* __restrict__ b,
                           float* __restrict__ os, float* __restrict__ ob)
{
    const int c = threadIdx.x;
    const float m = ssum[c] * MINVF;
    const float v = ssq[c] * MINVF - m * m;
    const float s = g[c] / sqrtf(v + EPSF);
    os[c] = s;
    ob[c] = b[c] - m * s;
}

// ---------------- prep: transpose 5 weight matrices to bf16 image layout ----------------
// img[mat][kstep][n*40 + kr] = bf16(W[kstep*32 + kr][n]); mats: wq,wk,wv,g1w,g2w
__global__ __launch_bounds__(256) void prep_weights(
    const float* __restrict__ wq, const float* __restrict__ wk,
    const float* __restrict__ wv, const float* __restrict__ g1w,
    const float* __restrict__ g2w, u16* __restrict__ img_all)
{
    const int s = blockIdx.x;
    const int mat = blockIdx.y;
    const float* W = mat == 0 ? wq : mat == 1 ? wk : mat == 2 ? wv : mat == 3 ? g1w : g2w;
    u16* img = img_all + (size_t)mat * IMG_TOTAL + (size_t)s * IMG_PER_KSTEP;
    const int n = threadIdx.x;
    #pragma unroll
    for (int i = 0; i < 32; ++i) {
        img[n*40 + i] = f2bf(W[(size_t)(s*32 + i) * AA + n]);
    }
}

// ---------------- K7': stage3 MFMA ----------------
__global__ __launch_bounds__(256, 2) void stage3_mfma(
    const float* __restrict__ qproj, const float* __restrict__ kproj,
    const float* __restrict__ t3, const int* __restrict__ idx,
    const float* __restrict__ consts, float* __restrict__ stats,
    const float* __restrict__ d2w, const float* __restrict__ d2b,
    const u16* __restrict__ g1img, const float* __restrict__ g1b,
    __hip_bfloat16* __restrict__ h2)
{
    const int t = threadIdx.x;
    const int l = t & 63, w = t >> 6;
    const int pt0 = blockIdx.x * WPB;
    const int bI = pt0 >> 12;

    __shared__ __align__(16) u16 A_lds[MROWS * 256];
    __shared__ __align__(16) u16 B_lds[IMG_PER_KSTEP];
    __shared__ int   idxs[MROWS];
    __shared__ float a3s[MROWS * 3];

    if (t < MROWS) idxs[t] = idx[(size_t)pt0 * KK + t];
    if (t < MROWS * 3) {
        const int j = t % 3;
        a3s[t] = fmaxf(fmaf(t3[(size_t)pt0 * 48 + t], consts[CO_BND_S + j], consts[CO_BND_B + j]), 0.f);
    }
    __syncthreads();

    {
        const float d20 = d2w[t], d21 = d2w[CC + t], d22 = d2w[2*CC + t], d2bc = d2b[t];
        const float g1s = consts[CO_G1_S + t], g1sh = consts[CO_G1_B + t];
        float qv[WPB];
        #pragma unroll
        for (int p = 0; p < WPB; ++p) qv[p] = qproj[(size_t)(pt0 + p) * CC + t];
        for (int r = 0; r < MROWS; ++r) {
            const int mi = idxs[r];
            const float kv = kproj[((size_t)bI * NN + mi) * CC + t];
            const float pe = fmaf(a3s[r*3], d20, fmaf(a3s[r*3+1], d21, fmaf(a3s[r*3+2], d22, d2bc)));
            const float h = qv[r >> 4] - kv + pe;
            const float av = fmaxf(fmaf(h, g1s, g1sh), 0.f);
            A_lds[(r * 256 + t) ^ ((r & 7) << 3)] = f2bf(av);
        }
    }
    __syncthreads();

    f32x4 acc[4][4];
    #pragma unroll
    for (int q = 0; q < 4; ++q) {
        const float gb = g1b[(w*4 + q) * 16 + (l & 15)];
        #pragma unroll
        for (int m = 0; m < 4; ++m) acc[m][q] = (f32x4){gb, gb, gb, gb};
    }

    for (int s = 0; s < 8; ++s) {
        #pragma unroll
        for (int i = 0; i < 5; ++i) {
            const int e = t + i * 256;
            *(uint4*)&B_lds[e * 8] = *(const uint4*)&g1img[(size_t)s * IMG_PER_KSTEP + e * 8];
        }
        __syncthreads();
        bf16x8 bf[4];
        #pragma unroll
        for (int q = 0; q < 4; ++q)
            bf[q] = *(const bf16x8*)&B_lds[((w*4 + q) * 16 + (l & 15)) * 40 + (l >> 4) * 8];
        #pragma unroll
        for (int m = 0; m < 4; ++m) {
            const int r = m * 16 + (l & 15);
            const bf16x8 af = *(const bf16x8*)&A_lds[((r * 256 + s * 32 + (l >> 4) * 8)) ^ ((r & 7) << 3)];
            #pragma unroll
            for (int q = 0; q < 4; ++q)
                acc[m][q] = __builtin_amdgcn_mfma_f32_16x16x32_bf16(af, bf[q], acc[m][q], 0, 0, 0);
        }
        __syncthreads();
    }

    #pragma unroll
    for (int q = 0; q < 4; ++q) {
        const int a = (w*4 + q) * 16 + (l & 15);
        float sc = 0.f, sq = 0.f;
        #pragma unroll
        for (int m = 0; m < 4; ++m) {
            #pragma unroll
            for (int j = 0; j < 4; ++j) {
                const float v = acc[m][q][j];
                sc += v; sq = fmaf(v, v, sq);
                h2[((size_t)(pt0 + m) * KK + ((l >> 4) * 4 + j)) * AA + a] = __float2bfloat16(v);
            }
        }
        sc += __shfl_xor(sc, 16); sc += __shfl_xor(sc, 32);
        sq += __shfl_xor(sq, 16); sq += __shfl_xor(sq, 32);
        if (l < 16) {
            atomicAdd(&stats[ST_G2_SUM + a], sc);
            atomicAdd(&stats[ST_G2_SQ + a], sq);
        }
    }
}

// ---------------- K9': stage4 MFMA ----------------
__global__ __launch_bounds__(256, 2) void stage4_mfma(
    const float* __restrict__ vproj,
    const float* __restrict__ t3, const int* __restrict__ idx,
    const float* __restrict__ consts,
    const float* __restrict__ d2w, const float* __restrict__ d2b,
    const u16* __restrict__ g2img, const float* __restrict__ g2b,
    const __hip_bfloat16* __restrict__ h2, float* __restrict__ out)
{
    const int t = threadIdx.x;
    const int l = t & 63, w = t >> 6;
    const int pt0 = blockIdx.x * WPB;
    const int bI = pt0 >> 12;

    __shared__ __align__(16) u16 A_lds[MROWS * 256];
    __shared__ __align__(16) u16 B_lds[IMG_PER_KSTEP];
    __shared__ int   idxs[MROWS];
    __shared__ float a3s[MROWS * 3];

    if (t < MROWS) idxs[t] = idx[(size_t)pt0 * KK + t];
    if (t < MROWS * 3) {
        const int j = t % 3;
        a3s[t] = fmaxf(fmaf(t3[(size_t)pt0 * 48 + t], consts[CO_BND_S + j], consts[CO_BND_B + j]), 0.f);
    }
    __syncthreads();

    {
        const float g2s = consts[CO_G2_S + t], g2sh = consts[CO_G2_B + t];
        for (int r = 0; r < MROWS; ++r) {
            const float hv = __bfloat162float(h2[((size_t)pt0 * KK + r) * AA + t]);
            const float av = fmaxf(fmaf(hv, g2s, g2sh), 0.f);
            A_lds[(r * 256 + t) ^ ((r & 7) << 3)] = f2bf(av);
        }
    }
    __syncthreads();

    f32x4 acc[4][4];
    #pragma unroll
    for (int q = 0; q < 4; ++q) {
        const float gb = g2b[(w*4 + q) * 16 + (l & 15)];
        #pragma unroll
        for (int m = 0; m < 4; ++m) acc[m][q] = (f32x4){gb, gb, gb, gb};
    }

    for (int s = 0; s < 8; ++s) {
        #pragma unroll
        for (int i = 0; i < 5; ++i) {
            const int e = t + i * 256;
            *(uint4*)&B_lds[e * 8] = *(const uint4*)&g2img[(size_t)s * IMG_PER_KSTEP + e * 8];
        }
        __syncthreads();
        bf16x8 bf[4];
        #pragma unroll
        for (int q = 0; q < 4; ++q)
            bf[q] = *(const bf16x8*)&B_lds[((w*4 + q) * 16 + (l & 15)) * 40 + (l >> 4) * 8];
        #pragma unroll
        for (int m = 0; m < 4; ++m) {
            const int r = m * 16 + (l & 15);
            const bf16x8 af = *(const bf16x8*)&A_lds[((r * 256 + s * 32 + (l >> 4) * 8)) ^ ((r & 7) << 3)];
            #pragma unroll
            for (int q = 0; q < 4; ++q)
                acc[m][q] = __builtin_amdgcn_mfma_f32_16x16x32_bf16(af, bf[q], acc[m][q], 0, 0, 0);
        }
        __syncthreads();
    }

    #pragma unroll
    for (int q = 0; q < 4; ++q) {
        const int a = (w*4 + q) * 16 + (l & 15);
        const float dw0 = d2w[a], dw1 = d2w[CC + a], dw2 = d2w[2*CC + a], db = d2b[a];
        #pragma unroll
        for (int m = 0; m < 4; ++m) {
            f32x4 lg = acc[m][q];
            float mx = fmaxf(fmaxf(lg[0], lg[1]), fmaxf(lg[2], lg[3]));
            mx = fmaxf(mx, __shfl_xor(mx, 16));
            mx = fmaxf(mx, __shfl_xor(mx, 32));
            float e[4]; float ss = 0.f;
            #pragma unroll
            for (int j = 0; j < 4; ++j) { e[j] = expf(lg[j] - mx); ss += e[j]; }
            ss += __shfl_xor(ss, 16); ss += __shfl_xor(ss, 32);
            const float inv = 1.0f / ss;
            float part = 0.f;
            #pragma unroll
            for (int j = 0; j < 4; ++j) {
                const int kk = (l >> 4) * 4 + j;
                const int mi = idxs[m * 16 + kk];
                const float vv = vproj[((size_t)bI * NN + mi) * CC + a];
                const float pe = fmaf(a3s[(m*16+kk)*3], dw0,
                                 fmaf(a3s[(m*16+kk)*3+1], dw1,
                                 fmaf(a3s[(m*16+kk)*3+2], dw2, db)));
                part = fmaf(e[j] * inv, vv + pe, part);
            }
            part += __shfl_xor(part, 16); part += __shfl_xor(part, 32);
            if (l < 16) out[(size_t)(pt0 + m) * CC + a] = part;
        }
    }
}

// ---------------- fallback fp32 kernels (ws too small) ----------------
__global__ __launch_bounds__(256, 2) void stage3_fp32(
    const float* __restrict__ qproj, const float* __restrict__ kproj,
    const float* __restrict__ t3, const int* __restrict__ idx,
    const float* __restrict__ consts, float* __restrict__ stats,
    const float* __restrict__ d2w, const float* __restrict__ d2b,
    const float* __restrict__ g1w, const float* __restrict__ g1b)
{
    const size_t pt = blockIdx.x;
    const int b = (int)(pt >> 12);
    const int t = threadIdx.x;
    __shared__ float a3[48];
    __shared__ int idxs[16];
    __shared__ __align__(16) float hr[16][256];
    if (t < 48) {
        const int j = t % 3;
        a3[t] = fmaxf(fmaf(t3[pt*48 + t], consts[CO_BND_S + j], consts[CO_BND_B + j]), 0.f);
    }
    if (t < 16) idxs[t] = idx[pt*16 + t];
    __syncthreads();
    {
        const float d20 = d2w[t], d21 = d2w[CC + t], d22 = d2w[2*CC + t], d2bc = d2b[t];
        const float g1s = consts[CO_G1_S + t], g1sh = consts[CO_G1_B + t];
        const float qv = qproj[pt * CC + t];
        #pragma unroll
        for (int k = 0; k < 16; ++k) {
            const int mi = idxs[k];
            const float kv = kproj[((size_t)b * NN + mi) * CC + t];
            const float pe = fmaf(a3[k*3], d20, fmaf(a3[k*3+1], d21, fmaf(a3[k*3+2], d22, d2bc)));
            hr[k][t] = fmaxf(fmaf(qv - kv + pe, g1s, g1sh), 0.f);
        }
    }
    __syncthreads();
    float acc[16];
    const float gb = g1b[t];
    #pragma unroll
    for (int k = 0; k < 16; ++k) acc[k] = gb;
    #pragma unroll 4
    for (int c4 = 0; c4 < 64; ++c4) {
        const float* wp = g1w + (size_t)(c4*4) * AA + t;
        const float w0 = wp[0], w1 = wp[AA], w2 = wp[2*AA], w3 = wp[3*AA];
        #pragma unroll
        for (int k = 0; k < 16; ++k) {
            const float4 hv = *(const float4*)&hr[k][c4*4];
            acc[k] = fmaf(hv.x, w0, fmaf(hv.y, w1, fmaf(hv.z, w2, fmaf(hv.w, w3, acc[k]))));
        }
    }
    float s = 0.f, sq = 0.f;
    #pragma unroll
    for (int k = 0; k < 16; ++k) { s += acc[k]; sq = fmaf(acc[k], acc[k], sq); }
    atomicAdd(&stats[ST_G2_SUM + t], s);
    atomicAdd(&stats[ST_G2_SQ + t], sq);
}

__global__ __launch_bounds__(256, 2) void stage4_fp32(
    const float* __restrict__ qproj, const float* __restrict__ kproj,
    const float* __restrict__ vproj,
    const float* __restrict__ t3, const int* __restrict__ idx,
    const float* __restrict__ consts,
    const float* __restrict__ d2w, const float* __restrict__ d2b,
    const float* __restrict__ g1w, const float* __restrict__ g1b,
    const float* __restrict__ g2w, const float* __restrict__ g2b,
    float* __restrict__ out)
{
    const size_t pt = blockIdx.x;
    const int b = (int)(pt >> 12);
    const int t = threadIdx.x;
    __shared__ float a3[48];
    __shared__ int idxs[16];
    __shared__ __align__(16) float r2[16][256];
    if (t < 48) {
        const int j = t % 3;
        a3[t] = fmaxf(fmaf(t3[pt*48 + t], consts[CO_BND_S + j], consts[CO_BND_B + j]), 0.f);
    }
    if (t < 16) idxs[t] = idx[pt*16 + t];
    __syncthreads();
    const float g2s = consts[CO_G2_S + t], g2sh = consts[CO_G2_B + t];
    {
        __shared__ __align__(16) float hr[16][256];
        {
            const float d20 = d2w[t], d21 = d2w[CC + t], d22 = d2w[2*CC + t], d2bc = d2b[t];
            const float g1s = consts[CO_G1_S + t], g1sh = consts[CO_G1_B + t];
            const float qv = qproj[pt * CC + t];
            #pragma unroll
            for (int k = 0; k < 16; ++k) {
                const int mi = idxs[k];
                const float kv = kproj[((size_t)b * NN + mi) * CC + t];
                const float pe = fmaf(a3[k*3], d20, fmaf(a3[k*3+1], d21, fmaf(a3[k*3+2], d22, d2bc)));
                hr[k][t] = fmaxf(fmaf(qv - kv + pe, g1s, g1sh), 0.f);
            }
        }
        __syncthreads();
        float acc[16];
        const float gb = g1b[t];
        #pragma unroll
        for (int k = 0; k < 16; ++k) acc[k] = gb;
        #pragma unroll 4
        for (int c4 = 0; c4 < 64; ++c4) {
            const float* wp = g1w + (size_t)(c4*4) * AA + t;
            const float w0 = wp[0], w1 = wp[AA], w2 = wp[2*AA], w3 = wp[3*AA];
            #pragma unroll
            for (int k = 0; k < 16; ++k) {
                const float4 hv = *(const float4*)&hr[k][c4*4];
                acc[k] = fmaf(hv.x, w0, fmaf(hv.y, w1, fmaf(hv.z, w2, fmaf(hv.w, w3, acc[k]))));
            }
        }
        __syncthreads();
        #pragma unroll
        for (int k = 0; k < 16; ++k) r2[k][t] = fmaxf(fmaf(acc[k], g2s, g2sh), 0.f);
        __syncthreads();
    }
    float lg[16];
    const float gb2 = g2b[t];
    #pragma unroll
    for (int k = 0; k < 16; ++k) lg[k] = gb2;
    #pragma unroll 4
    for (int c4 = 0; c4 < 64; ++c4) {
        const float* wp = g2w + (size_t)(c4*4) * AA + t;
        const float w0 = wp[0], w1 = wp[AA], w2 = wp[2*AA], w3 = wp[3*AA];
        #pragma unroll
        for (int k = 0; k < 16; ++k) {
            const float4 hv = *(const float4*)&r2[k][c4*4];
            lg[k] = fmaf(hv.x, w0, fmaf(hv.y, w1, fmaf(hv.z, w2, fmaf(hv.w, w3, lg[k]))));
        }
    }
    float mx = lg[0];
    #pragma unroll
    for (int k = 1; k < 16; ++k) mx = fmaxf(mx, lg[k]);
    float sum = 0.f;
    #pragma unroll
    for (int k = 0; k < 16; ++k) { lg[k] = expf(lg[k] - mx); sum += lg[k]; }
    const float inv = 1.0f / sum;
    const float d20 = d2w[t], d21 = d2w[CC + t], d22 = d2w[2*CC + t], d2bc = d2b[t];
    float o = 0.f;
    #pragma unroll
    for (int k = 0; k < 16; ++k) {
        const int mi = idxs[k];
        const float vv = vproj[((size_t)b * NN + mi) * CC + t];
        const float pe = fmaf(a3[k*3], d20, fmaf(a3[k*3+1], d21, fmaf(a3[k*3+2], d22, d2bc)));
        o = fmaf(vv + pe, lg[k] * inv, o);
    }
    out[pt * CC + t] = o;
}

// ---------------- host ----------------
extern "C" void kernel_launch(void* const* d_in, const int* in_sizes, int n_in,
                              void* d_out, int out_size, void* d_ws, size_t ws_size,
                              hipStream_t stream)
{
    const float* xyz   = (const float*)d_in[0];
    const float* feat  = (const float*)d_in[1];
    const float* wq    = (const float*)d_in[2];
    const float* bq    = (const float*)d_in[3];
    const float* wk    = (const float*)d_in[4];
    const float* bk    = (const float*)d_in[5];
    const float* wv    = (const float*)d_in[6];
    const float* bv    = (const float*)d_in[7];
    const float* d1w   = (const float*)d_in[8];
    const float* d1b   = (const float*)d_in[9];
    const float* bndg  = (const float*)d_in[10];
    const float* bndb  = (const float*)d_in[11];
    const float* d2w   = (const float*)d_in[12];
    const float* d2b   = (const float*)d_in[13];
    const float* g1g   = (const float*)d_in[14];
    const float* g1bb  = (const float*)d_in[15];
    const float* g1w   = (const float*)d_in[16];
    const float* g1b   = (const float*)d_in[17];
    const float* g2g   = (const float*)d_in[18];
    const float* g2bb  = (const float*)d_in[19];
    const float* g2w   = (const float*)d_in[20];
    const float* g2b   = (const float*)d_in[21];
    float* out = (float*)d_out;

    // workspace layout
    float* qproj = (float*)d_ws;
    float* kproj = qproj + (size_t)NPTS * CC;
    float* vproj = kproj + (size_t)NPTS * CC;
    float* t3    = vproj + (size_t)NPTS * CC;
    float* stats = t3 + (size_t)BNKTOT * 3;
    float* consts = stats + 2048;
    int*   idxb  = (int*)(consts + 2048);
    u16*   wimg  = (u16*)(idxb + BNKTOT);          // 5 matrices: wq,wk,wv,g1w,g2w
    u16*   g1img = wimg + (size_t)3 * IMG_TOTAL;
    u16*   g2img = wimg + (size_t)4 * IMG_TOTAL;
    __hip_bfloat16* h2 = (__hip_bfloat16*)(wimg + (size_t)5 * IMG_TOTAL);
    const size_t need_store = (size_t)((char*)h2 - (char*)d_ws) + (size_t)BNKTOT * AA * 2;
    const bool store = ws_size >= need_store;

    hipMemsetAsync(stats, 0, 2048 * sizeof(float), stream);

    if (store) {
        prep_weights<<<dim3(8, 5), 256, 0, stream>>>(wq, wk, wv, g1w, g2w, wimg);
        qkv_mfma<<<dim3(NPTS / 64, 3), 256, 0, stream>>>(feat, wimg, bq, bk, bv,
                                                         qproj, kproj, vproj);
    } else {
        dim3 gq(NPTS / 64, 3);
        qkv_kernel<<<gq, 256, 0, stream>>>(feat, wq, bq, wk, bk, wv, bv, qproj, kproj, vproj);
    }

    knn_kernel<<<512, 256, 0, stream>>>(xyz, idxb);

    fc_delta_kernel<<<BNKTOT / 256, 256, 0, stream>>>(xyz, idxb, d1w, d1b, t3, stats);

    finalize_bnd<<<1, 64, 0, stream>>>(stats, bndg, bndb, consts);

    bn1_stats_kernel<<<1024, 256, 0, stream>>>(qproj, kproj, t3, idxb, consts, d2w, d2b, stats);

    finalize_g<<<1, 256, 0, stream>>>(stats + ST_G1_SUM, stats + ST_G1_SQ, g1g, g1bb,
                                      consts + CO_G1_S, consts + CO_G1_B);

    if (store)
        stage3_mfma<<<NPTS / WPB, 256, 0, stream>>>(qproj, kproj, t3, idxb, consts, stats,
                                                    d2w, d2b, g1img, g1b, h2);
    else
        stage3_fp32<<<NPTS, 256, 0, stream>>>(qproj, kproj, t3, idxb, consts, stats,
                                              d2w, d2b, g1w, g1b);

    finalize_g<<<1, 256, 0, stream>>>(stats + ST_G2_SUM, stats + ST_G2_SQ, g2g, g2bb,
                                      consts + CO_G2_S, consts + CO_G2_B);

    if (store)
        stage4_mfma<<<NPTS / WPB, 256, 0, stream>>>(vproj, t3, idxb, consts,
                                                    d2w, d2b, g2img, g2b, h2, out);
    else
        stage4_fp32<<<NPTS, 256, 0, stream>>>(qproj, kproj, vproj, t3, idxb, consts,
                                              d2w, d2b, g1w, g1b, g2w, g2b, out);
}

// Round 10
// 1246.424 us; speedup vs baseline: 5.3776x; 1.0667x over previous
//
#include <hip/hip_runtime.h>
#include <hip/hip_bf16.h>
#include <math.h>

#define BB 4
#define NN 4096
#define CC 256
#define KK 16
#define AA 256
#define NPTS (BB*NN)            // 16384
#define BNKTOT (NPTS*KK)        // 262144
#define EPSF 1e-5f
#define MINVF (1.0f/262144.0f)

#define WPB 4                    // points per MFMA block (stage3/4)
#define MROWS (WPB*KK)           // 64 rows
#define IMG_PER_KSTEP (256*40)   // ushorts: 256 n-rows x 40 (32 k + pad to 80B)
#define IMG_TOTAL (8*IMG_PER_KSTEP)

// stats / consts float offsets
#define ST_BND_SUM 0
#define ST_BND_SQ  8
#define ST_G1_SUM  16
#define ST_G1_SQ   272
#define ST_G2_SUM  528
#define ST_G2_SQ   784
#define CO_BND_S   0
#define CO_BND_B   4
#define CO_G1_S    16
#define CO_G1_B    272
#define CO_G2_S    528
#define CO_G2_B    784

typedef unsigned short u16;
typedef __attribute__((ext_vector_type(8))) short bf16x8;
typedef __attribute__((ext_vector_type(4))) float f32x4;

__device__ inline u16 f2bf(float x) {           // round-to-nearest-even bf16
    unsigned u = __float_as_uint(x);
    unsigned r = (u + 0x7FFFu + ((u >> 16) & 1u)) >> 16;
    return (u16)r;
}

__device__ inline float waveReduceAdd(float v) {
    #pragma unroll
    for (int o = 32; o > 0; o >>= 1) v += __shfl_down(v, o);
    return v;
}

// ---------------- K1': qkv MFMA — {q,k,v} = feat @ W + b ----------------
__global__ __launch_bounds__(256, 2) void qkv_mfma(
    const float* __restrict__ feat, const u16* __restrict__ wimg_all,
    const float* __restrict__ bq, const float* __restrict__ bk, const float* __restrict__ bv,
    float* __restrict__ oq, float* __restrict__ ok, float* __restrict__ ov)
{
    const int t = threadIdx.x;
    const int l = t & 63, w = t >> 6;
    const int p0 = blockIdx.x * 64;
    const u16* img = wimg_all + (size_t)blockIdx.y * IMG_TOTAL;
    const float* bias = blockIdx.y == 0 ? bq : (blockIdx.y == 1 ? bk : bv);
    float* out = blockIdx.y == 0 ? oq : (blockIdx.y == 1 ? ok : ov);

    __shared__ __align__(16) u16 A_lds[64 * 256];        // 32KB
    __shared__ __align__(16) u16 B_lds[IMG_PER_KSTEP];   // 20KB

    for (int r = 0; r < 64; ++r)
        A_lds[(r * 256 + t) ^ ((r & 7) << 3)] = f2bf(feat[(size_t)(p0 + r) * CC + t]);
    __syncthreads();

    f32x4 acc[4][4];
    #pragma unroll
    for (int q = 0; q < 4; ++q) {
        const float gb = bias[(w*4 + q) * 16 + (l & 15)];
        #pragma unroll
        for (int m = 0; m < 4; ++m) acc[m][q] = (f32x4){gb, gb, gb, gb};
    }

    for (int s = 0; s < 8; ++s) {
        #pragma unroll
        for (int i = 0; i < 5; ++i) {
            const int e = t + i * 256;
            *(uint4*)&B_lds[e * 8] = *(const uint4*)&img[(size_t)s * IMG_PER_KSTEP + e * 8];
        }
        __syncthreads();
        bf16x8 bf[4];
        #pragma unroll
        for (int q = 0; q < 4; ++q)
            bf[q] = *(const bf16x8*)&B_lds[((w*4 + q) * 16 + (l & 15)) * 40 + (l >> 4) * 8];
        #pragma unroll
        for (int m = 0; m < 4; ++m) {
            const int r = m * 16 + (l & 15);
            const bf16x8 af = *(const bf16x8*)&A_lds[((r * 256 + s * 32 + (l >> 4) * 8)) ^ ((r & 7) << 3)];
            #pragma unroll
            for (int q = 0; q < 4; ++q)
                acc[m][q] = __builtin_amdgcn_mfma_f32_16x16x32_bf16(af, bf[q], acc[m][q], 0, 0, 0);
        }
        __syncthreads();
    }

    #pragma unroll
    for (int q = 0; q < 4; ++q) {
        const int a = (w*4 + q) * 16 + (l & 15);
        #pragma unroll
        for (int m = 0; m < 4; ++m)
            #pragma unroll
            for (int j = 0; j < 4; ++j)
                out[(size_t)(p0 + m*16 + (l >> 4)*4 + j) * CC + a] = acc[m][q][j];
    }
}

// ---------------- K1 fallback: fp32 qkv ----------------
__global__ __launch_bounds__(256, 2) void qkv_kernel(
    const float* __restrict__ feat,
    const float* __restrict__ wq, const float* __restrict__ bq,
    const float* __restrict__ wk, const float* __restrict__ bk,
    const float* __restrict__ wv, const float* __restrict__ bv,
    float* __restrict__ oq, float* __restrict__ ok, float* __restrict__ ov)
{
    const float* W; const float* bias; float* out;
    if (blockIdx.y == 0)      { W = wq; bias = bq; out = oq; }
    else if (blockIdx.y == 1) { W = wk; bias = bk; out = ok; }
    else                      { W = wv; bias = bv; out = ov; }

    const int p0 = blockIdx.x * 64;
    const int t  = threadIdx.x;
    __shared__ __align__(16) float fs[64][65];

    float acc[64];
    #pragma unroll
    for (int p = 0; p < 64; ++p) acc[p] = 0.f;

    for (int it = 0; it < 4; ++it) {
        const int tp = t >> 2;
        #pragma unroll
        for (int q = 0; q < 4; ++q) {
            const int ch = (t & 3) + q * 4;
            float4 v = *(const float4*)&feat[(size_t)(p0 + tp) * CC + it * 64 + ch * 4];
            fs[tp][ch*4+0] = v.x; fs[tp][ch*4+1] = v.y; fs[tp][ch*4+2] = v.z; fs[tp][ch*4+3] = v.w;
        }
        __syncthreads();
        #pragma unroll 4
        for (int i = 0; i < 64; ++i) {
            const float w = W[(size_t)(it * 64 + i) * CC + t];
            #pragma unroll
            for (int p = 0; p < 64; ++p) acc[p] = fmaf(fs[p][i], w, acc[p]);
        }
        __syncthreads();
    }
    const float bv_ = bias[t];
    #pragma unroll
    for (int p = 0; p < 64; ++p) out[(size_t)(p0 + p) * CC + t] = acc[p] + bv_;
}

// ---------------- K2: KNN top-16 (16 queries x 16 chunks per block) ----------------
// Round-9 lesson: 512-block grid capped blocks/CU at 2 (grid-limited, not LDS).
// Now grid = 1024 blocks (4/CU), 256 candidates/thread (halved main loop).
// LDS 36.1KB: tile (8KB, main loop) aliases pl_* (live only after loop).
__global__ __launch_bounds__(256, 2) void knn_kernel(
    const float* __restrict__ xyz, int* __restrict__ idxout)
{
    const int t = threadIdx.x;
    const int q = t >> 4;                      // 0..15 query slot
    const int c = t & 15;                      // 0..15 chunk
    const int b = blockIdx.x >> 8;             // 256 blocks per batch
    const int n = ((blockIdx.x & 255) << 4) + q;
    const float* xb = xyz + (size_t)b * NN * 3;

    const float qx = xb[n*3+0], qy = xb[n*3+1], qz = xb[n*3+2];
    const float sqn = qx*qx + qy*qy + qz*qz;   // keep exact formula of prior rounds

    __shared__ __align__(16) unsigned char smem[36992];
    float4* tile = (float4*)smem;              // [512] during main loop
    float*  pl_d = (float*)smem;               // [(c*17+s)*17+q] after loop
    int*    pl_i = (int*)(smem + 18496);

    float bd[16]; int bi[16];
    #pragma unroll
    for (int s = 0; s < 16; ++s) { bd[s] = 1e30f; bi[s] = 0; }

    for (int t0 = 0; t0 < NN; t0 += 512) {
        #pragma unroll
        for (int r = 0; r < 2; ++r) {
            const int j = t + r * 256;
            const float x = xb[(t0 + j)*3 + 0];
            const float y = xb[(t0 + j)*3 + 1];
            const float z = xb[(t0 + j)*3 + 2];
            tile[j] = make_float4(x, y, z, x*x + y*y + z*z);
        }
        __syncthreads();
        for (int j0 = 0; j0 < 512; j0 += 16) {
            const int j = j0 + c;
            const float4 p = tile[j];
            const float d = sqn + p.w - 2.0f * (qx*p.x + qy*p.y + qz*p.z);
            if (d < bd[15]) {
                const int m = t0 + j;
                bool placed = false;
                #pragma unroll
                for (int s = 15; s > 0; --s) {
                    if (!placed) {
                        if (bd[s-1] > d) { bd[s] = bd[s-1]; bi[s] = bi[s-1]; }
                        else             { bd[s] = d; bi[s] = m; placed = true; }
                    }
                }
                if (!placed) { bd[0] = d; bi[0] = m; }
            }
        }
        __syncthreads();
    }

    // dump partial sorted lists (tile region no longer read)
    #pragma unroll
    for (int s = 0; s < 16; ++s) {
        pl_d[(c*17 + s)*17 + q] = bd[s];
        pl_i[(c*17 + s)*17 + q] = bi[s];
    }
    __syncthreads();

    // exact 16-way merge, one query per thread (threads 0..15)
    if (t < 16) {
        const int qq = t;
        float hd[16]; int hi[16]; int p[16];
        #pragma unroll
        for (int cc = 0; cc < 16; ++cc) {
            hd[cc] = pl_d[(cc*17)*17 + qq]; hi[cc] = pl_i[(cc*17)*17 + qq]; p[cc] = 1;
        }
        const int nq = ((blockIdx.x & 255) << 4) + qq;
        int* op = idxout + ((size_t)b * NN + nq) * KK;
        #pragma unroll
        for (int s = 0; s < 16; ++s) {
            float bdv = hd[0]; int biv = hi[0]; int bc = 0;
            #pragma unroll
            for (int cc = 1; cc < 16; ++cc) {
                const bool better = (hd[cc] < bdv) || (hd[cc] == bdv && hi[cc] < biv);
                if (better) { bdv = hd[cc]; biv = hi[cc]; bc = cc; }
            }
            op[s] = biv;
            #pragma unroll
            for (int cc = 0; cc < 16; ++cc) {
                if (bc == cc) {
                    const int pp = p[cc];
                    const bool ok = pp < 16;
                    hd[cc] = ok ? pl_d[(cc*17 + pp)*17 + qq] : 1e38f;
                    hi[cc] = ok ? pl_i[(cc*17 + pp)*17 + qq] : 0;
                    p[cc] = pp + 1;
                }
            }
        }
    }
}

// ---------------- K3: t = rel@d1_w + d1_b, bn_d stats ----------------
__global__ __launch_bounds__(256) void fc_delta_kernel(
    const float* __restrict__ xyz, const int* __restrict__ idx,
    const float* __restrict__ d1w, const float* __restrict__ d1b,
    float* __restrict__ t3, float* __restrict__ stats)
{
    const int g = blockIdx.x * 256 + threadIdx.x;
    const int b = g >> 16;
    const int rem = g & 65535;
    const int n = rem >> 4;
    const int mi = idx[g];
    const float* xb = xyz + (size_t)b * NN * 3;
    const float rx = xb[n*3+0] - xb[mi*3+0];
    const float ry = xb[n*3+1] - xb[mi*3+1];
    const float rz = xb[n*3+2] - xb[mi*3+2];
    float tv[3];
    #pragma unroll
    for (int j = 0; j < 3; ++j) {
        tv[j] = fmaf(rx, d1w[0*3+j], fmaf(ry, d1w[1*3+j], fmaf(rz, d1w[2*3+j], d1b[j])));
        t3[(size_t)g*3 + j] = tv[j];
    }
    const int lane = threadIdx.x & 63;
    #pragma unroll
    for (int j = 0; j < 3; ++j) {
        float s  = waveReduceAdd(tv[j]);
        float sq = waveReduceAdd(tv[j]*tv[j]);
        if (lane == 0) {
            atomicAdd(&stats[ST_BND_SUM + j], s);
            atomicAdd(&stats[ST_BND_SQ + j], sq);
        }
    }
}

// ---------------- finalize bn_d ----------------
__global__ void finalize_bnd(const float* __restrict__ stats,
                             const float* __restrict__ g, const float* __restrict__ b,
                             float* __restrict__ consts)
{
    const int t = threadIdx.x;
    if (t < 3) {
        const float m = stats[ST_BND_SUM + t] * MINVF;
        const float v = stats[ST_BND_SQ + t] * MINVF - m * m;
        const float s = g[t] / sqrtf(v + EPSF);
        consts[CO_BND_S + t] = s;
        consts[CO_BND_B + t] = b[t] - m * s;
    }
}

// ---------------- K5: g_bn1 stats ----------------
__global__ __launch_bounds__(256, 2) void bn1_stats_kernel(
    const float* __restrict__ qproj, const float* __restrict__ kproj,
    const float* __restrict__ t3, const int* __restrict__ idx,
    const float* __restrict__ consts,
    const float* __restrict__ d2w, const float* __restrict__ d2b,
    float* __restrict__ stats)
{
    const int b   = blockIdx.x >> 8;
    const int pt0 = (blockIdx.x & 255) * 16;
    const int t = threadIdx.x;

    __shared__ float a3[768];
    __shared__ int idxs[256];

    const float bs[3]  = {consts[CO_BND_S+0], consts[CO_BND_S+1], consts[CO_BND_S+2]};
    const float bsh[3] = {consts[CO_BND_B+0], consts[CO_BND_B+1], consts[CO_BND_B+2]};
    const float* t3b = t3 + (size_t)(b * NN + pt0) * KK * 3;
    #pragma unroll
    for (int q = 0; q < 3; ++q) {
        const int f = t + q * 256;
        const int j = f % 3;
        a3[f] = fmaxf(fmaf(t3b[f], bs[j], bsh[j]), 0.f);
    }
    idxs[t] = idx[(size_t)(b * NN + pt0) * KK + t];
    __syncthreads();

    const int c = t;
    const float d20 = d2w[c], d21 = d2w[CC + c], d22 = d2w[2*CC + c], d2bc = d2b[c];
    float s = 0.f, sq = 0.f;
    for (int p = 0; p < 16; ++p) {
        const float qv = qproj[(size_t)(b * NN + pt0 + p) * CC + c];
        #pragma unroll
        for (int k = 0; k < 16; ++k) {
            const int mi = idxs[p*16 + k];
            const float kv = kproj[((size_t)b * NN + mi) * CC + c];
            const int f = (p*16 + k) * 3;
            const float pe = fmaf(a3[f], d20, fmaf(a3[f+1], d21, fmaf(a3[f+2], d22, d2bc)));
            const float h = qv - kv + pe;
            s += h; sq = fmaf(h, h, sq);
        }
    }
    atomicAdd(&stats[ST_G1_SUM + c], s);
    atomicAdd(&stats[ST_G1_SQ + c], sq);
}

// ---------------- finalize g_bn ----------------
__global__ void finalize_g(const float* __restrict__ ssum, const float* __restrict__ ssq,
                           const float* __restrict__ g, const float* __restrict__ b,
                           float* __restrict__ os, float* __restrict__ ob)
{
    const int c = threadIdx.x;
    const float m = ssum[c] * MINVF;
    const float v = ssq[c] * MINVF - m * m;
    const float s = g[c] / sqrtf(v + EPSF);
    os[c] = s;
    ob[c] = b[c] - m * s;
}

// ---------------- prep: transpose 5 weight matrices to bf16 image layout ----------------
__global__ __launch_bounds__(256) void prep_weights(
    const float* __restrict__ wq, const float* __restrict__ wk,
    const float* __restrict__ wv, const float* __restrict__ g1w,
    const float* __restrict__ g2w, u16* __restrict__ img_all)
{
    const int s = blockIdx.x;
    const int mat = blockIdx.y;
    const float* W = mat == 0 ? wq : mat == 1 ? wk : mat == 2 ? wv : mat == 3 ? g1w : g2w;
    u16* img = img_all + (size_t)mat * IMG_TOTAL + (size_t)s * IMG_PER_KSTEP;
    const int n = threadIdx.x;
    #pragma unroll
    for (int i = 0; i < 32; ++i) {
        img[n*40 + i] = f2bf(W[(size_t)(s*32 + i) * AA + n]);
    }
}

// ---------------- K7': stage3 MFMA ----------------
__global__ __launch_bounds__(256, 2) void stage3_mfma(
    const float* __restrict__ qproj, const float* __restrict__ kproj,
    const float* __restrict__ t3, const int* __restrict__ idx,
    const float* __restrict__ consts, float* __restrict__ stats,
    const float* __restrict__ d2w, const float* __restrict__ d2b,
    const u16* __restrict__ g1img, const float* __restrict__ g1b,
    __hip_bfloat16* __restrict__ h2)
{
    const int t = threadIdx.x;
    const int l = t & 63, w = t >> 6;
    const int pt0 = blockIdx.x * WPB;
    const int bI = pt0 >> 12;

    __shared__ __align__(16) u16 A_lds[MROWS * 256];
    __shared__ __align__(16) u16 B_lds[IMG_PER_KSTEP];
    __shared__ int   idxs[MROWS];
    __shared__ float a3s[MROWS * 3];

    if (t < MROWS) idxs[t] = idx[(size_t)pt0 * KK + t];
    if (t < MROWS * 3) {
        const int j = t % 3;
        a3s[t] = fmaxf(fmaf(t3[(size_t)pt0 * 48 + t], consts[CO_BND_S + j], consts[CO_BND_B + j]), 0.f);
    }
    __syncthreads();

    {
        const float d20 = d2w[t], d21 = d2w[CC + t], d22 = d2w[2*CC + t], d2bc = d2b[t];
        const float g1s = consts[CO_G1_S + t], g1sh = consts[CO_G1_B + t];
        float qv[WPB];
        #pragma unroll
        for (int p = 0; p < WPB; ++p) qv[p] = qproj[(size_t)(pt0 + p) * CC + t];
        for (int r = 0; r < MROWS; ++r) {
            const int mi = idxs[r];
            const float kv = kproj[((size_t)bI * NN + mi) * CC + t];
            const float pe = fmaf(a3s[r*3], d20, fmaf(a3s[r*3+1], d21, fmaf(a3s[r*3+2], d22, d2bc)));
            const float h = qv[r >> 4] - kv + pe;
            const float av = fmaxf(fmaf(h, g1s, g1sh), 0.f);
            A_lds[(r * 256 + t) ^ ((r & 7) << 3)] = f2bf(av);
        }
    }
    __syncthreads();

    f32x4 acc[4][4];
    #pragma unroll
    for (int q = 0; q < 4; ++q) {
        const float gb = g1b[(w*4 + q) * 16 + (l & 15)];
        #pragma unroll
        for (int m = 0; m < 4; ++m) acc[m][q] = (f32x4){gb, gb, gb, gb};
    }

    for (int s = 0; s < 8; ++s) {
        #pragma unroll
        for (int i = 0; i < 5; ++i) {
            const int e = t + i * 256;
            *(uint4*)&B_lds[e * 8] = *(const uint4*)&g1img[(size_t)s * IMG_PER_KSTEP + e * 8];
        }
        __syncthreads();
        bf16x8 bf[4];
        #pragma unroll
        for (int q = 0; q < 4; ++q)
            bf[q] = *(const bf16x8*)&B_lds[((w*4 + q) * 16 + (l & 15)) * 40 + (l >> 4) * 8];
        #pragma unroll
        for (int m = 0; m < 4; ++m) {
            const int r = m * 16 + (l & 15);
            const bf16x8 af = *(const bf16x8*)&A_lds[((r * 256 + s * 32 + (l >> 4) * 8)) ^ ((r & 7) << 3)];
            #pragma unroll
            for (int q = 0; q < 4; ++q)
                acc[m][q] = __builtin_amdgcn_mfma_f32_16x16x32_bf16(af, bf[q], acc[m][q], 0, 0, 0);
        }
        __syncthreads();
    }

    #pragma unroll
    for (int q = 0; q < 4; ++q) {
        const int a = (w*4 + q) * 16 + (l & 15);
        float sc = 0.f, sq = 0.f;
        #pragma unroll
        for (int m = 0; m < 4; ++m) {
            #pragma unroll
            for (int j = 0; j < 4; ++j) {
                const float v = acc[m][q][j];
                sc += v; sq = fmaf(v, v, sq);
                h2[((size_t)(pt0 + m) * KK + ((l >> 4) * 4 + j)) * AA + a] = __float2bfloat16(v);
            }
        }
        sc += __shfl_xor(sc, 16); sc += __shfl_xor(sc, 32);
        sq += __shfl_xor(sq, 16); sq += __shfl_xor(sq, 32);
        if (l < 16) {
            atomicAdd(&stats[ST_G2_SUM + a], sc);
            atomicAdd(&stats[ST_G2_SQ + a], sq);
        }
    }
}

// ---------------- K9': stage4 MFMA ----------------
__global__ __launch_bounds__(256, 2) void stage4_mfma(
    const float* __restrict__ vproj,
    const float* __restrict__ t3, const int* __restrict__ idx,
    const float* __restrict__ consts,
    const float* __restrict__ d2w, const float* __restrict__ d2b,
    const u16* __restrict__ g2img, const float* __restrict__ g2b,
    const __hip_bfloat16* __restrict__ h2, float* __restrict__ out)
{
    const int t = threadIdx.x;
    const int l = t & 63, w = t >> 6;
    const int pt0 = blockIdx.x * WPB;
    const int bI = pt0 >> 12;

    __shared__ __align__(16) u16 A_lds[MROWS * 256];
    __shared__ __align__(16) u16 B_lds[IMG_PER_KSTEP];
    __shared__ int   idxs[MROWS];
    __shared__ float a3s[MROWS * 3];

    if (t < MROWS) idxs[t] = idx[(size_t)pt0 * KK + t];
    if (t < MROWS * 3) {
        const int j = t % 3;
        a3s[t] = fmaxf(fmaf(t3[(size_t)pt0 * 48 + t], consts[CO_BND_S + j], consts[CO_BND_B + j]), 0.f);
    }
    __syncthreads();

    {
        const float g2s = consts[CO_G2_S + t], g2sh = consts[CO_G2_B + t];
        for (int r = 0; r < MROWS; ++r) {
            const float hv = __bfloat162float(h2[((size_t)pt0 * KK + r) * AA + t]);
            const float av = fmaxf(fmaf(hv, g2s, g2sh), 0.f);
            A_lds[(r * 256 + t) ^ ((r & 7) << 3)] = f2bf(av);
        }
    }
    __syncthreads();

    f32x4 acc[4][4];
    #pragma unroll
    for (int q = 0; q < 4; ++q) {
        const float gb = g2b[(w*4 + q) * 16 + (l & 15)];
        #pragma unroll
        for (int m = 0; m < 4; ++m) acc[m][q] = (f32x4){gb, gb, gb, gb};
    }

    for (int s = 0; s < 8; ++s) {
        #pragma unroll
        for (int i = 0; i < 5; ++i) {
            const int e = t + i * 256;
            *(uint4*)&B_lds[e * 8] = *(const uint4*)&g2img[(size_t)s * IMG_PER_KSTEP + e * 8];
        }
        __syncthreads();
        bf16x8 bf[4];
        #pragma unroll
        for (int q = 0; q < 4; ++q)
            bf[q] = *(const bf16x8*)&B_lds[((w*4 + q) * 16 + (l & 15)) * 40 + (l >> 4) * 8];
        #pragma unroll
        for (int m = 0; m < 4; ++m) {
            const int r = m * 16 + (l & 15);
            const bf16x8 af = *(const bf16x8*)&A_lds[((r * 256 + s * 32 + (l >> 4) * 8)) ^ ((r & 7) << 3)];
            #pragma unroll
            for (int q = 0; q < 4; ++q)
                acc[m][q] = __builtin_amdgcn_mfma_f32_16x16x32_bf16(af, bf[q], acc[m][q], 0, 0, 0);
        }
        __syncthreads();
    }

    #pragma unroll
    for (int q = 0; q < 4; ++q) {
        const int a = (w*4 + q) * 16 + (l & 15);
        const float dw0 = d2w[a], dw1 = d2w[CC + a], dw2 = d2w[2*CC + a], db = d2b[a];
        #pragma unroll
        for (int m = 0; m < 4; ++m) {
            f32x4 lg = acc[m][q];
            float mx = fmaxf(fmaxf(lg[0], lg[1]), fmaxf(lg[2], lg[3]));
            mx = fmaxf(mx, __shfl_xor(mx, 16));
            mx = fmaxf(mx, __shfl_xor(mx, 32));
            float e[4]; float ss = 0.f;
            #pragma unroll
            for (int j = 0; j < 4; ++j) { e[j] = expf(lg[j] - mx); ss += e[j]; }
            ss += __shfl_xor(ss, 16); ss += __shfl_xor(ss, 32);
            const float inv = 1.0f / ss;
            float part = 0.f;
            #pragma unroll
            for (int j = 0; j < 4; ++j) {
                const int kk = (l >> 4) * 4 + j;
                const int mi = idxs[m * 16 + kk];
                const float vv = vproj[((size_t)bI * NN + mi) * CC + a];
                const float pe = fmaf(a3s[(m*16+kk)*3], dw0,
                                 fmaf(a3s[(m*16+kk)*3+1], dw1,
                                 fmaf(a3s[(m*16+kk)*3+2], dw2, db)));
                part = fmaf(e[j] * inv, vv + pe, part);
            }
            part += __shfl_xor(part, 16); part += __shfl_xor(part, 32);
            if (l < 16) out[(size_t)(pt0 + m) * CC + a] = part;
        }
    }
}

// ---------------- fallback fp32 kernels (ws too small) ----------------
__global__ __launch_bounds__(256, 2) void stage3_fp32(
    const float* __restrict__ qproj, const float* __restrict__ kproj,
    const float* __restrict__ t3, const int* __restrict__ idx,
    const float* __restrict__ consts, float* __restrict__ stats,
    const float* __restrict__ d2w, const float* __restrict__ d2b,
    const float* __restrict__ g1w, const float* __restrict__ g1b)
{
    const size_t pt = blockIdx.x;
    const int b = (int)(pt >> 12);
    const int t = threadIdx.x;
    __shared__ float a3[48];
    __shared__ int idxs[16];
    __shared__ __align__(16) float hr[16][256];
    if (t < 48) {
        const int j = t % 3;
        a3[t] = fmaxf(fmaf(t3[pt*48 + t], consts[CO_BND_S + j], consts[CO_BND_B + j]), 0.f);
    }
    if (t < 16) idxs[t] = idx[pt*16 + t];
    __syncthreads();
    {
        const float d20 = d2w[t], d21 = d2w[CC + t], d22 = d2w[2*CC + t], d2bc = d2b[t];
        const float g1s = consts[CO_G1_S + t], g1sh = consts[CO_G1_B + t];
        const float qv = qproj[pt * CC + t];
        #pragma unroll
        for (int k = 0; k < 16; ++k) {
            const int mi = idxs[k];
            const float kv = kproj[((size_t)b * NN + mi) * CC + t];
            const float pe = fmaf(a3[k*3], d20, fmaf(a3[k*3+1], d21, fmaf(a3[k*3+2], d22, d2bc)));
            hr[k][t] = fmaxf(fmaf(qv - kv + pe, g1s, g1sh), 0.f);
        }
    }
    __syncthreads();
    float acc[16];
    const float gb = g1b[t];
    #pragma unroll
    for (int k = 0; k < 16; ++k) acc[k] = gb;
    #pragma unroll 4
    for (int c4 = 0; c4 < 64; ++c4) {
        const float* wp = g1w + (size_t)(c4*4) * AA + t;
        const float w0 = wp[0], w1 = wp[AA], w2 = wp[2*AA], w3 = wp[3*AA];
        #pragma unroll
        for (int k = 0; k < 16; ++k) {
            const float4 hv = *(const float4*)&hr[k][c4*4];
            acc[k] = fmaf(hv.x, w0, fmaf(hv.y, w1, fmaf(hv.z, w2, fmaf(hv.w, w3, acc[k]))));
        }
    }
    float s = 0.f, sq = 0.f;
    #pragma unroll
    for (int k = 0; k < 16; ++k) { s += acc[k]; sq = fmaf(acc[k], acc[k], sq); }
    atomicAdd(&stats[ST_G2_SUM + t], s);
    atomicAdd(&stats[ST_G2_SQ + t], sq);
}

__global__ __launch_bounds__(256, 2) void stage4_fp32(
    const float* __restrict__ qproj, const float* __restrict__ kproj,
    const float* __restrict__ vproj,
    const float* __restrict__ t3, const int* __restrict__ idx,
    const float* __restrict__ consts,
    const float* __restrict__ d2w, const float* __restrict__ d2b,
    const float* __restrict__ g1w, const float* __restrict__ g1b,
    const float* __restrict__ g2w, const float* __restrict__ g2b,
    float* __restrict__ out)
{
    const size_t pt = blockIdx.x;
    const int b = (int)(pt >> 12);
    const int t = threadIdx.x;
    __shared__ float a3[48];
    __shared__ int idxs[16];
    __shared__ __align__(16) float r2[16][256];
    if (t < 48) {
        const int j = t % 3;
        a3[t] = fmaxf(fmaf(t3[pt*48 + t], consts[CO_BND_S + j], consts[CO_BND_B + j]), 0.f);
    }
    if (t < 16) idxs[t] = idx[pt*16 + t];
    __syncthreads();
    const float g2s = consts[CO_G2_S + t], g2sh = consts[CO_G2_B + t];
    {
        __shared__ __align__(16) float hr[16][256];
        {
            const float d20 = d2w[t], d21 = d2w[CC + t], d22 = d2w[2*CC + t], d2bc = d2b[t];
            const float g1s = consts[CO_G1_S + t], g1sh = consts[CO_G1_B + t];
            const float qv = qproj[pt * CC + t];
            #pragma unroll
            for (int k = 0; k < 16; ++k) {
                const int mi = idxs[k];
                const float kv = kproj[((size_t)b * NN + mi) * CC + t];
                const float pe = fmaf(a3[k*3], d20, fmaf(a3[k*3+1], d21, fmaf(a3[k*3+2], d22, d2bc)));
                hr[k][t] = fmaxf(fmaf(qv - kv + pe, g1s, g1sh), 0.f);
            }
        }
        __syncthreads();
        float acc[16];
        const float gb = g1b[t];
        #pragma unroll
        for (int k = 0; k < 16; ++k) acc[k] = gb;
        #pragma unroll 4
        for (int c4 = 0; c4 < 64; ++c4) {
            const float* wp = g1w + (size_t)(c4*4) * AA + t;
            const float w0 = wp[0], w1 = wp[AA], w2 = wp[2*AA], w3 = wp[3*AA];
            #pragma unroll
            for (int k = 0; k < 16; ++k) {
                const float4 hv = *(const float4*)&hr[k][c4*4];
                acc[k] = fmaf(hv.x, w0, fmaf(hv.y, w1, fmaf(hv.z, w2, fmaf(hv.w, w3, acc[k]))));
            }
        }
        __syncthreads();
        #pragma unroll
        for (int k = 0; k < 16; ++k) r2[k][t] = fmaxf(fmaf(acc[k], g2s, g2sh), 0.f);
        __syncthreads();
    }
    float lg[16];
    const float gb2 = g2b[t];
    #pragma unroll
    for (int k = 0; k < 16; ++k) lg[k] = gb2;
    #pragma unroll 4
    for (int c4 = 0; c4 < 64; ++c4) {
        const float* wp = g2w + (size_t)(c4*4) * AA + t;
        const float w0 = wp[0], w1 = wp[AA], w2 = wp[2*AA], w3 = wp[3*AA];
        #pragma unroll
        for (int k = 0; k < 16; ++k) {
            const float4 hv = *(const float4*)&r2[k][c4*4];
            lg[k] = fmaf(hv.x, w0, fmaf(hv.y, w1, fmaf(hv.z, w2, fmaf(hv.w, w3, lg[k]))));
        }
    }
    float mx = lg[0];
    #pragma unroll
    for (int k = 1; k < 16; ++k) mx = fmaxf(mx, lg[k]);
    float sum = 0.f;
    #pragma unroll
    for (int k = 0; k < 16; ++k) { lg[k] = expf(lg[k] - mx); sum += lg[k]; }
    const float inv = 1.0f / sum;
    const float d20 = d2w[t], d21 = d2w[CC + t], d22 = d2w[2*CC + t], d2bc = d2b[t];
    float o = 0.f;
    #pragma unroll
    for (int k = 0; k < 16; ++k) {
        const int mi = idxs[k];
        const float vv = vproj[((size_t)b * NN + mi) * CC + t];
        const float pe = fmaf(a3[k*3], d20, fmaf(a3[k*3+1], d21, fmaf(a3[k*3+2], d22, d2bc)));
        o = fmaf(vv + pe, lg[k] * inv, o);
    }
    out[pt * CC + t] = o;
}

// ---------------- host ----------------
extern "C" void kernel_launch(void* const* d_in, const int* in_sizes, int n_in,
                              void* d_out, int out_size, void* d_ws, size_t ws_size,
                              hipStream_t stream)
{
    const float* xyz   = (const float*)d_in[0];
    const float* feat  = (const float*)d_in[1];
    const float* wq    = (const float*)d_in[2];
    const float* bq    = (const float*)d_in[3];
    const float* wk    = (const float*)d_in[4];
    const float* bk    = (const float*)d_in[5];
    const float* wv    = (const float*)d_in[6];
    const float* bv    = (const float*)d_in[7];
    const float* d1w   = (const float*)d_in[8];
    const float* d1b   = (const float*)d_in[9];
    const float* bndg  = (const float*)d_in[10];
    const float* bndb  = (const float*)d_in[11];
    const float* d2w   = (const float*)d_in[12];
    const float* d2b   = (const float*)d_in[13];
    const float* g1g   = (const float*)d_in[14];
    const float* g1bb  = (const float*)d_in[15];
    const float* g1w   = (const float*)d_in[16];
    const float* g1b   = (const float*)d_in[17];
    const float* g2g   = (const float*)d_in[18];
    const float* g2bb  = (const float*)d_in[19];
    const float* g2w   = (const float*)d_in[20];
    const float* g2b   = (const float*)d_in[21];
    float* out = (float*)d_out;

    // workspace layout
    float* qproj = (float*)d_ws;
    float* kproj = qproj + (size_t)NPTS * CC;
    float* vproj = kproj + (size_t)NPTS * CC;
    float* t3    = vproj + (size_t)NPTS * CC;
    float* stats = t3 + (size_t)BNKTOT * 3;
    float* consts = stats + 2048;
    int*   idxb  = (int*)(consts + 2048);
    u16*   wimg  = (u16*)(idxb + BNKTOT);          // 5 matrices: wq,wk,wv,g1w,g2w
    u16*   g1img = wimg + (size_t)3 * IMG_TOTAL;
    u16*   g2img = wimg + (size_t)4 * IMG_TOTAL;
    __hip_bfloat16* h2 = (__hip_bfloat16*)(wimg + (size_t)5 * IMG_TOTAL);
    const size_t need_store = (size_t)((char*)h2 - (char*)d_ws) + (size_t)BNKTOT * AA * 2;
    const bool store = ws_size >= need_store;

    hipMemsetAsync(stats, 0, 2048 * sizeof(float), stream);

    if (store) {
        prep_weights<<<dim3(8, 5), 256, 0, stream>>>(wq, wk, wv, g1w, g2w, wimg);
        qkv_mfma<<<dim3(NPTS / 64, 3), 256, 0, stream>>>(feat, wimg, bq, bk, bv,
                                                         qproj, kproj, vproj);
    } else {
        dim3 gq(NPTS / 64, 3);
        qkv_kernel<<<gq, 256, 0, stream>>>(feat, wq, bq, wk, bk, wv, bv, qproj, kproj, vproj);
    }

    knn_kernel<<<1024, 256, 0, stream>>>(xyz, idxb);

    fc_delta_kernel<<<BNKTOT / 256, 256, 0, stream>>>(xyz, idxb, d1w, d1b, t3, stats);

    finalize_bnd<<<1, 64, 0, stream>>>(stats, bndg, bndb, consts);

    bn1_stats_kernel<<<1024, 256, 0, stream>>>(qproj, kproj, t3, idxb, consts, d2w, d2b, stats);

    finalize_g<<<1, 256, 0, stream>>>(stats + ST_G1_SUM, stats + ST_G1_SQ, g1g, g1bb,
                                      consts + CO_G1_S, consts + CO_G1_B);

    if (store)
        stage3_mfma<<<NPTS / WPB, 256, 0, stream>>>(qproj, kproj, t3, idxb, consts, stats,
                                                    d2w, d2b, g1img, g1b, h2);
    else
        stage3_fp32<<<NPTS, 256, 0, stream>>>(qproj, kproj, t3, idxb, consts, stats,
                                              d2w, d2b, g1w, g1b);

    finalize_g<<<1, 256, 0, stream>>>(stats + ST_G2_SUM, stats + ST_G2_SQ, g2g, g2bb,
                                      consts + CO_G2_S, consts + CO_G2_B);

    if (store)
        stage4_mfma<<<NPTS / WPB, 256, 0, stream>>>(vproj, t3, idxb, consts,
                                                    d2w, d2b, g2img, g2b, h2, out);
    else
        stage4_fp32<<<NPTS, 256, 0, stream>>>(qproj, kproj, vproj, t3, idxb, consts,
                                              d2w, d2b, g1w, g1b, g2w, g2b, out);
}

// Round 11
// 992.842 us; speedup vs baseline: 6.7512x; 1.2554x over previous
//
#include <hip/hip_runtime.h>
#include <hip/hip_bf16.h>
#include <math.h>

#define BB 4
#define NN 4096
#define CC 256
#define KK 16
#define AA 256
#define NPTS (BB*NN)            // 16384
#define BNKTOT (NPTS*KK)        // 262144
#define EPSF 1e-5f
#define MINVF (1.0f/262144.0f)

#define WPB 4                    // points per MFMA block (stage3/4)
#define MROWS (WPB*KK)           // 64 rows
#define IMG_PER_KSTEP (256*40)   // ushorts: 256 n-rows x 40 (32 k + pad to 80B)
#define IMG_TOTAL (8*IMG_PER_KSTEP)

// stats / consts float offsets
#define ST_BND_SUM 0
#define ST_BND_SQ  8
#define ST_G1_SUM  16
#define ST_G1_SQ   272
#define ST_G2_SUM  528
#define ST_G2_SQ   784
#define CO_BND_S   0
#define CO_BND_B   4
#define CO_G1_S    16
#define CO_G1_B    272
#define CO_G2_S    528
#define CO_G2_B    784

typedef unsigned short u16;
typedef __attribute__((ext_vector_type(8))) short bf16x8;
typedef __attribute__((ext_vector_type(4))) float f32x4;

__device__ inline u16 f2bf(float x) {           // round-to-nearest-even bf16
    unsigned u = __float_as_uint(x);
    unsigned r = (u + 0x7FFFu + ((u >> 16) & 1u)) >> 16;
    return (u16)r;
}

__device__ inline float waveReduceAdd(float v) {
    #pragma unroll
    for (int o = 32; o > 0; o >>= 1) v += __shfl_down(v, o);
    return v;
}

__device__ inline bool lexlt(float d1, int i1, float d2, int i2) {
    return (d1 < d2) || (d1 == d2 && i1 < i2);
}

// ---------------- K1': qkv MFMA — {q,k,v} = feat @ W + b ----------------
__global__ __launch_bounds__(256, 2) void qkv_mfma(
    const float* __restrict__ feat, const u16* __restrict__ wimg_all,
    const float* __restrict__ bq, const float* __restrict__ bk, const float* __restrict__ bv,
    float* __restrict__ oq, float* __restrict__ ok, float* __restrict__ ov)
{
    const int t = threadIdx.x;
    const int l = t & 63, w = t >> 6;
    const int p0 = blockIdx.x * 64;
    const u16* img = wimg_all + (size_t)blockIdx.y * IMG_TOTAL;
    const float* bias = blockIdx.y == 0 ? bq : (blockIdx.y == 1 ? bk : bv);
    float* out = blockIdx.y == 0 ? oq : (blockIdx.y == 1 ? ok : ov);

    __shared__ __align__(16) u16 A_lds[64 * 256];        // 32KB
    __shared__ __align__(16) u16 B_lds[IMG_PER_KSTEP];   // 20KB

    for (int r = 0; r < 64; ++r)
        A_lds[(r * 256 + t) ^ ((r & 7) << 3)] = f2bf(feat[(size_t)(p0 + r) * CC + t]);
    __syncthreads();

    f32x4 acc[4][4];
    #pragma unroll
    for (int q = 0; q < 4; ++q) {
        const float gb = bias[(w*4 + q) * 16 + (l & 15)];
        #pragma unroll
        for (int m = 0; m < 4; ++m) acc[m][q] = (f32x4){gb, gb, gb, gb};
    }

    for (int s = 0; s < 8; ++s) {
        #pragma unroll
        for (int i = 0; i < 5; ++i) {
            const int e = t + i * 256;
            *(uint4*)&B_lds[e * 8] = *(const uint4*)&img[(size_t)s * IMG_PER_KSTEP + e * 8];
        }
        __syncthreads();
        bf16x8 bf[4];
        #pragma unroll
        for (int q = 0; q < 4; ++q)
            bf[q] = *(const bf16x8*)&B_lds[((w*4 + q) * 16 + (l & 15)) * 40 + (l >> 4) * 8];
        #pragma unroll
        for (int m = 0; m < 4; ++m) {
            const int r = m * 16 + (l & 15);
            const bf16x8 af = *(const bf16x8*)&A_lds[((r * 256 + s * 32 + (l >> 4) * 8)) ^ ((r & 7) << 3)];
            #pragma unroll
            for (int q = 0; q < 4; ++q)
                acc[m][q] = __builtin_amdgcn_mfma_f32_16x16x32_bf16(af, bf[q], acc[m][q], 0, 0, 0);
        }
        __syncthreads();
    }

    #pragma unroll
    for (int q = 0; q < 4; ++q) {
        const int a = (w*4 + q) * 16 + (l & 15);
        #pragma unroll
        for (int m = 0; m < 4; ++m)
            #pragma unroll
            for (int j = 0; j < 4; ++j)
                out[(size_t)(p0 + m*16 + (l >> 4)*4 + j) * CC + a] = acc[m][q][j];
    }
}

// ---------------- K1 fallback: fp32 qkv ----------------
__global__ __launch_bounds__(256, 2) void qkv_kernel(
    const float* __restrict__ feat,
    const float* __restrict__ wq, const float* __restrict__ bq,
    const float* __restrict__ wk, const float* __restrict__ bk,
    const float* __restrict__ wv, const float* __restrict__ bv,
    float* __restrict__ oq, float* __restrict__ ok, float* __restrict__ ov)
{
    const float* W; const float* bias; float* out;
    if (blockIdx.y == 0)      { W = wq; bias = bq; out = oq; }
    else if (blockIdx.y == 1) { W = wk; bias = bk; out = ok; }
    else                      { W = wv; bias = bv; out = ov; }

    const int p0 = blockIdx.x * 64;
    const int t  = threadIdx.x;
    __shared__ __align__(16) float fs[64][65];

    float acc[64];
    #pragma unroll
    for (int p = 0; p < 64; ++p) acc[p] = 0.f;

    for (int it = 0; it < 4; ++it) {
        const int tp = t >> 2;
        #pragma unroll
        for (int q = 0; q < 4; ++q) {
            const int ch = (t & 3) + q * 4;
            float4 v = *(const float4*)&feat[(size_t)(p0 + tp) * CC + it * 64 + ch * 4];
            fs[tp][ch*4+0] = v.x; fs[tp][ch*4+1] = v.y; fs[tp][ch*4+2] = v.z; fs[tp][ch*4+3] = v.w;
        }
        __syncthreads();
        #pragma unroll 4
        for (int i = 0; i < 64; ++i) {
            const float w = W[(size_t)(it * 64 + i) * CC + t];
            #pragma unroll
            for (int p = 0; p < 64; ++p) acc[p] = fmaf(fs[p][i], w, acc[p]);
        }
        __syncthreads();
    }
    const float bv_ = bias[t];
    #pragma unroll
    for (int p = 0; p < 64; ++p) out[(size_t)(p0 + p) * CC + t] = acc[p] + bv_;
}

// ---------------- K2: KNN top-16 — wave-select with shared threshold ----------------
// One wave per query (4 queries/block, grid 4096). The wave keeps ONE exact
// top-16 (lanes 0..15 hold the sorted list) + a wave-uniform (kd,ki) boundary.
// Candidates beating the boundary are ballot-appended to a 48-slot LDS buffer;
// flush = 64-lane bitonic sort of list+buffer by (d,idx), tightening the
// boundary. Expected accepts ~16*ln(4096/16)=89/query -> ~4 flushes, vs the
// old scheme's 256 wave-wide divergent 16-deep insertions (the 401us cost).
#define KNN_BUFCAP 48
__global__ __launch_bounds__(256) void knn_kernel(
    const float* __restrict__ xyz, int* __restrict__ idxout)
{
    const int t = threadIdx.x;
    const int l = t & 63;
    const int w = t >> 6;
    const int g = blockIdx.x * 4 + w;          // global query id
    const int b = g >> 12;
    const int n = g & 4095;
    const float* xb = xyz + (size_t)b * NN * 3;

    const float qx = xb[n*3+0], qy = xb[n*3+1], qz = xb[n*3+2];
    const float sqn = qx*qx + qy*qy + qz*qz;

    __shared__ float4 tile[512];
    __shared__ float bufd[4][KNN_BUFCAP];
    __shared__ int   bufi[4][KNN_BUFCAP];

    const float INF = 3.0e38f;
    float ld = INF; int li = 0x7fffffff;        // my sorted-list slot (lane<16)
    float kd = INF; int ki = 0x7fffffff;        // 16th-smallest boundary
    int cnt = 0;                                 // wave-uniform buffer count

    for (int t0 = 0; t0 < NN; t0 += 512) {
        #pragma unroll
        for (int r = 0; r < 2; ++r) {
            const int j = t + r * 256;
            const float x = xb[(t0 + j)*3 + 0];
            const float y = xb[(t0 + j)*3 + 1];
            const float z = xb[(t0 + j)*3 + 2];
            tile[j] = make_float4(x, y, z, x*x + y*y + z*z);
        }
        __syncthreads();
        for (int j0 = 0; j0 < 512; j0 += 64) {
            const float4 p = tile[j0 + l];
            const float d = sqn + p.w - 2.0f * (qx*p.x + qy*p.y + qz*p.z);
            const int  ci = t0 + j0 + l;
            bool pass = lexlt(d, ci, kd, ki);
            while (__any(pass)) {
                const unsigned long long m = __ballot(pass);
                const int rank  = (int)__popcll(m & ((1ull << l) - 1ull));
                const int total = (int)__popcll(m);
                const int space = KNN_BUFCAP - cnt;
                if (pass && rank < space) {
                    bufd[w][cnt + rank] = d;
                    bufi[w][cnt + rank] = ci;
                    pass = false;
                }
                cnt += total < space ? total : space;
                if (__any(pass)) {
                    // FLUSH: bitonic sort list(16)+buffer(cnt) across 64 lanes
                    float sd; int si;
                    if (l < 16)            { sd = ld; si = li; }
                    else if (l - 16 < cnt) { sd = bufd[w][l-16]; si = bufi[w][l-16]; }
                    else                   { sd = INF; si = 0x7fffffff; }
                    #pragma unroll
                    for (int k = 2; k <= 64; k <<= 1) {
                        #pragma unroll
                        for (int jj = k >> 1; jj > 0; jj >>= 1) {
                            const float od = __shfl_xor(sd, jj);
                            const int   oi = __shfl_xor(si, jj);
                            const bool keepMin = (((l & jj) == 0) == ((l & k) == 0));
                            const bool oSm = lexlt(od, oi, sd, si);
                            if (keepMin ? oSm : !oSm) { sd = od; si = oi; }
                        }
                    }
                    ld = (l < 16) ? sd : INF;
                    li = (l < 16) ? si : 0x7fffffff;
                    kd = __shfl(sd, 15);
                    ki = __shfl(si, 15);
                    cnt = 0;
                    pass = pass && lexlt(d, ci, kd, ki);
                }
            }
        }
        __syncthreads();
    }

    if (cnt > 0) {   // final flush
        float sd; int si;
        if (l < 16)            { sd = ld; si = li; }
        else if (l - 16 < cnt) { sd = bufd[w][l-16]; si = bufi[w][l-16]; }
        else                   { sd = INF; si = 0x7fffffff; }
        #pragma unroll
        for (int k = 2; k <= 64; k <<= 1) {
            #pragma unroll
            for (int jj = k >> 1; jj > 0; jj >>= 1) {
                const float od = __shfl_xor(sd, jj);
                const int   oi = __shfl_xor(si, jj);
                const bool keepMin = (((l & jj) == 0) == ((l & k) == 0));
                const bool oSm = lexlt(od, oi, sd, si);
                if (keepMin ? oSm : !oSm) { sd = od; si = oi; }
            }
        }
        li = si;
    }
    if (l < 16) idxout[((size_t)b * NN + n) * KK + l] = li;
}

// ---------------- K3: t = rel@d1_w + d1_b, bn_d stats ----------------
__global__ __launch_bounds__(256) void fc_delta_kernel(
    const float* __restrict__ xyz, const int* __restrict__ idx,
    const float* __restrict__ d1w, const float* __restrict__ d1b,
    float* __restrict__ t3, float* __restrict__ stats)
{
    const int g = blockIdx.x * 256 + threadIdx.x;
    const int b = g >> 16;
    const int rem = g & 65535;
    const int n = rem >> 4;
    const int mi = idx[g];
    const float* xb = xyz + (size_t)b * NN * 3;
    const float rx = xb[n*3+0] - xb[mi*3+0];
    const float ry = xb[n*3+1] - xb[mi*3+1];
    const float rz = xb[n*3+2] - xb[mi*3+2];
    float tv[3];
    #pragma unroll
    for (int j = 0; j < 3; ++j) {
        tv[j] = fmaf(rx, d1w[0*3+j], fmaf(ry, d1w[1*3+j], fmaf(rz, d1w[2*3+j], d1b[j])));
        t3[(size_t)g*3 + j] = tv[j];
    }
    const int lane = threadIdx.x & 63;
    #pragma unroll
    for (int j = 0; j < 3; ++j) {
        float s  = waveReduceAdd(tv[j]);
        float sq = waveReduceAdd(tv[j]*tv[j]);
        if (lane == 0) {
            atomicAdd(&stats[ST_BND_SUM + j], s);
            atomicAdd(&stats[ST_BND_SQ + j], sq);
        }
    }
}

// ---------------- finalize bn_d ----------------
__global__ void finalize_bnd(const float* __restrict__ stats,
                             const float* __restrict__ g, const float* __restrict__ b,
                             float* __restrict__ consts)
{
    const int t = threadIdx.x;
    if (t < 3) {
        const float m = stats[ST_BND_SUM + t] * MINVF;
        const float v = stats[ST_BND_SQ + t] * MINVF - m * m;
        const float s = g[t] / sqrtf(v + EPSF);
        consts[CO_BND_S + t] = s;
        consts[CO_BND_B + t] = b[t] - m * s;
    }
}

// ---------------- K5: g_bn1 stats ----------------
__global__ __launch_bounds__(256, 2) void bn1_stats_kernel(
    const float* __restrict__ qproj, const float* __restrict__ kproj,
    const float* __restrict__ t3, const int* __restrict__ idx,
    const float* __restrict__ consts,
    const float* __restrict__ d2w, const float* __restrict__ d2b,
    float* __restrict__ stats)
{
    const int b   = blockIdx.x >> 8;
    const int pt0 = (blockIdx.x & 255) * 16;
    const int t = threadIdx.x;

    __shared__ float a3[768];
    __shared__ int idxs[256];

    const float bs[3]  = {consts[CO_BND_S+0], consts[CO_BND_S+1], consts[CO_BND_S+2]};
    const float bsh[3] = {consts[CO_BND_B+0], consts[CO_BND_B+1], consts[CO_BND_B+2]};
    const float* t3b = t3 + (size_t)(b * NN + pt0) * KK * 3;
    #pragma unroll
    for (int q = 0; q < 3; ++q) {
        const int f = t + q * 256;
        const int j = f % 3;
        a3[f] = fmaxf(fmaf(t3b[f], bs[j], bsh[j]), 0.f);
    }
    idxs[t] = idx[(size_t)(b * NN + pt0) * KK + t];
    __syncthreads();

    const int c = t;
    const float d20 = d2w[c], d21 = d2w[CC + c], d22 = d2w[2*CC + c], d2bc = d2b[c];
    float s = 0.f, sq = 0.f;
    for (int p = 0; p < 16; ++p) {
        const float qv = qproj[(size_t)(b * NN + pt0 + p) * CC + c];
        #pragma unroll
        for (int k = 0; k < 16; ++k) {
            const int mi = idxs[p*16 + k];
            const float kv = kproj[((size_t)b * NN + mi) * CC + c];
            const int f = (p*16 + k) * 3;
            const float pe = fmaf(a3[f], d20, fmaf(a3[f+1], d21, fmaf(a3[f+2], d22, d2bc)));
            const float h = qv - kv + pe;
            s += h; sq = fmaf(h, h, sq);
        }
    }
    atomicAdd(&stats[ST_G1_SUM + c], s);
    atomicAdd(&stats[ST_G1_SQ + c], sq);
}

// ---------------- finalize g_bn ----------------
__global__ void finalize_g(const float* __restrict__ ssum, const float* __restrict__ ssq,
                           const float* __restrict__ g, const float* __restrict__ b,
                           float* __restrict__ os, float* __restrict__ ob)
{
    const int c = threadIdx.x;
    const float m = ssum[c] * MINVF;
    const float v = ssq[c] * MINVF - m * m;
    const float s = g[c] / sqrtf(v + EPSF);
    os[c] = s;
    ob[c] = b[c] - m * s;
}

// ---------------- prep: transpose 5 weight matrices to bf16 image layout ----------------
__global__ __launch_bounds__(256) void prep_weights(
    const float* __restrict__ wq, const float* __restrict__ wk,
    const float* __restrict__ wv, const float* __restrict__ g1w,
    const float* __restrict__ g2w, u16* __restrict__ img_all)
{
    const int s = blockIdx.x;
    const int mat = blockIdx.y;
    const float* W = mat == 0 ? wq : mat == 1 ? wk : mat == 2 ? wv : mat == 3 ? g1w : g2w;
    u16* img = img_all + (size_t)mat * IMG_TOTAL + (size_t)s * IMG_PER_KSTEP;
    const int n = threadIdx.x;
    #pragma unroll
    for (int i = 0; i < 32; ++i) {
        img[n*40 + i] = f2bf(W[(size_t)(s*32 + i) * AA + n]);
    }
}

// ---------------- K7': stage3 MFMA ----------------
__global__ __launch_bounds__(256, 2) void stage3_mfma(
    const float* __restrict__ qproj, const float* __restrict__ kproj,
    const float* __restrict__ t3, const int* __restrict__ idx,
    const float* __restrict__ consts, float* __restrict__ stats,
    const float* __restrict__ d2w, const float* __restrict__ d2b,
    const u16* __restrict__ g1img, const float* __restrict__ g1b,
    __hip_bfloat16* __restrict__ h2)
{
    const int t = threadIdx.x;
    const int l = t & 63, w = t >> 6;
    const int pt0 = blockIdx.x * WPB;
    const int bI = pt0 >> 12;

    __shared__ __align__(16) u16 A_lds[MROWS * 256];
    __shared__ __align__(16) u16 B_lds[IMG_PER_KSTEP];
    __shared__ int   idxs[MROWS];
    __shared__ float a3s[MROWS * 3];

    if (t < MROWS) idxs[t] = idx[(size_t)pt0 * KK + t];
    if (t < MROWS * 3) {
        const int j = t % 3;
        a3s[t] = fmaxf(fmaf(t3[(size_t)pt0 * 48 + t], consts[CO_BND_S + j], consts[CO_BND_B + j]), 0.f);
    }
    __syncthreads();

    {
        const float d20 = d2w[t], d21 = d2w[CC + t], d22 = d2w[2*CC + t], d2bc = d2b[t];
        const float g1s = consts[CO_G1_S + t], g1sh = consts[CO_G1_B + t];
        float qv[WPB];
        #pragma unroll
        for (int p = 0; p < WPB; ++p) qv[p] = qproj[(size_t)(pt0 + p) * CC + t];
        for (int r = 0; r < MROWS; ++r) {
            const int mi = idxs[r];
            const float kv = kproj[((size_t)bI * NN + mi) * CC + t];
            const float pe = fmaf(a3s[r*3], d20, fmaf(a3s[r*3+1], d21, fmaf(a3s[r*3+2], d22, d2bc)));
            const float h = qv[r >> 4] - kv + pe;
            const float av = fmaxf(fmaf(h, g1s, g1sh), 0.f);
            A_lds[(r * 256 + t) ^ ((r & 7) << 3)] = f2bf(av);
        }
    }
    __syncthreads();

    f32x4 acc[4][4];
    #pragma unroll
    for (int q = 0; q < 4; ++q) {
        const float gb = g1b[(w*4 + q) * 16 + (l & 15)];
        #pragma unroll
        for (int m = 0; m < 4; ++m) acc[m][q] = (f32x4){gb, gb, gb, gb};
    }

    for (int s = 0; s < 8; ++s) {
        #pragma unroll
        for (int i = 0; i < 5; ++i) {
            const int e = t + i * 256;
            *(uint4*)&B_lds[e * 8] = *(const uint4*)&g1img[(size_t)s * IMG_PER_KSTEP + e * 8];
        }
        __syncthreads();
        bf16x8 bf[4];
        #pragma unroll
        for (int q = 0; q < 4; ++q)
            bf[q] = *(const bf16x8*)&B_lds[((w*4 + q) * 16 + (l & 15)) * 40 + (l >> 4) * 8];
        #pragma unroll
        for (int m = 0; m < 4; ++m) {
            const int r = m * 16 + (l & 15);
            const bf16x8 af = *(const bf16x8*)&A_lds[((r * 256 + s * 32 + (l >> 4) * 8)) ^ ((r & 7) << 3)];
            #pragma unroll
            for (int q = 0; q < 4; ++q)
                acc[m][q] = __builtin_amdgcn_mfma_f32_16x16x32_bf16(af, bf[q], acc[m][q], 0, 0, 0);
        }
        __syncthreads();
    }

    #pragma unroll
    for (int q = 0; q < 4; ++q) {
        const int a = (w*4 + q) * 16 + (l & 15);
        float sc = 0.f, sq = 0.f;
        #pragma unroll
        for (int m = 0; m < 4; ++m) {
            #pragma unroll
            for (int j = 0; j < 4; ++j) {
                const float v = acc[m][q][j];
                sc += v; sq = fmaf(v, v, sq);
                h2[((size_t)(pt0 + m) * KK + ((l >> 4) * 4 + j)) * AA + a] = __float2bfloat16(v);
            }
        }
        sc += __shfl_xor(sc, 16); sc += __shfl_xor(sc, 32);
        sq += __shfl_xor(sq, 16); sq += __shfl_xor(sq, 32);
        if (l < 16) {
            atomicAdd(&stats[ST_G2_SUM + a], sc);
            atomicAdd(&stats[ST_G2_SQ + a], sq);
        }
    }
}

// ---------------- K9': stage4 MFMA ----------------
__global__ __launch_bounds__(256, 2) void stage4_mfma(
    const float* __restrict__ vproj,
    const float* __restrict__ t3, const int* __restrict__ idx,
    const float* __restrict__ consts,
    const float* __restrict__ d2w, const float* __restrict__ d2b,
    const u16* __restrict__ g2img, const float* __restrict__ g2b,
    const __hip_bfloat16* __restrict__ h2, float* __restrict__ out)
{
    const int t = threadIdx.x;
    const int l = t & 63, w = t >> 6;
    const int pt0 = blockIdx.x * WPB;
    const int bI = pt0 >> 12;

    __shared__ __align__(16) u16 A_lds[MROWS * 256];
    __shared__ __align__(16) u16 B_lds[IMG_PER_KSTEP];
    __shared__ int   idxs[MROWS];
    __shared__ float a3s[MROWS * 3];

    if (t < MROWS) idxs[t] = idx[(size_t)pt0 * KK + t];
    if (t < MROWS * 3) {
        const int j = t % 3;
        a3s[t] = fmaxf(fmaf(t3[(size_t)pt0 * 48 + t], consts[CO_BND_S + j], consts[CO_BND_B + j]), 0.f);
    }
    __syncthreads();

    {
        const float g2s = consts[CO_G2_S + t], g2sh = consts[CO_G2_B + t];
        for (int r = 0; r < MROWS; ++r) {
            const float hv = __bfloat162float(h2[((size_t)pt0 * KK + r) * AA + t]);
            const float av = fmaxf(fmaf(hv, g2s, g2sh), 0.f);
            A_lds[(r * 256 + t) ^ ((r & 7) << 3)] = f2bf(av);
        }
    }
    __syncthreads();

    f32x4 acc[4][4];
    #pragma unroll
    for (int q = 0; q < 4; ++q) {
        const float gb = g2b[(w*4 + q) * 16 + (l & 15)];
        #pragma unroll
        for (int m = 0; m < 4; ++m) acc[m][q] = (f32x4){gb, gb, gb, gb};
    }

    for (int s = 0; s < 8; ++s) {
        #pragma unroll
        for (int i = 0; i < 5; ++i) {
            const int e = t + i * 256;
            *(uint4*)&B_lds[e * 8] = *(const uint4*)&g2img[(size_t)s * IMG_PER_KSTEP + e * 8];
        }
        __syncthreads();
        bf16x8 bf[4];
        #pragma unroll
        for (int q = 0; q < 4; ++q)
            bf[q] = *(const bf16x8*)&B_lds[((w*4 + q) * 16 + (l & 15)) * 40 + (l >> 4) * 8];
        #pragma unroll
        for (int m = 0; m < 4; ++m) {
            const int r = m * 16 + (l & 15);
            const bf16x8 af = *(const bf16x8*)&A_lds[((r * 256 + s * 32 + (l >> 4) * 8)) ^ ((r & 7) << 3)];
            #pragma unroll
            for (int q = 0; q < 4; ++q)
                acc[m][q] = __builtin_amdgcn_mfma_f32_16x16x32_bf16(af, bf[q], acc[m][q], 0, 0, 0);
        }
        __syncthreads();
    }

    #pragma unroll
    for (int q = 0; q < 4; ++q) {
        const int a = (w*4 + q) * 16 + (l & 15);
        const float dw0 = d2w[a], dw1 = d2w[CC + a], dw2 = d2w[2*CC + a], db = d2b[a];
        #pragma unroll
        for (int m = 0; m < 4; ++m) {
            f32x4 lg = acc[m][q];
            float mx = fmaxf(fmaxf(lg[0], lg[1]), fmaxf(lg[2], lg[3]));
            mx = fmaxf(mx, __shfl_xor(mx, 16));
            mx = fmaxf(mx, __shfl_xor(mx, 32));
            float e[4]; float ss = 0.f;
            #pragma unroll
            for (int j = 0; j < 4; ++j) { e[j] = expf(lg[j] - mx); ss += e[j]; }
            ss += __shfl_xor(ss, 16); ss += __shfl_xor(ss, 32);
            const float inv = 1.0f / ss;
            float part = 0.f;
            #pragma unroll
            for (int j = 0; j < 4; ++j) {
                const int kk = (l >> 4) * 4 + j;
                const int mi = idxs[m * 16 + kk];
                const float vv = vproj[((size_t)bI * NN + mi) * CC + a];
                const float pe = fmaf(a3s[(m*16+kk)*3], dw0,
                                 fmaf(a3s[(m*16+kk)*3+1], dw1,
                                 fmaf(a3s[(m*16+kk)*3+2], dw2, db)));
                part = fmaf(e[j] * inv, vv + pe, part);
            }
            part += __shfl_xor(part, 16); part += __shfl_xor(part, 32);
            if (l < 16) out[(size_t)(pt0 + m) * CC + a] = part;
        }
    }
}

// ---------------- fallback fp32 kernels (ws too small) ----------------
__global__ __launch_bounds__(256, 2) void stage3_fp32(
    const float* __restrict__ qproj, const float* __restrict__ kproj,
    const float* __restrict__ t3, const int* __restrict__ idx,
    const float* __restrict__ consts, float* __restrict__ stats,
    const float* __restrict__ d2w, const float* __restrict__ d2b,
    const float* __restrict__ g1w, const float* __restrict__ g1b)
{
    const size_t pt = blockIdx.x;
    const int b = (int)(pt >> 12);
    const int t = threadIdx.x;
    __shared__ float a3[48];
    __shared__ int idxs[16];
    __shared__ __align__(16) float hr[16][256];
    if (t < 48) {
        const int j = t % 3;
        a3[t] = fmaxf(fmaf(t3[pt*48 + t], consts[CO_BND_S + j], consts[CO_BND_B + j]), 0.f);
    }
    if (t < 16) idxs[t] = idx[pt*16 + t];
    __syncthreads();
    {
        const float d20 = d2w[t], d21 = d2w[CC + t], d22 = d2w[2*CC + t], d2bc = d2b[t];
        const float g1s = consts[CO_G1_S + t], g1sh = consts[CO_G1_B + t];
        const float qv = qproj[pt * CC + t];
        #pragma unroll
        for (int k = 0; k < 16; ++k) {
            const int mi = idxs[k];
            const float kv = kproj[((size_t)b * NN + mi) * CC + t];
            const float pe = fmaf(a3[k*3], d20, fmaf(a3[k*3+1], d21, fmaf(a3[k*3+2], d22, d2bc)));
            hr[k][t] = fmaxf(fmaf(qv - kv + pe, g1s, g1sh), 0.f);
        }
    }
    __syncthreads();
    float acc[16];
    const float gb = g1b[t];
    #pragma unroll
    for (int k = 0; k < 16; ++k) acc[k] = gb;
    #pragma unroll 4
    for (int c4 = 0; c4 < 64; ++c4) {
        const float* wp = g1w + (size_t)(c4*4) * AA + t;
        const float w0 = wp[0], w1 = wp[AA], w2 = wp[2*AA], w3 = wp[3*AA];
        #pragma unroll
        for (int k = 0; k < 16; ++k) {
            const float4 hv = *(const float4*)&hr[k][c4*4];
            acc[k] = fmaf(hv.x, w0, fmaf(hv.y, w1, fmaf(hv.z, w2, fmaf(hv.w, w3, acc[k]))));
        }
    }
    float s = 0.f, sq = 0.f;
    #pragma unroll
    for (int k = 0; k < 16; ++k) { s += acc[k]; sq = fmaf(acc[k], acc[k], sq); }
    atomicAdd(&stats[ST_G2_SUM + t], s);
    atomicAdd(&stats[ST_G2_SQ + t], sq);
}

__global__ __launch_bounds__(256, 2) void stage4_fp32(
    const float* __restrict__ qproj, const float* __restrict__ kproj,
    const float* __restrict__ vproj,
    const float* __restrict__ t3, const int* __restrict__ idx,
    const float* __restrict__ consts,
    const float* __restrict__ d2w, const float* __restrict__ d2b,
    const float* __restrict__ g1w, const float* __restrict__ g1b,
    const float* __restrict__ g2w, const float* __restrict__ g2b,
    float* __restrict__ out)
{
    const size_t pt = blockIdx.x;
    const int b = (int)(pt >> 12);
    const int t = threadIdx.x;
    __shared__ float a3[48];
    __shared__ int idxs[16];
    __shared__ __align__(16) float r2[16][256];
    if (t < 48) {
        const int j = t % 3;
        a3[t] = fmaxf(fmaf(t3[pt*48 + t], consts[CO_BND_S + j], consts[CO_BND_B + j]), 0.f);
    }
    if (t < 16) idxs[t] = idx[pt*16 + t];
    __syncthreads();
    const float g2s = consts[CO_G2_S + t], g2sh = consts[CO_G2_B + t];
    {
        __shared__ __align__(16) float hr[16][256];
        {
            const float d20 = d2w[t], d21 = d2w[CC + t], d22 = d2w[2*CC + t], d2bc = d2b[t];
            const float g1s = consts[CO_G1_S + t], g1sh = consts[CO_G1_B + t];
            const float qv = qproj[pt * CC + t];
            #pragma unroll
            for (int k = 0; k < 16; ++k) {
                const int mi = idxs[k];
                const float kv = kproj[((size_t)b * NN + mi) * CC + t];
                const float pe = fmaf(a3[k*3], d20, fmaf(a3[k*3+1], d21, fmaf(a3[k*3+2], d22, d2bc)));
                hr[k][t] = fmaxf(fmaf(qv - kv + pe, g1s, g1sh), 0.f);
            }
        }
        __syncthreads();
        float acc[16];
        const float gb = g1b[t];
        #pragma unroll
        for (int k = 0; k < 16; ++k) acc[k] = gb;
        #pragma unroll 4
        for (int c4 = 0; c4 < 64; ++c4) {
            const float* wp = g1w + (size_t)(c4*4) * AA + t;
            const float w0 = wp[0], w1 = wp[AA], w2 = wp[2*AA], w3 = wp[3*AA];
            #pragma unroll
            for (int k = 0; k < 16; ++k) {
                const float4 hv = *(const float4*)&hr[k][c4*4];
                acc[k] = fmaf(hv.x, w0, fmaf(hv.y, w1, fmaf(hv.z, w2, fmaf(hv.w, w3, acc[k]))));
            }
        }
        __syncthreads();
        #pragma unroll
        for (int k = 0; k < 16; ++k) r2[k][t] = fmaxf(fmaf(acc[k], g2s, g2sh), 0.f);
        __syncthreads();
    }
    float lg[16];
    const float gb2 = g2b[t];
    #pragma unroll
    for (int k = 0; k < 16; ++k) lg[k] = gb2;
    #pragma unroll 4
    for (int c4 = 0; c4 < 64; ++c4) {
        const float* wp = g2w + (size_t)(c4*4) * AA + t;
        const float w0 = wp[0], w1 = wp[AA], w2 = wp[2*AA], w3 = wp[3*AA];
        #pragma unroll
        for (int k = 0; k < 16; ++k) {
            const float4 hv = *(const float4*)&r2[k][c4*4];
            lg[k] = fmaf(hv.x, w0, fmaf(hv.y, w1, fmaf(hv.z, w2, fmaf(hv.w, w3, lg[k]))));
        }
    }
    float mx = lg[0];
    #pragma unroll
    for (int k = 1; k < 16; ++k) mx = fmaxf(mx, lg[k]);
    float sum = 0.f;
    #pragma unroll
    for (int k = 0; k < 16; ++k) { lg[k] = expf(lg[k] - mx); sum += lg[k]; }
    const float inv = 1.0f / sum;
    const float d20 = d2w[t], d21 = d2w[CC + t], d22 = d2w[2*CC + t], d2bc = d2b[t];
    float o = 0.f;
    #pragma unroll
    for (int k = 0; k < 16; ++k) {
        const int mi = idxs[k];
        const float vv = vproj[((size_t)b * NN + mi) * CC + t];
        const float pe = fmaf(a3[k*3], d20, fmaf(a3[k*3+1], d21, fmaf(a3[k*3+2], d22, d2bc)));
        o = fmaf(vv + pe, lg[k] * inv, o);
    }
    out[pt * CC + t] = o;
}

// ---------------- host ----------------
extern "C" void kernel_launch(void* const* d_in, const int* in_sizes, int n_in,
                              void* d_out, int out_size, void* d_ws, size_t ws_size,
                              hipStream_t stream)
{
    const float* xyz   = (const float*)d_in[0];
    const float* feat  = (const float*)d_in[1];
    const float* wq    = (const float*)d_in[2];
    const float* bq    = (const float*)d_in[3];
    const float* wk    = (const float*)d_in[4];
    const float* bk    = (const float*)d_in[5];
    const float* wv    = (const float*)d_in[6];
    const float* bv    = (const float*)d_in[7];
    const float* d1w   = (const float*)d_in[8];
    const float* d1b   = (const float*)d_in[9];
    const float* bndg  = (const float*)d_in[10];
    const float* bndb  = (const float*)d_in[11];
    const float* d2w   = (const float*)d_in[12];
    const float* d2b   = (const float*)d_in[13];
    const float* g1g   = (const float*)d_in[14];
    const float* g1bb  = (const float*)d_in[15];
    const float* g1w   = (const float*)d_in[16];
    const float* g1b   = (const float*)d_in[17];
    const float* g2g   = (const float*)d_in[18];
    const float* g2bb  = (const float*)d_in[19];
    const float* g2w   = (const float*)d_in[20];
    const float* g2b   = (const float*)d_in[21];
    float* out = (float*)d_out;

    // workspace layout
    float* qproj = (float*)d_ws;
    float* kproj = qproj + (size_t)NPTS * CC;
    float* vproj = kproj + (size_t)NPTS * CC;
    float* t3    = vproj + (size_t)NPTS * CC;
    float* stats = t3 + (size_t)BNKTOT * 3;
    float* consts = stats + 2048;
    int*   idxb  = (int*)(consts + 2048);
    u16*   wimg  = (u16*)(idxb + BNKTOT);          // 5 matrices: wq,wk,wv,g1w,g2w
    u16*   g1img = wimg + (size_t)3 * IMG_TOTAL;
    u16*   g2img = wimg + (size_t)4 * IMG_TOTAL;
    __hip_bfloat16* h2 = (__hip_bfloat16*)(wimg + (size_t)5 * IMG_TOTAL);
    const size_t need_store = (size_t)((char*)h2 - (char*)d_ws) + (size_t)BNKTOT * AA * 2;
    const bool store = ws_size >= need_store;

    hipMemsetAsync(stats, 0, 2048 * sizeof(float), stream);

    if (store) {
        prep_weights<<<dim3(8, 5), 256, 0, stream>>>(wq, wk, wv, g1w, g2w, wimg);
        qkv_mfma<<<dim3(NPTS / 64, 3), 256, 0, stream>>>(feat, wimg, bq, bk, bv,
                                                         qproj, kproj, vproj);
    } else {
        dim3 gq(NPTS / 64, 3);
        qkv_kernel<<<gq, 256, 0, stream>>>(feat, wq, bq, wk, bk, wv, bv, qproj, kproj, vproj);
    }

    knn_kernel<<<NPTS / 4, 256, 0, stream>>>(xyz, idxb);

    fc_delta_kernel<<<BNKTOT / 256, 256, 0, stream>>>(xyz, idxb, d1w, d1b, t3, stats);

    finalize_bnd<<<1, 64, 0, stream>>>(stats, bndg, bndb, consts);

    bn1_stats_kernel<<<1024, 256, 0, stream>>>(qproj, kproj, t3, idxb, consts, d2w, d2b, stats);

    finalize_g<<<1, 256, 0, stream>>>(stats + ST_G1_SUM, stats + ST_G1_SQ, g1g, g1bb,
                                      consts + CO_G1_S, consts + CO_G1_B);

    if (store)
        stage3_mfma<<<NPTS / WPB, 256, 0, stream>>>(qproj, kproj, t3, idxb, consts, stats,
                                                    d2w, d2b, g1img, g1b, h2);
    else
        stage3_fp32<<<NPTS, 256, 0, stream>>>(qproj, kproj, t3, idxb, consts, stats,
                                              d2w, d2b, g1w, g1b);

    finalize_g<<<1, 256, 0, stream>>>(stats + ST_G2_SUM, stats + ST_G2_SQ, g2g, g2bb,
                                      consts + CO_G2_S, consts + CO_G2_B);

    if (store)
        stage4_mfma<<<NPTS / WPB, 256, 0, stream>>>(vproj, t3, idxb, consts,
                                                    d2w, d2b, g2img, g2b, h2, out);
    else
        stage4_fp32<<<NPTS, 256, 0, stream>>>(qproj, kproj, vproj, t3, idxb, consts,
                                              d2w, d2b, g1w, g1b, g2w, g2b, out);
}

// Round 12
// 681.876 us; speedup vs baseline: 9.8300x; 1.4560x over previous
//
#include <hip/hip_runtime.h>
#include <hip/hip_bf16.h>
#include <math.h>

#define BB 4
#define NN 4096
#define CC 256
#define KK 16
#define AA 256
#define NPTS (BB*NN)            // 16384
#define BNKTOT (NPTS*KK)        // 262144
#define EPSF 1e-5f
#define MINVF (1.0f/262144.0f)

#define WPB 4                    // points per MFMA block (stage3/4)
#define MROWS (WPB*KK)           // 64 rows
#define IMG_PER_KSTEP (256*40)   // ushorts: 256 n-rows x 40 (32 k + pad to 80B)
#define IMG_TOTAL (8*IMG_PER_KSTEP)

// stats / consts float offsets
#define ST_BND_SUM 0
#define ST_BND_SQ  8
#define ST_G1_SUM  16
#define ST_G1_SQ   272
#define ST_G2_SUM  528
#define ST_G2_SQ   784
#define CO_BND_S   0
#define CO_BND_B   4
#define CO_G1_S    16
#define CO_G1_B    272
#define CO_G2_S    528
#define CO_G2_B    784

typedef unsigned short u16;
typedef __attribute__((ext_vector_type(8))) short bf16x8;
typedef __attribute__((ext_vector_type(4))) float f32x4;

__device__ inline u16 f2bf(float x) {           // round-to-nearest-even bf16
    unsigned u = __float_as_uint(x);
    unsigned r = (u + 0x7FFFu + ((u >> 16) & 1u)) >> 16;
    return (u16)r;
}

__device__ inline float waveReduceAdd(float v) {
    #pragma unroll
    for (int o = 32; o > 0; o >>= 1) v += __shfl_down(v, o);
    return v;
}

__device__ inline bool lexlt(float d1, int i1, float d2, int i2) {
    return (d1 < d2) || (d1 == d2 && i1 < i2);
}

// ---------------- K1': qkv MFMA — {q,k,v} = feat @ W + b ----------------
__global__ __launch_bounds__(256, 2) void qkv_mfma(
    const float* __restrict__ feat, const u16* __restrict__ wimg_all,
    const float* __restrict__ bq, const float* __restrict__ bk, const float* __restrict__ bv,
    float* __restrict__ oq, float* __restrict__ ok, float* __restrict__ ov)
{
    const int t = threadIdx.x;
    const int l = t & 63, w = t >> 6;
    const int p0 = blockIdx.x * 64;
    const u16* img = wimg_all + (size_t)blockIdx.y * IMG_TOTAL;
    const float* bias = blockIdx.y == 0 ? bq : (blockIdx.y == 1 ? bk : bv);
    float* out = blockIdx.y == 0 ? oq : (blockIdx.y == 1 ? ok : ov);

    __shared__ __align__(16) u16 A_lds[64 * 256];        // 32KB
    __shared__ __align__(16) u16 B_lds[IMG_PER_KSTEP];   // 20KB

    for (int r = 0; r < 64; ++r)
        A_lds[(r * 256 + t) ^ ((r & 7) << 3)] = f2bf(feat[(size_t)(p0 + r) * CC + t]);
    __syncthreads();

    f32x4 acc[4][4];
    #pragma unroll
    for (int q = 0; q < 4; ++q) {
        const float gb = bias[(w*4 + q) * 16 + (l & 15)];
        #pragma unroll
        for (int m = 0; m < 4; ++m) acc[m][q] = (f32x4){gb, gb, gb, gb};
    }

    for (int s = 0; s < 8; ++s) {
        #pragma unroll
        for (int i = 0; i < 5; ++i) {
            const int e = t + i * 256;
            *(uint4*)&B_lds[e * 8] = *(const uint4*)&img[(size_t)s * IMG_PER_KSTEP + e * 8];
        }
        __syncthreads();
        bf16x8 bf[4];
        #pragma unroll
        for (int q = 0; q < 4; ++q)
            bf[q] = *(const bf16x8*)&B_lds[((w*4 + q) * 16 + (l & 15)) * 40 + (l >> 4) * 8];
        #pragma unroll
        for (int m = 0; m < 4; ++m) {
            const int r = m * 16 + (l & 15);
            const bf16x8 af = *(const bf16x8*)&A_lds[((r * 256 + s * 32 + (l >> 4) * 8)) ^ ((r & 7) << 3)];
            #pragma unroll
            for (int q = 0; q < 4; ++q)
                acc[m][q] = __builtin_amdgcn_mfma_f32_16x16x32_bf16(af, bf[q], acc[m][q], 0, 0, 0);
        }
        __syncthreads();
    }

    #pragma unroll
    for (int q = 0; q < 4; ++q) {
        const int a = (w*4 + q) * 16 + (l & 15);
        #pragma unroll
        for (int m = 0; m < 4; ++m)
            #pragma unroll
            for (int j = 0; j < 4; ++j)
                out[(size_t)(p0 + m*16 + (l >> 4)*4 + j) * CC + a] = acc[m][q][j];
    }
}

// ---------------- K1 fallback: fp32 qkv ----------------
__global__ __launch_bounds__(256, 2) void qkv_kernel(
    const float* __restrict__ feat,
    const float* __restrict__ wq, const float* __restrict__ bq,
    const float* __restrict__ wk, const float* __restrict__ bk,
    const float* __restrict__ wv, const float* __restrict__ bv,
    float* __restrict__ oq, float* __restrict__ ok, float* __restrict__ ov)
{
    const float* W; const float* bias; float* out;
    if (blockIdx.y == 0)      { W = wq; bias = bq; out = oq; }
    else if (blockIdx.y == 1) { W = wk; bias = bk; out = ok; }
    else                      { W = wv; bias = bv; out = ov; }

    const int p0 = blockIdx.x * 64;
    const int t  = threadIdx.x;
    __shared__ __align__(16) float fs[64][65];

    float acc[64];
    #pragma unroll
    for (int p = 0; p < 64; ++p) acc[p] = 0.f;

    for (int it = 0; it < 4; ++it) {
        const int tp = t >> 2;
        #pragma unroll
        for (int q = 0; q < 4; ++q) {
            const int ch = (t & 3) + q * 4;
            float4 v = *(const float4*)&feat[(size_t)(p0 + tp) * CC + it * 64 + ch * 4];
            fs[tp][ch*4+0] = v.x; fs[tp][ch*4+1] = v.y; fs[tp][ch*4+2] = v.z; fs[tp][ch*4+3] = v.w;
        }
        __syncthreads();
        #pragma unroll 4
        for (int i = 0; i < 64; ++i) {
            const float w = W[(size_t)(it * 64 + i) * CC + t];
            #pragma unroll
            for (int p = 0; p < 64; ++p) acc[p] = fmaf(fs[p][i], w, acc[p]);
        }
        __syncthreads();
    }
    const float bv_ = bias[t];
    #pragma unroll
    for (int p = 0; p < 64; ++p) out[(size_t)(p0 + p) * CC + t] = acc[p] + bv_;
}

// ---------------- K2: KNN top-16 — wave-select with shared threshold ----------------
#define KNN_BUFCAP 48
__global__ __launch_bounds__(256) void knn_kernel(
    const float* __restrict__ xyz, int* __restrict__ idxout)
{
    const int t = threadIdx.x;
    const int l = t & 63;
    const int w = t >> 6;
    const int g = blockIdx.x * 4 + w;          // global query id
    const int b = g >> 12;
    const int n = g & 4095;
    const float* xb = xyz + (size_t)b * NN * 3;

    const float qx = xb[n*3+0], qy = xb[n*3+1], qz = xb[n*3+2];
    const float sqn = qx*qx + qy*qy + qz*qz;

    __shared__ float4 tile[512];
    __shared__ float bufd[4][KNN_BUFCAP];
    __shared__ int   bufi[4][KNN_BUFCAP];

    const float INF = 3.0e38f;
    float ld = INF; int li = 0x7fffffff;
    float kd = INF; int ki = 0x7fffffff;
    int cnt = 0;

    for (int t0 = 0; t0 < NN; t0 += 512) {
        #pragma unroll
        for (int r = 0; r < 2; ++r) {
            const int j = t + r * 256;
            const float x = xb[(t0 + j)*3 + 0];
            const float y = xb[(t0 + j)*3 + 1];
            const float z = xb[(t0 + j)*3 + 2];
            tile[j] = make_float4(x, y, z, x*x + y*y + z*z);
        }
        __syncthreads();
        for (int j0 = 0; j0 < 512; j0 += 64) {
            const float4 p = tile[j0 + l];
            const float d = sqn + p.w - 2.0f * (qx*p.x + qy*p.y + qz*p.z);
            const int  ci = t0 + j0 + l;
            bool pass = lexlt(d, ci, kd, ki);
            while (__any(pass)) {
                const unsigned long long m = __ballot(pass);
                const int rank  = (int)__popcll(m & ((1ull << l) - 1ull));
                const int total = (int)__popcll(m);
                const int space = KNN_BUFCAP - cnt;
                if (pass && rank < space) {
                    bufd[w][cnt + rank] = d;
                    bufi[w][cnt + rank] = ci;
                    pass = false;
                }
                cnt += total < space ? total : space;
                if (__any(pass)) {
                    float sd; int si;
                    if (l < 16)            { sd = ld; si = li; }
                    else if (l - 16 < cnt) { sd = bufd[w][l-16]; si = bufi[w][l-16]; }
                    else                   { sd = INF; si = 0x7fffffff; }
                    #pragma unroll
                    for (int k = 2; k <= 64; k <<= 1) {
                        #pragma unroll
                        for (int jj = k >> 1; jj > 0; jj >>= 1) {
                            const float od = __shfl_xor(sd, jj);
                            const int   oi = __shfl_xor(si, jj);
                            const bool keepMin = (((l & jj) == 0) == ((l & k) == 0));
                            const bool oSm = lexlt(od, oi, sd, si);
                            if (keepMin ? oSm : !oSm) { sd = od; si = oi; }
                        }
                    }
                    ld = (l < 16) ? sd : INF;
                    li = (l < 16) ? si : 0x7fffffff;
                    kd = __shfl(sd, 15);
                    ki = __shfl(si, 15);
                    cnt = 0;
                    pass = pass && lexlt(d, ci, kd, ki);
                }
            }
        }
        __syncthreads();
    }

    if (cnt > 0) {   // final flush
        float sd; int si;
        if (l < 16)            { sd = ld; si = li; }
        else if (l - 16 < cnt) { sd = bufd[w][l-16]; si = bufi[w][l-16]; }
        else                   { sd = INF; si = 0x7fffffff; }
        #pragma unroll
        for (int k = 2; k <= 64; k <<= 1) {
            #pragma unroll
            for (int jj = k >> 1; jj > 0; jj >>= 1) {
                const float od = __shfl_xor(sd, jj);
                const int   oi = __shfl_xor(si, jj);
                const bool keepMin = (((l & jj) == 0) == ((l & k) == 0));
                const bool oSm = lexlt(od, oi, sd, si);
                if (keepMin ? oSm : !oSm) { sd = od; si = oi; }
            }
        }
        li = si;
    }
    if (l < 16) idxout[((size_t)b * NN + n) * KK + l] = li;
}

// ---------------- K3: t = rel@d1_w + d1_b, bn_d stats ----------------
// Round-11 profile: VALUBusy 0.3%, HBM 0.2%, dur 314us -> pure serialization
// on 24576 fp32 atomics to ONE cacheline (6 per wave x 4096 waves).
// Now: 256 blocks x 256 threads x 4 elems; wave-reduce -> LDS block-reduce ->
// 6 atomics PER BLOCK (1536 total, 16x fewer).
__global__ __launch_bounds__(256) void fc_delta_kernel(
    const float* __restrict__ xyz, const int* __restrict__ idx,
    const float* __restrict__ d1w, const float* __restrict__ d1b,
    float* __restrict__ t3, float* __restrict__ stats)
{
    const int t = threadIdx.x;
    float s[3] = {0.f, 0.f, 0.f}, sq[3] = {0.f, 0.f, 0.f};

    #pragma unroll
    for (int it = 0; it < 4; ++it) {
        const int g = blockIdx.x * 1024 + it * 256 + t;
        const int b = g >> 16;
        const int n = (g & 65535) >> 4;
        const int mi = idx[g];
        const float* xb = xyz + (size_t)b * NN * 3;
        const float rx = xb[n*3+0] - xb[mi*3+0];
        const float ry = xb[n*3+1] - xb[mi*3+1];
        const float rz = xb[n*3+2] - xb[mi*3+2];
        #pragma unroll
        for (int j = 0; j < 3; ++j) {
            const float tv = fmaf(rx, d1w[0*3+j], fmaf(ry, d1w[1*3+j], fmaf(rz, d1w[2*3+j], d1b[j])));
            t3[(size_t)g*3 + j] = tv;
            s[j] += tv;
            sq[j] = fmaf(tv, tv, sq[j]);
        }
    }

    __shared__ float red[4][6];
    const int lane = t & 63, wv = t >> 6;
    #pragma unroll
    for (int j = 0; j < 3; ++j) {
        const float rs  = waveReduceAdd(s[j]);
        const float rsq = waveReduceAdd(sq[j]);
        if (lane == 0) { red[wv][j] = rs; red[wv][3+j] = rsq; }
    }
    __syncthreads();
    if (t < 6) {
        const float v = red[0][t] + red[1][t] + red[2][t] + red[3][t];
        atomicAdd(&stats[t < 3 ? ST_BND_SUM + t : ST_BND_SQ + (t-3)], v);
    }
}

// ---------------- finalize bn_d ----------------
__global__ void finalize_bnd(const float* __restrict__ stats,
                             const float* __restrict__ g, const float* __restrict__ b,
                             float* __restrict__ consts)
{
    const int t = threadIdx.x;
    if (t < 3) {
        const float m = stats[ST_BND_SUM + t] * MINVF;
        const float v = stats[ST_BND_SQ + t] * MINVF - m * m;
        const float s = g[t] / sqrtf(v + EPSF);
        consts[CO_BND_S + t] = s;
        consts[CO_BND_B + t] = b[t] - m * s;
    }
}

// ---------------- K5: g_bn1 stats ----------------
__global__ __launch_bounds__(256, 2) void bn1_stats_kernel(
    const float* __restrict__ qproj, const float* __restrict__ kproj,
    const float* __restrict__ t3, const int* __restrict__ idx,
    const float* __restrict__ consts,
    const float* __restrict__ d2w, const float* __restrict__ d2b,
    float* __restrict__ stats)
{
    const int b   = blockIdx.x >> 8;
    const int pt0 = (blockIdx.x & 255) * 16;
    const int t = threadIdx.x;

    __shared__ float a3[768];
    __shared__ int idxs[256];

    const float bs[3]  = {consts[CO_BND_S+0], consts[CO_BND_S+1], consts[CO_BND_S+2]};
    const float bsh[3] = {consts[CO_BND_B+0], consts[CO_BND_B+1], consts[CO_BND_B+2]};
    const float* t3b = t3 + (size_t)(b * NN + pt0) * KK * 3;
    #pragma unroll
    for (int q = 0; q < 3; ++q) {
        const int f = t + q * 256;
        const int j = f % 3;
        a3[f] = fmaxf(fmaf(t3b[f], bs[j], bsh[j]), 0.f);
    }
    idxs[t] = idx[(size_t)(b * NN + pt0) * KK + t];
    __syncthreads();

    const int c = t;
    const float d20 = d2w[c], d21 = d2w[CC + c], d22 = d2w[2*CC + c], d2bc = d2b[c];
    float s = 0.f, sq = 0.f;
    for (int p = 0; p < 16; ++p) {
        const float qv = qproj[(size_t)(b * NN + pt0 + p) * CC + c];
        #pragma unroll
        for (int k = 0; k < 16; ++k) {
            const int mi = idxs[p*16 + k];
            const float kv = kproj[((size_t)b * NN + mi) * CC + c];
            const int f = (p*16 + k) * 3;
            const float pe = fmaf(a3[f], d20, fmaf(a3[f+1], d21, fmaf(a3[f+2], d22, d2bc)));
            const float h = qv - kv + pe;
            s += h; sq = fmaf(h, h, sq);
        }
    }
    atomicAdd(&stats[ST_G1_SUM + c], s);
    atomicAdd(&stats[ST_G1_SQ + c], sq);
}

// ---------------- finalize g_bn ----------------
__global__ void finalize_g(const float* __restrict__ ssum, const float* __restrict__ ssq,
                           const float* __restrict__ g, const float* __restrict__ b,
                           float* __restrict__ os, float* __restrict__ ob)
{
    const int c = threadIdx.x;
    const float m = ssum[c] * MINVF;
    const float v = ssq[c] * MINVF - m * m;
    const float s = g[c] / sqrtf(v + EPSF);
    os[c] = s;
    ob[c] = b[c] - m * s;
}

// ---------------- prep: transpose 5 weight matrices to bf16 image layout ----------------
__global__ __launch_bounds__(256) void prep_weights(
    const float* __restrict__ wq, const float* __restrict__ wk,
    const float* __restrict__ wv, const float* __restrict__ g1w,
    const float* __restrict__ g2w, u16* __restrict__ img_all)
{
    const int s = blockIdx.x;
    const int mat = blockIdx.y;
    const float* W = mat == 0 ? wq : mat == 1 ? wk : mat == 2 ? wv : mat == 3 ? g1w : g2w;
    u16* img = img_all + (size_t)mat * IMG_TOTAL + (size_t)s * IMG_PER_KSTEP;
    const int n = threadIdx.x;
    #pragma unroll
    for (int i = 0; i < 32; ++i) {
        img[n*40 + i] = f2bf(W[(size_t)(s*32 + i) * AA + n]);
    }
}

// ---------------- K7': stage3 MFMA ----------------
__global__ __launch_bounds__(256, 2) void stage3_mfma(
    const float* __restrict__ qproj, const float* __restrict__ kproj,
    const float* __restrict__ t3, const int* __restrict__ idx,
    const float* __restrict__ consts, float* __restrict__ stats,
    const float* __restrict__ d2w, const float* __restrict__ d2b,
    const u16* __restrict__ g1img, const float* __restrict__ g1b,
    __hip_bfloat16* __restrict__ h2)
{
    const int t = threadIdx.x;
    const int l = t & 63, w = t >> 6;
    const int pt0 = blockIdx.x * WPB;
    const int bI = pt0 >> 12;

    __shared__ __align__(16) u16 A_lds[MROWS * 256];
    __shared__ __align__(16) u16 B_lds[IMG_PER_KSTEP];
    __shared__ int   idxs[MROWS];
    __shared__ float a3s[MROWS * 3];

    if (t < MROWS) idxs[t] = idx[(size_t)pt0 * KK + t];
    if (t < MROWS * 3) {
        const int j = t % 3;
        a3s[t] = fmaxf(fmaf(t3[(size_t)pt0 * 48 + t], consts[CO_BND_S + j], consts[CO_BND_B + j]), 0.f);
    }
    __syncthreads();

    {
        const float d20 = d2w[t], d21 = d2w[CC + t], d22 = d2w[2*CC + t], d2bc = d2b[t];
        const float g1s = consts[CO_G1_S + t], g1sh = consts[CO_G1_B + t];
        float qv[WPB];
        #pragma unroll
        for (int p = 0; p < WPB; ++p) qv[p] = qproj[(size_t)(pt0 + p) * CC + t];
        for (int r = 0; r < MROWS; ++r) {
            const int mi = idxs[r];
            const float kv = kproj[((size_t)bI * NN + mi) * CC + t];
            const float pe = fmaf(a3s[r*3], d20, fmaf(a3s[r*3+1], d21, fmaf(a3s[r*3+2], d22, d2bc)));
            const float h = qv[r >> 4] - kv + pe;
            const float av = fmaxf(fmaf(h, g1s, g1sh), 0.f);
            A_lds[(r * 256 + t) ^ ((r & 7) << 3)] = f2bf(av);
        }
    }
    __syncthreads();

    f32x4 acc[4][4];
    #pragma unroll
    for (int q = 0; q < 4; ++q) {
        const float gb = g1b[(w*4 + q) * 16 + (l & 15)];
        #pragma unroll
        for (int m = 0; m < 4; ++m) acc[m][q] = (f32x4){gb, gb, gb, gb};
    }

    for (int s = 0; s < 8; ++s) {
        #pragma unroll
        for (int i = 0; i < 5; ++i) {
            const int e = t + i * 256;
            *(uint4*)&B_lds[e * 8] = *(const uint4*)&g1img[(size_t)s * IMG_PER_KSTEP + e * 8];
        }
        __syncthreads();
        bf16x8 bf[4];
        #pragma unroll
        for (int q = 0; q < 4; ++q)
            bf[q] = *(const bf16x8*)&B_lds[((w*4 + q) * 16 + (l & 15)) * 40 + (l >> 4) * 8];
        #pragma unroll
        for (int m = 0; m < 4; ++m) {
            const int r = m * 16 + (l & 15);
            const bf16x8 af = *(const bf16x8*)&A_lds[((r * 256 + s * 32 + (l >> 4) * 8)) ^ ((r & 7) << 3)];
            #pragma unroll
            for (int q = 0; q < 4; ++q)
                acc[m][q] = __builtin_amdgcn_mfma_f32_16x16x32_bf16(af, bf[q], acc[m][q], 0, 0, 0);
        }
        __syncthreads();
    }

    #pragma unroll
    for (int q = 0; q < 4; ++q) {
        const int a = (w*4 + q) * 16 + (l & 15);
        float sc = 0.f, sq = 0.f;
        #pragma unroll
        for (int m = 0; m < 4; ++m) {
            #pragma unroll
            for (int j = 0; j < 4; ++j) {
                const float v = acc[m][q][j];
                sc += v; sq = fmaf(v, v, sq);
                h2[((size_t)(pt0 + m) * KK + ((l >> 4) * 4 + j)) * AA + a] = __float2bfloat16(v);
            }
        }
        sc += __shfl_xor(sc, 16); sc += __shfl_xor(sc, 32);
        sq += __shfl_xor(sq, 16); sq += __shfl_xor(sq, 32);
        if (l < 16) {
            atomicAdd(&stats[ST_G2_SUM + a], sc);
            atomicAdd(&stats[ST_G2_SQ + a], sq);
        }
    }
}

// ---------------- K9': stage4 MFMA ----------------
__global__ __launch_bounds__(256, 2) void stage4_mfma(
    const float* __restrict__ vproj,
    const float* __restrict__ t3, const int* __restrict__ idx,
    const float* __restrict__ consts,
    const float* __restrict__ d2w, const float* __restrict__ d2b,
    const u16* __restrict__ g2img, const float* __restrict__ g2b,
    const __hip_bfloat16* __restrict__ h2, float* __restrict__ out)
{
    const int t = threadIdx.x;
    const int l = t & 63, w = t >> 6;
    const int pt0 = blockIdx.x * WPB;
    const int bI = pt0 >> 12;

    __shared__ __align__(16) u16 A_lds[MROWS * 256];
    __shared__ __align__(16) u16 B_lds[IMG_PER_KSTEP];
    __shared__ int   idxs[MROWS];
    __shared__ float a3s[MROWS * 3];

    if (t < MROWS) idxs[t] = idx[(size_t)pt0 * KK + t];
    if (t < MROWS * 3) {
        const int j = t % 3;
        a3s[t] = fmaxf(fmaf(t3[(size_t)pt0 * 48 + t], consts[CO_BND_S + j], consts[CO_BND_B + j]), 0.f);
    }
    __syncthreads();

    {
        const float g2s = consts[CO_G2_S + t], g2sh = consts[CO_G2_B + t];
        for (int r = 0; r < MROWS; ++r) {
            const float hv = __bfloat162float(h2[((size_t)pt0 * KK + r) * AA + t]);
            const float av = fmaxf(fmaf(hv, g2s, g2sh), 0.f);
            A_lds[(r * 256 + t) ^ ((r & 7) << 3)] = f2bf(av);
        }
    }
    __syncthreads();

    f32x4 acc[4][4];
    #pragma unroll
    for (int q = 0; q < 4; ++q) {
        const float gb = g2b[(w*4 + q) * 16 + (l & 15)];
        #pragma unroll
        for (int m = 0; m < 4; ++m) acc[m][q] = (f32x4){gb, gb, gb, gb};
    }

    for (int s = 0; s < 8; ++s) {
        #pragma unroll
        for (int i = 0; i < 5; ++i) {
            const int e = t + i * 256;
            *(uint4*)&B_lds[e * 8] = *(const uint4*)&g2img[(size_t)s * IMG_PER_KSTEP + e * 8];
        }
        __syncthreads();
        bf16x8 bf[4];
        #pragma unroll
        for (int q = 0; q < 4; ++q)
            bf[q] = *(const bf16x8*)&B_lds[((w*4 + q) * 16 + (l & 15)) * 40 + (l >> 4) * 8];
        #pragma unroll
        for (int m = 0; m < 4; ++m) {
            const int r = m * 16 + (l & 15);
            const bf16x8 af = *(const bf16x8*)&A_lds[((r * 256 + s * 32 + (l >> 4) * 8)) ^ ((r & 7) << 3)];
            #pragma unroll
            for (int q = 0; q < 4; ++q)
                acc[m][q] = __builtin_amdgcn_mfma_f32_16x16x32_bf16(af, bf[q], acc[m][q], 0, 0, 0);
        }
        __syncthreads();
    }

    #pragma unroll
    for (int q = 0; q < 4; ++q) {
        const int a = (w*4 + q) * 16 + (l & 15);
        const float dw0 = d2w[a], dw1 = d2w[CC + a], dw2 = d2w[2*CC + a], db = d2b[a];
        #pragma unroll
        for (int m = 0; m < 4; ++m) {
            f32x4 lg = acc[m][q];
            float mx = fmaxf(fmaxf(lg[0], lg[1]), fmaxf(lg[2], lg[3]));
            mx = fmaxf(mx, __shfl_xor(mx, 16));
            mx = fmaxf(mx, __shfl_xor(mx, 32));
            float e[4]; float ss = 0.f;
            #pragma unroll
            for (int j = 0; j < 4; ++j) { e[j] = expf(lg[j] - mx); ss += e[j]; }
            ss += __shfl_xor(ss, 16); ss += __shfl_xor(ss, 32);
            const float inv = 1.0f / ss;
            float part = 0.f;
            #pragma unroll
            for (int j = 0; j < 4; ++j) {
                const int kk = (l >> 4) * 4 + j;
                const int mi = idxs[m * 16 + kk];
                const float vv = vproj[((size_t)bI * NN + mi) * CC + a];
                const float pe = fmaf(a3s[(m*16+kk)*3], dw0,
                                 fmaf(a3s[(m*16+kk)*3+1], dw1,
                                 fmaf(a3s[(m*16+kk)*3+2], dw2, db)));
                part = fmaf(e[j] * inv, vv + pe, part);
            }
            part += __shfl_xor(part, 16); part += __shfl_xor(part, 32);
            if (l < 16) out[(size_t)(pt0 + m) * CC + a] = part;
        }
    }
}

// ---------------- fallback fp32 kernels (ws too small) ----------------
__global__ __launch_bounds__(256, 2) void stage3_fp32(
    const float* __restrict__ qproj, const float* __restrict__ kproj,
    const float* __restrict__ t3, const int* __restrict__ idx,
    const float* __restrict__ consts, float* __restrict__ stats,
    const float* __restrict__ d2w, const float* __restrict__ d2b,
    const float* __restrict__ g1w, const float* __restrict__ g1b)
{
    const size_t pt = blockIdx.x;
    const int b = (int)(pt >> 12);
    const int t = threadIdx.x;
    __shared__ float a3[48];
    __shared__ int idxs[16];
    __shared__ __align__(16) float hr[16][256];
    if (t < 48) {
        const int j = t % 3;
        a3[t] = fmaxf(fmaf(t3[pt*48 + t], consts[CO_BND_S + j], consts[CO_BND_B + j]), 0.f);
    }
    if (t < 16) idxs[t] = idx[pt*16 + t];
    __syncthreads();
    {
        const float d20 = d2w[t], d21 = d2w[CC + t], d22 = d2w[2*CC + t], d2bc = d2b[t];
        const float g1s = consts[CO_G1_S + t], g1sh = consts[CO_G1_B + t];
        const float qv = qproj[pt * CC + t];
        #pragma unroll
        for (int k = 0; k < 16; ++k) {
            const int mi = idxs[k];
            const float kv = kproj[((size_t)b * NN + mi) * CC + t];
            const float pe = fmaf(a3[k*3], d20, fmaf(a3[k*3+1], d21, fmaf(a3[k*3+2], d22, d2bc)));
            hr[k][t] = fmaxf(fmaf(qv - kv + pe, g1s, g1sh), 0.f);
        }
    }
    __syncthreads();
    float acc[16];
    const float gb = g1b[t];
    #pragma unroll
    for (int k = 0; k < 16; ++k) acc[k] = gb;
    #pragma unroll 4
    for (int c4 = 0; c4 < 64; ++c4) {
        const float* wp = g1w + (size_t)(c4*4) * AA + t;
        const float w0 = wp[0], w1 = wp[AA], w2 = wp[2*AA], w3 = wp[3*AA];
        #pragma unroll
        for (int k = 0; k < 16; ++k) {
            const float4 hv = *(const float4*)&hr[k][c4*4];
            acc[k] = fmaf(hv.x, w0, fmaf(hv.y, w1, fmaf(hv.z, w2, fmaf(hv.w, w3, acc[k]))));
        }
    }
    float s = 0.f, sq = 0.f;
    #pragma unroll
    for (int k = 0; k < 16; ++k) { s += acc[k]; sq = fmaf(acc[k], acc[k], sq); }
    atomicAdd(&stats[ST_G2_SUM + t], s);
    atomicAdd(&stats[ST_G2_SQ + t], sq);
}

__global__ __launch_bounds__(256, 2) void stage4_fp32(
    const float* __restrict__ qproj, const float* __restrict__ kproj,
    const float* __restrict__ vproj,
    const float* __restrict__ t3, const int* __restrict__ idx,
    const float* __restrict__ consts,
    const float* __restrict__ d2w, const float* __restrict__ d2b,
    const float* __restrict__ g1w, const float* __restrict__ g1b,
    const float* __restrict__ g2w, const float* __restrict__ g2b,
    float* __restrict__ out)
{
    const size_t pt = blockIdx.x;
    const int b = (int)(pt >> 12);
    const int t = threadIdx.x;
    __shared__ float a3[48];
    __shared__ int idxs[16];
    __shared__ __align__(16) float r2[16][256];
    if (t < 48) {
        const int j = t % 3;
        a3[t] = fmaxf(fmaf(t3[pt*48 + t], consts[CO_BND_S + j], consts[CO_BND_B + j]), 0.f);
    }
    if (t < 16) idxs[t] = idx[pt*16 + t];
    __syncthreads();
    const float g2s = consts[CO_G2_S + t], g2sh = consts[CO_G2_B + t];
    {
        __shared__ __align__(16) float hr[16][256];
        {
            const float d20 = d2w[t], d21 = d2w[CC + t], d22 = d2w[2*CC + t], d2bc = d2b[t];
            const float g1s = consts[CO_G1_S + t], g1sh = consts[CO_G1_B + t];
            const float qv = qproj[pt * CC + t];
            #pragma unroll
            for (int k = 0; k < 16; ++k) {
                const int mi = idxs[k];
                const float kv = kproj[((size_t)b * NN + mi) * CC + t];
                const float pe = fmaf(a3[k*3], d20, fmaf(a3[k*3+1], d21, fmaf(a3[k*3+2], d22, d2bc)));
                hr[k][t] = fmaxf(fmaf(qv - kv + pe, g1s, g1sh), 0.f);
            }
        }
        __syncthreads();
        float acc[16];
        const float gb = g1b[t];
        #pragma unroll
        for (int k = 0; k < 16; ++k) acc[k] = gb;
        #pragma unroll 4
        for (int c4 = 0; c4 < 64; ++c4) {
            const float* wp = g1w + (size_t)(c4*4) * AA + t;
            const float w0 = wp[0], w1 = wp[AA], w2 = wp[2*AA], w3 = wp[3*AA];
            #pragma unroll
            for (int k = 0; k < 16; ++k) {
                const float4 hv = *(const float4*)&hr[k][c4*4];
                acc[k] = fmaf(hv.x, w0, fmaf(hv.y, w1, fmaf(hv.z, w2, fmaf(hv.w, w3, acc[k]))));
            }
        }
        __syncthreads();
        #pragma unroll
        for (int k = 0; k < 16; ++k) r2[k][t] = fmaxf(fmaf(acc[k], g2s, g2sh), 0.f);
        __syncthreads();
    }
    float lg[16];
    const float gb2 = g2b[t];
    #pragma unroll
    for (int k = 0; k < 16; ++k) lg[k] = gb2;
    #pragma unroll 4
    for (int c4 = 0; c4 < 64; ++c4) {
        const float* wp = g2w + (size_t)(c4*4) * AA + t;
        const float w0 = wp[0], w1 = wp[AA], w2 = wp[2*AA], w3 = wp[3*AA];
        #pragma unroll
        for (int k = 0; k < 16; ++k) {
            const float4 hv = *(const float4*)&r2[k][c4*4];
            lg[k] = fmaf(hv.x, w0, fmaf(hv.y, w1, fmaf(hv.z, w2, fmaf(hv.w, w3, lg[k]))));
        }
    }
    float mx = lg[0];
    #pragma unroll
    for (int k = 1; k < 16; ++k) mx = fmaxf(mx, lg[k]);
    float sum = 0.f;
    #pragma unroll
    for (int k = 0; k < 16; ++k) { lg[k] = expf(lg[k] - mx); sum += lg[k]; }
    const float inv = 1.0f / sum;
    const float d20 = d2w[t], d21 = d2w[CC + t], d22 = d2w[2*CC + t], d2bc = d2b[t];
    float o = 0.f;
    #pragma unroll
    for (int k = 0; k < 16; ++k) {
        const int mi = idxs[k];
        const float vv = vproj[((size_t)b * NN + mi) * CC + t];
        const float pe = fmaf(a3[k*3], d20, fmaf(a3[k*3+1], d21, fmaf(a3[k*3+2], d22, d2bc)));
        o = fmaf(vv + pe, lg[k] * inv, o);
    }
    out[pt * CC + t] = o;
}

// ---------------- host ----------------
extern "C" void kernel_launch(void* const* d_in, const int* in_sizes, int n_in,
                              void* d_out, int out_size, void* d_ws, size_t ws_size,
                              hipStream_t stream)
{
    const float* xyz   = (const float*)d_in[0];
    const float* feat  = (const float*)d_in[1];
    const float* wq    = (const float*)d_in[2];
    const float* bq    = (const float*)d_in[3];
    const float* wk    = (const float*)d_in[4];
    const float* bk    = (const float*)d_in[5];
    const float* wv    = (const float*)d_in[6];
    const float* bv    = (const float*)d_in[7];
    const float* d1w   = (const float*)d_in[8];
    const float* d1b   = (const float*)d_in[9];
    const float* bndg  = (const float*)d_in[10];
    const float* bndb  = (const float*)d_in[11];
    const float* d2w   = (const float*)d_in[12];
    const float* d2b   = (const float*)d_in[13];
    const float* g1g   = (const float*)d_in[14];
    const float* g1bb  = (const float*)d_in[15];
    const float* g1w   = (const float*)d_in[16];
    const float* g1b   = (const float*)d_in[17];
    const float* g2g   = (const float*)d_in[18];
    const float* g2bb  = (const float*)d_in[19];
    const float* g2w   = (const float*)d_in[20];
    const float* g2b   = (const float*)d_in[21];
    float* out = (float*)d_out;

    // workspace layout
    float* qproj = (float*)d_ws;
    float* kproj = qproj + (size_t)NPTS * CC;
    float* vproj = kproj + (size_t)NPTS * CC;
    float* t3    = vproj + (size_t)NPTS * CC;
    float* stats = t3 + (size_t)BNKTOT * 3;
    float* consts = stats + 2048;
    int*   idxb  = (int*)(consts + 2048);
    u16*   wimg  = (u16*)(idxb + BNKTOT);          // 5 matrices: wq,wk,wv,g1w,g2w
    u16*   g1img = wimg + (size_t)3 * IMG_TOTAL;
    u16*   g2img = wimg + (size_t)4 * IMG_TOTAL;
    __hip_bfloat16* h2 = (__hip_bfloat16*)(wimg + (size_t)5 * IMG_TOTAL);
    const size_t need_store = (size_t)((char*)h2 - (char*)d_ws) + (size_t)BNKTOT * AA * 2;
    const bool store = ws_size >= need_store;

    hipMemsetAsync(stats, 0, 2048 * sizeof(float), stream);

    if (store) {
        prep_weights<<<dim3(8, 5), 256, 0, stream>>>(wq, wk, wv, g1w, g2w, wimg);
        qkv_mfma<<<dim3(NPTS / 64, 3), 256, 0, stream>>>(feat, wimg, bq, bk, bv,
                                                         qproj, kproj, vproj);
    } else {
        dim3 gq(NPTS / 64, 3);
        qkv_kernel<<<gq, 256, 0, stream>>>(feat, wq, bq, wk, bk, wv, bv, qproj, kproj, vproj);
    }

    knn_kernel<<<NPTS / 4, 256, 0, stream>>>(xyz, idxb);

    fc_delta_kernel<<<BNKTOT / 1024, 256, 0, stream>>>(xyz, idxb, d1w, d1b, t3, stats);

    finalize_bnd<<<1, 64, 0, stream>>>(stats, bndg, bndb, consts);

    bn1_stats_kernel<<<1024, 256, 0, stream>>>(qproj, kproj, t3, idxb, consts, d2w, d2b, stats);

    finalize_g<<<1, 256, 0, stream>>>(stats + ST_G1_SUM, stats + ST_G1_SQ, g1g, g1bb,
                                      consts + CO_G1_S, consts + CO_G1_B);

    if (store)
        stage3_mfma<<<NPTS / WPB, 256, 0, stream>>>(qproj, kproj, t3, idxb, consts, stats,
                                                    d2w, d2b, g1img, g1b, h2);
    else
        stage3_fp32<<<NPTS, 256, 0, stream>>>(qproj, kproj, t3, idxb, consts, stats,
                                              d2w, d2b, g1w, g1b);

    finalize_g<<<1, 256, 0, stream>>>(stats + ST_G2_SUM, stats + ST_G2_SQ, g2g, g2bb,
                                      consts + CO_G2_S, consts + CO_G2_B);

    if (store)
        stage4_mfma<<<NPTS / WPB, 256, 0, stream>>>(vproj, t3, idxb, consts,
                                                    d2w, d2b, g2img, g2b, h2, out);
    else
        stage4_fp32<<<NPTS, 256, 0, stream>>>(qproj, kproj, vproj, t3, idxb, consts,
                                              d2w, d2b, g1w, g1b, g2w, g2b, out);
}

// Round 13
// 593.647 us; speedup vs baseline: 11.2909x; 1.1486x over previous
//
#include <hip/hip_runtime.h>
#include <hip/hip_bf16.h>
#include <math.h>

#define BB 4
#define NN 4096
#define CC 256
#define KK 16
#define AA 256
#define NPTS (BB*NN)            // 16384
#define BNKTOT (NPTS*KK)        // 262144
#define EPSF 1e-5f
#define MINVF (1.0f/262144.0f)

#define WPB 4                    // points per MFMA block (stage3/4)
#define MROWS (WPB*KK)           // 64 rows
// fragment-major bf16 weight image: [kstep][n][h] 8-elem chunks, no padding.
// A wave's 4 B-frag loads (q fixed) tile a contiguous 1KB region -> fully
// coalesced global read, L2-resident (shared by all blocks). No B_lds needed.
#define IMG_PER_KSTEP (256*32)   // u16 per kstep
#define IMG_TOTAL (8*IMG_PER_KSTEP)

// stats / consts float offsets
#define ST_BND_SUM 0
#define ST_BND_SQ  8
#define ST_G1_SUM  16
#define ST_G1_SQ   272
#define ST_G2_SUM  528
#define ST_G2_SQ   784
#define CO_BND_S   0
#define CO_BND_B   4
#define CO_G1_S    16
#define CO_G1_B    272
#define CO_G2_S    528
#define CO_G2_B    784

typedef unsigned short u16;
typedef __attribute__((ext_vector_type(8))) short bf16x8;
typedef __attribute__((ext_vector_type(4))) float f32x4;

__device__ inline u16 f2bf(float x) {           // round-to-nearest-even bf16
    unsigned u = __float_as_uint(x);
    unsigned r = (u + 0x7FFFu + ((u >> 16) & 1u)) >> 16;
    return (u16)r;
}

__device__ inline float waveReduceAdd(float v) {
    #pragma unroll
    for (int o = 32; o > 0; o >>= 1) v += __shfl_down(v, o);
    return v;
}

__device__ inline bool lexlt(float d1, int i1, float d2, int i2) {
    return (d1 < d2) || (d1 == d2 && i1 < i2);
}

// ---------------- K1': qkv MFMA — {q,k,v} = feat @ W + b ----------------
// B-frags read directly from the L2-resident fragment-major image; K-loop has
// no barriers (A_lds is write-once). Round-12 lesson: B_lds staging cost
// 2 barriers/kstep + 20KB LDS + bank conflicts for data all blocks share.
__global__ __launch_bounds__(256, 2) void qkv_mfma(
    const float* __restrict__ feat, const u16* __restrict__ wimg_all,
    const float* __restrict__ bq, const float* __restrict__ bk, const float* __restrict__ bv,
    float* __restrict__ oq, float* __restrict__ ok, float* __restrict__ ov)
{
    const int t = threadIdx.x;
    const int l = t & 63, w = t >> 6;
    const int p0 = blockIdx.x * 64;
    const u16* img = wimg_all + (size_t)blockIdx.y * IMG_TOTAL;
    const float* bias = blockIdx.y == 0 ? bq : (blockIdx.y == 1 ? bk : bv);
    float* out = blockIdx.y == 0 ? oq : (blockIdx.y == 1 ? ok : ov);

    __shared__ __align__(16) u16 A_lds[64 * 256];        // 32KB

    for (int r = 0; r < 64; ++r)
        A_lds[(r * 256 + t) ^ ((r & 7) << 3)] = f2bf(feat[(size_t)(p0 + r) * CC + t]);
    __syncthreads();

    f32x4 acc[4][4];
    #pragma unroll
    for (int q = 0; q < 4; ++q) {
        const float gb = bias[(w*4 + q) * 16 + (l & 15)];
        #pragma unroll
        for (int m = 0; m < 4; ++m) acc[m][q] = (f32x4){gb, gb, gb, gb};
    }

    for (int s = 0; s < 8; ++s) {
        bf16x8 bf[4];
        #pragma unroll
        for (int q = 0; q < 4; ++q) {
            const int nq = (w*4 + q) * 16 + (l & 15);
            bf[q] = *(const bf16x8*)&img[(size_t)s * IMG_PER_KSTEP + ((nq*4 + (l >> 4)) * 8)];
        }
        #pragma unroll
        for (int m = 0; m < 4; ++m) {
            const int r = m * 16 + (l & 15);
            const bf16x8 af = *(const bf16x8*)&A_lds[((r * 256 + s * 32 + (l >> 4) * 8)) ^ ((r & 7) << 3)];
            #pragma unroll
            for (int q = 0; q < 4; ++q)
                acc[m][q] = __builtin_amdgcn_mfma_f32_16x16x32_bf16(af, bf[q], acc[m][q], 0, 0, 0);
        }
    }

    #pragma unroll
    for (int q = 0; q < 4; ++q) {
        const int a = (w*4 + q) * 16 + (l & 15);
        #pragma unroll
        for (int m = 0; m < 4; ++m)
            #pragma unroll
            for (int j = 0; j < 4; ++j)
                out[(size_t)(p0 + m*16 + (l >> 4)*4 + j) * CC + a] = acc[m][q][j];
    }
}

// ---------------- K1 fallback: fp32 qkv ----------------
__global__ __launch_bounds__(256, 2) void qkv_kernel(
    const float* __restrict__ feat,
    const float* __restrict__ wq, const float* __restrict__ bq,
    const float* __restrict__ wk, const float* __restrict__ bk,
    const float* __restrict__ wv, const float* __restrict__ bv,
    float* __restrict__ oq, float* __restrict__ ok, float* __restrict__ ov)
{
    const float* W; const float* bias; float* out;
    if (blockIdx.y == 0)      { W = wq; bias = bq; out = oq; }
    else if (blockIdx.y == 1) { W = wk; bias = bk; out = ok; }
    else                      { W = wv; bias = bv; out = ov; }

    const int p0 = blockIdx.x * 64;
    const int t  = threadIdx.x;
    __shared__ __align__(16) float fs[64][65];

    float acc[64];
    #pragma unroll
    for (int p = 0; p < 64; ++p) acc[p] = 0.f;

    for (int it = 0; it < 4; ++it) {
        const int tp = t >> 2;
        #pragma unroll
        for (int q = 0; q < 4; ++q) {
            const int ch = (t & 3) + q * 4;
            float4 v = *(const float4*)&feat[(size_t)(p0 + tp) * CC + it * 64 + ch * 4];
            fs[tp][ch*4+0] = v.x; fs[tp][ch*4+1] = v.y; fs[tp][ch*4+2] = v.z; fs[tp][ch*4+3] = v.w;
        }
        __syncthreads();
        #pragma unroll 4
        for (int i = 0; i < 64; ++i) {
            const float w = W[(size_t)(it * 64 + i) * CC + t];
            #pragma unroll
            for (int p = 0; p < 64; ++p) acc[p] = fmaf(fs[p][i], w, acc[p]);
        }
        __syncthreads();
    }
    const float bv_ = bias[t];
    #pragma unroll
    for (int p = 0; p < 64; ++p) out[(size_t)(p0 + p) * CC + t] = acc[p] + bv_;
}

// ---------------- K2: KNN top-16 — wave-select with shared threshold ----------------
#define KNN_BUFCAP 48
__global__ __launch_bounds__(256) void knn_kernel(
    const float* __restrict__ xyz, int* __restrict__ idxout)
{
    const int t = threadIdx.x;
    const int l = t & 63;
    const int w = t >> 6;
    const int g = blockIdx.x * 4 + w;          // global query id
    const int b = g >> 12;
    const int n = g & 4095;
    const float* xb = xyz + (size_t)b * NN * 3;

    const float qx = xb[n*3+0], qy = xb[n*3+1], qz = xb[n*3+2];
    const float sqn = qx*qx + qy*qy + qz*qz;

    __shared__ float4 tile[512];
    __shared__ float bufd[4][KNN_BUFCAP];
    __shared__ int   bufi[4][KNN_BUFCAP];

    const float INF = 3.0e38f;
    float ld = INF; int li = 0x7fffffff;
    float kd = INF; int ki = 0x7fffffff;
    int cnt = 0;

    for (int t0 = 0; t0 < NN; t0 += 512) {
        #pragma unroll
        for (int r = 0; r < 2; ++r) {
            const int j = t + r * 256;
            const float x = xb[(t0 + j)*3 + 0];
            const float y = xb[(t0 + j)*3 + 1];
            const float z = xb[(t0 + j)*3 + 2];
            tile[j] = make_float4(x, y, z, x*x + y*y + z*z);
        }
        __syncthreads();
        for (int j0 = 0; j0 < 512; j0 += 64) {
            const float4 p = tile[j0 + l];
            const float d = sqn + p.w - 2.0f * (qx*p.x + qy*p.y + qz*p.z);
            const int  ci = t0 + j0 + l;
            bool pass = lexlt(d, ci, kd, ki);
            while (__any(pass)) {
                const unsigned long long m = __ballot(pass);
                const int rank  = (int)__popcll(m & ((1ull << l) - 1ull));
                const int total = (int)__popcll(m);
                const int space = KNN_BUFCAP - cnt;
                if (pass && rank < space) {
                    bufd[w][cnt + rank] = d;
                    bufi[w][cnt + rank] = ci;
                    pass = false;
                }
                cnt += total < space ? total : space;
                if (__any(pass)) {
                    float sd; int si;
                    if (l < 16)            { sd = ld; si = li; }
                    else if (l - 16 < cnt) { sd = bufd[w][l-16]; si = bufi[w][l-16]; }
                    else                   { sd = INF; si = 0x7fffffff; }
                    #pragma unroll
                    for (int k = 2; k <= 64; k <<= 1) {
                        #pragma unroll
                        for (int jj = k >> 1; jj > 0; jj >>= 1) {
                            const float od = __shfl_xor(sd, jj);
                            const int   oi = __shfl_xor(si, jj);
                            const bool keepMin = (((l & jj) == 0) == ((l & k) == 0));
                            const bool oSm = lexlt(od, oi, sd, si);
                            if (keepMin ? oSm : !oSm) { sd = od; si = oi; }
                        }
                    }
                    ld = (l < 16) ? sd : INF;
                    li = (l < 16) ? si : 0x7fffffff;
                    kd = __shfl(sd, 15);
                    ki = __shfl(si, 15);
                    cnt = 0;
                    pass = pass && lexlt(d, ci, kd, ki);
                }
            }
        }
        __syncthreads();
    }

    if (cnt > 0) {   // final flush
        float sd; int si;
        if (l < 16)            { sd = ld; si = li; }
        else if (l - 16 < cnt) { sd = bufd[w][l-16]; si = bufi[w][l-16]; }
        else                   { sd = INF; si = 0x7fffffff; }
        #pragma unroll
        for (int k = 2; k <= 64; k <<= 1) {
            #pragma unroll
            for (int jj = k >> 1; jj > 0; jj >>= 1) {
                const float od = __shfl_xor(sd, jj);
                const int   oi = __shfl_xor(si, jj);
                const bool keepMin = (((l & jj) == 0) == ((l & k) == 0));
                const bool oSm = lexlt(od, oi, sd, si);
                if (keepMin ? oSm : !oSm) { sd = od; si = oi; }
            }
        }
        li = si;
    }
    if (l < 16) idxout[((size_t)b * NN + n) * KK + l] = li;
}

// ---------------- K3: t = rel@d1_w + d1_b, bn_d stats ----------------
__global__ __launch_bounds__(256) void fc_delta_kernel(
    const float* __restrict__ xyz, const int* __restrict__ idx,
    const float* __restrict__ d1w, const float* __restrict__ d1b,
    float* __restrict__ t3, float* __restrict__ stats)
{
    const int t = threadIdx.x;
    float s[3] = {0.f, 0.f, 0.f}, sq[3] = {0.f, 0.f, 0.f};

    #pragma unroll
    for (int it = 0; it < 4; ++it) {
        const int g = blockIdx.x * 1024 + it * 256 + t;
        const int b = g >> 16;
        const int n = (g & 65535) >> 4;
        const int mi = idx[g];
        const float* xb = xyz + (size_t)b * NN * 3;
        const float rx = xb[n*3+0] - xb[mi*3+0];
        const float ry = xb[n*3+1] - xb[mi*3+1];
        const float rz = xb[n*3+2] - xb[mi*3+2];
        #pragma unroll
        for (int j = 0; j < 3; ++j) {
            const float tv = fmaf(rx, d1w[0*3+j], fmaf(ry, d1w[1*3+j], fmaf(rz, d1w[2*3+j], d1b[j])));
            t3[(size_t)g*3 + j] = tv;
            s[j] += tv;
            sq[j] = fmaf(tv, tv, sq[j]);
        }
    }

    __shared__ float red[4][6];
    const int lane = t & 63, wv = t >> 6;
    #pragma unroll
    for (int j = 0; j < 3; ++j) {
        const float rs  = waveReduceAdd(s[j]);
        const float rsq = waveReduceAdd(sq[j]);
        if (lane == 0) { red[wv][j] = rs; red[wv][3+j] = rsq; }
    }
    __syncthreads();
    if (t < 6) {
        const float v = red[0][t] + red[1][t] + red[2][t] + red[3][t];
        atomicAdd(&stats[t < 3 ? ST_BND_SUM + t : ST_BND_SQ + (t-3)], v);
    }
}

// ---------------- finalize bn_d ----------------
__global__ void finalize_bnd(const float* __restrict__ stats,
                             const float* __restrict__ g, const float* __restrict__ b,
                             float* __restrict__ consts)
{
    const int t = threadIdx.x;
    if (t < 3) {
        const float m = stats[ST_BND_SUM + t] * MINVF;
        const float v = stats[ST_BND_SQ + t] * MINVF - m * m;
        const float s = g[t] / sqrtf(v + EPSF);
        consts[CO_BND_S + t] = s;
        consts[CO_BND_B + t] = b[t] - m * s;
    }
}

// ---------------- K5: g_bn1 stats ----------------
__global__ __launch_bounds__(256, 2) void bn1_stats_kernel(
    const float* __restrict__ qproj, const float* __restrict__ kproj,
    const float* __restrict__ t3, const int* __restrict__ idx,
    const float* __restrict__ consts,
    const float* __restrict__ d2w, const float* __restrict__ d2b,
    float* __restrict__ stats)
{
    const int b   = blockIdx.x >> 8;
    const int pt0 = (blockIdx.x & 255) * 16;
    const int t = threadIdx.x;

    __shared__ float a3[768];
    __shared__ int idxs[256];

    const float bs[3]  = {consts[CO_BND_S+0], consts[CO_BND_S+1], consts[CO_BND_S+2]};
    const float bsh[3] = {consts[CO_BND_B+0], consts[CO_BND_B+1], consts[CO_BND_B+2]};
    const float* t3b = t3 + (size_t)(b * NN + pt0) * KK * 3;
    #pragma unroll
    for (int q = 0; q < 3; ++q) {
        const int f = t + q * 256;
        const int j = f % 3;
        a3[f] = fmaxf(fmaf(t3b[f], bs[j], bsh[j]), 0.f);
    }
    idxs[t] = idx[(size_t)(b * NN + pt0) * KK + t];
    __syncthreads();

    const int c = t;
    const float d20 = d2w[c], d21 = d2w[CC + c], d22 = d2w[2*CC + c], d2bc = d2b[c];
    float s = 0.f, sq = 0.f;
    for (int p = 0; p < 16; ++p) {
        const float qv = qproj[(size_t)(b * NN + pt0 + p) * CC + c];
        #pragma unroll
        for (int k = 0; k < 16; ++k) {
            const int mi = idxs[p*16 + k];
            const float kv = kproj[((size_t)b * NN + mi) * CC + c];
            const int f = (p*16 + k) * 3;
            const float pe = fmaf(a3[f], d20, fmaf(a3[f+1], d21, fmaf(a3[f+2], d22, d2bc)));
            const float h = qv - kv + pe;
            s += h; sq = fmaf(h, h, sq);
        }
    }
    atomicAdd(&stats[ST_G1_SUM + c], s);
    atomicAdd(&stats[ST_G1_SQ + c], sq);
}

// ---------------- finalize g_bn ----------------
__global__ void finalize_g(const float* __restrict__ ssum, const float* __restrict__ ssq,
                           const float* __restrict__ g, const float* __restrict__ b,
                           float* __restrict__ os, float* __restrict__ ob)
{
    const int c = threadIdx.x;
    const float m = ssum[c] * MINVF;
    const float v = ssq[c] * MINVF - m * m;
    const float s = g[c] / sqrtf(v + EPSF);
    os[c] = s;
    ob[c] = b[c] - m * s;
}

// ---------------- prep: transpose 5 weight matrices to fragment-major bf16 ----------------
// img[mat][s][(n*4+h)*8+j] = bf16(W[s*32 + h*8 + j][n]) — one wave's 4 b-frag
// loads for fixed q tile a contiguous 1KB region (perfect coalescing).
__global__ __launch_bounds__(256) void prep_weights(
    const float* __restrict__ wq, const float* __restrict__ wk,
    const float* __restrict__ wv, const float* __restrict__ g1w,
    const float* __restrict__ g2w, u16* __restrict__ img_all)
{
    const int s = blockIdx.x;
    const int mat = blockIdx.y;
    const float* W = mat == 0 ? wq : mat == 1 ? wk : mat == 2 ? wv : mat == 3 ? g1w : g2w;
    u16* img = img_all + (size_t)mat * IMG_TOTAL + (size_t)s * IMG_PER_KSTEP;
    const int n = threadIdx.x;
    #pragma unroll
    for (int h = 0; h < 4; ++h)
        #pragma unroll
        for (int j = 0; j < 8; ++j)
            img[(n*4 + h)*8 + j] = f2bf(W[(size_t)(s*32 + h*8 + j) * AA + n]);
}

// ---------------- K7': stage3 MFMA ----------------
// B-frags from global (L2-resident), no B_lds, no barriers in the K-loop.
// LDS 33.5KB -> 4 blocks/CU (was 54KB -> 2, occupancy 21%, round-12 profile).
__global__ __launch_bounds__(256, 2) void stage3_mfma(
    const float* __restrict__ qproj, const float* __restrict__ kproj,
    const float* __restrict__ t3, const int* __restrict__ idx,
    const float* __restrict__ consts, float* __restrict__ stats,
    const float* __restrict__ d2w, const float* __restrict__ d2b,
    const u16* __restrict__ g1img, const float* __restrict__ g1b,
    __hip_bfloat16* __restrict__ h2)
{
    const int t = threadIdx.x;
    const int l = t & 63, w = t >> 6;
    const int pt0 = blockIdx.x * WPB;
    const int bI = pt0 >> 12;

    __shared__ __align__(16) u16 A_lds[MROWS * 256];
    __shared__ int   idxs[MROWS];
    __shared__ float a3s[MROWS * 3];

    if (t < MROWS) idxs[t] = idx[(size_t)pt0 * KK + t];
    if (t < MROWS * 3) {
        const int j = t % 3;
        a3s[t] = fmaxf(fmaf(t3[(size_t)pt0 * 48 + t], consts[CO_BND_S + j], consts[CO_BND_B + j]), 0.f);
    }
    __syncthreads();

    {
        const float d20 = d2w[t], d21 = d2w[CC + t], d22 = d2w[2*CC + t], d2bc = d2b[t];
        const float g1s = consts[CO_G1_S + t], g1sh = consts[CO_G1_B + t];
        float qv[WPB];
        #pragma unroll
        for (int p = 0; p < WPB; ++p) qv[p] = qproj[(size_t)(pt0 + p) * CC + t];
        for (int r = 0; r < MROWS; ++r) {
            const int mi = idxs[r];
            const float kv = kproj[((size_t)bI * NN + mi) * CC + t];
            const float pe = fmaf(a3s[r*3], d20, fmaf(a3s[r*3+1], d21, fmaf(a3s[r*3+2], d22, d2bc)));
            const float h = qv[r >> 4] - kv + pe;
            const float av = fmaxf(fmaf(h, g1s, g1sh), 0.f);
            A_lds[(r * 256 + t) ^ ((r & 7) << 3)] = f2bf(av);
        }
    }
    __syncthreads();

    f32x4 acc[4][4];
    #pragma unroll
    for (int q = 0; q < 4; ++q) {
        const float gb = g1b[(w*4 + q) * 16 + (l & 15)];
        #pragma unroll
        for (int m = 0; m < 4; ++m) acc[m][q] = (f32x4){gb, gb, gb, gb};
    }

    for (int s = 0; s < 8; ++s) {
        bf16x8 bf[4];
        #pragma unroll
        for (int q = 0; q < 4; ++q) {
            const int nq = (w*4 + q) * 16 + (l & 15);
            bf[q] = *(const bf16x8*)&g1img[(size_t)s * IMG_PER_KSTEP + ((nq*4 + (l >> 4)) * 8)];
        }
        #pragma unroll
        for (int m = 0; m < 4; ++m) {
            const int r = m * 16 + (l & 15);
            const bf16x8 af = *(const bf16x8*)&A_lds[((r * 256 + s * 32 + (l >> 4) * 8)) ^ ((r & 7) << 3)];
            #pragma unroll
            for (int q = 0; q < 4; ++q)
                acc[m][q] = __builtin_amdgcn_mfma_f32_16x16x32_bf16(af, bf[q], acc[m][q], 0, 0, 0);
        }
    }

    #pragma unroll
    for (int q = 0; q < 4; ++q) {
        const int a = (w*4 + q) * 16 + (l & 15);
        float sc = 0.f, sq = 0.f;
        #pragma unroll
        for (int m = 0; m < 4; ++m) {
            #pragma unroll
            for (int j = 0; j < 4; ++j) {
                const float v = acc[m][q][j];
                sc += v; sq = fmaf(v, v, sq);
                h2[((size_t)(pt0 + m) * KK + ((l >> 4) * 4 + j)) * AA + a] = __float2bfloat16(v);
            }
        }
        sc += __shfl_xor(sc, 16); sc += __shfl_xor(sc, 32);
        sq += __shfl_xor(sq, 16); sq += __shfl_xor(sq, 32);
        if (l < 16) {
            atomicAdd(&stats[ST_G2_SUM + a], sc);
            atomicAdd(&stats[ST_G2_SQ + a], sq);
        }
    }
}

// ---------------- K9': stage4 MFMA ----------------
__global__ __launch_bounds__(256, 2) void stage4_mfma(
    const float* __restrict__ vproj,
    const float* __restrict__ t3, const int* __restrict__ idx,
    const float* __restrict__ consts,
    const float* __restrict__ d2w, const float* __restrict__ d2b,
    const u16* __restrict__ g2img, const float* __restrict__ g2b,
    const __hip_bfloat16* __restrict__ h2, float* __restrict__ out)
{
    const int t = threadIdx.x;
    const int l = t & 63, w = t >> 6;
    const int pt0 = blockIdx.x * WPB;
    const int bI = pt0 >> 12;

    __shared__ __align__(16) u16 A_lds[MROWS * 256];
    __shared__ int   idxs[MROWS];
    __shared__ float a3s[MROWS * 3];

    if (t < MROWS) idxs[t] = idx[(size_t)pt0 * KK + t];
    if (t < MROWS * 3) {
        const int j = t % 3;
        a3s[t] = fmaxf(fmaf(t3[(size_t)pt0 * 48 + t], consts[CO_BND_S + j], consts[CO_BND_B + j]), 0.f);
    }
    __syncthreads();

    {
        const float g2s = consts[CO_G2_S + t], g2sh = consts[CO_G2_B + t];
        for (int r = 0; r < MROWS; ++r) {
            const float hv = __bfloat162float(h2[((size_t)pt0 * KK + r) * AA + t]);
            const float av = fmaxf(fmaf(hv, g2s, g2sh), 0.f);
            A_lds[(r * 256 + t) ^ ((r & 7) << 3)] = f2bf(av);
        }
    }
    __syncthreads();

    f32x4 acc[4][4];
    #pragma unroll
    for (int q = 0; q < 4; ++q) {
        const float gb = g2b[(w*4 + q) * 16 + (l & 15)];
        #pragma unroll
        for (int m = 0; m < 4; ++m) acc[m][q] = (f32x4){gb, gb, gb, gb};
    }

    for (int s = 0; s < 8; ++s) {
        bf16x8 bf[4];
        #pragma unroll
        for (int q = 0; q < 4; ++q) {
            const int nq = (w*4 + q) * 16 + (l & 15);
            bf[q] = *(const bf16x8*)&g2img[(size_t)s * IMG_PER_KSTEP + ((nq*4 + (l >> 4)) * 8)];
        }
        #pragma unroll
        for (int m = 0; m < 4; ++m) {
            const int r = m * 16 + (l & 15);
            const bf16x8 af = *(const bf16x8*)&A_lds[((r * 256 + s * 32 + (l >> 4) * 8)) ^ ((r & 7) << 3)];
            #pragma unroll
            for (int q = 0; q < 4; ++q)
                acc[m][q] = __builtin_amdgcn_mfma_f32_16x16x32_bf16(af, bf[q], acc[m][q], 0, 0, 0);
        }
    }

    #pragma unroll
    for (int q = 0; q < 4; ++q) {
        const int a = (w*4 + q) * 16 + (l & 15);
        const float dw0 = d2w[a], dw1 = d2w[CC + a], dw2 = d2w[2*CC + a], db = d2b[a];
        #pragma unroll
        for (int m = 0; m < 4; ++m) {
            f32x4 lg = acc[m][q];
            float mx = fmaxf(fmaxf(lg[0], lg[1]), fmaxf(lg[2], lg[3]));
            mx = fmaxf(mx, __shfl_xor(mx, 16));
            mx = fmaxf(mx, __shfl_xor(mx, 32));
            float e[4]; float ss = 0.f;
            #pragma unroll
            for (int j = 0; j < 4; ++j) { e[j] = expf(lg[j] - mx); ss += e[j]; }
            ss += __shfl_xor(ss, 16); ss += __shfl_xor(ss, 32);
            const float inv = 1.0f / ss;
            float part = 0.f;
            #pragma unroll
            for (int j = 0; j < 4; ++j) {
                const int kk = (l >> 4) * 4 + j;
                const int mi = idxs[m * 16 + kk];
                const float vv = vproj[((size_t)bI * NN + mi) * CC + a];
                const float pe = fmaf(a3s[(m*16+kk)*3], dw0,
                                 fmaf(a3s[(m*16+kk)*3+1], dw1,
                                 fmaf(a3s[(m*16+kk)*3+2], dw2, db)));
                part = fmaf(e[j] * inv, vv + pe, part);
            }
            part += __shfl_xor(part, 16); part += __shfl_xor(part, 32);
            if (l < 16) out[(size_t)(pt0 + m) * CC + a] = part;
        }
    }
}

// ---------------- fallback fp32 kernels (ws too small) ----------------
__global__ __launch_bounds__(256, 2) void stage3_fp32(
    const float* __restrict__ qproj, const float* __restrict__ kproj,
    const float* __restrict__ t3, const int* __restrict__ idx,
    const float* __restrict__ consts, float* __restrict__ stats,
    const float* __restrict__ d2w, const float* __restrict__ d2b,
    const float* __restrict__ g1w, const float* __restrict__ g1b)
{
    const size_t pt = blockIdx.x;
    const int b = (int)(pt >> 12);
    const int t = threadIdx.x;
    __shared__ float a3[48];
    __shared__ int idxs[16];
    __shared__ __align__(16) float hr[16][256];
    if (t < 48) {
        const int j = t % 3;
        a3[t] = fmaxf(fmaf(t3[pt*48 + t], consts[CO_BND_S + j], consts[CO_BND_B + j]), 0.f);
    }
    if (t < 16) idxs[t] = idx[pt*16 + t];
    __syncthreads();
    {
        const float d20 = d2w[t], d21 = d2w[CC + t], d22 = d2w[2*CC + t], d2bc = d2b[t];
        const float g1s = consts[CO_G1_S + t], g1sh = consts[CO_G1_B + t];
        const float qv = qproj[pt * CC + t];
        #pragma unroll
        for (int k = 0; k < 16; ++k) {
            const int mi = idxs[k];
            const float kv = kproj[((size_t)b * NN + mi) * CC + t];
            const float pe = fmaf(a3[k*3], d20, fmaf(a3[k*3+1], d21, fmaf(a3[k*3+2], d22, d2bc)));
            hr[k][t] = fmaxf(fmaf(qv - kv + pe, g1s, g1sh), 0.f);
        }
    }
    __syncthreads();
    float acc[16];
    const float gb = g1b[t];
    #pragma unroll
    for (int k = 0; k < 16; ++k) acc[k] = gb;
    #pragma unroll 4
    for (int c4 = 0; c4 < 64; ++c4) {
        const float* wp = g1w + (size_t)(c4*4) * AA + t;
        const float w0 = wp[0], w1 = wp[AA], w2 = wp[2*AA], w3 = wp[3*AA];
        #pragma unroll
        for (int k = 0; k < 16; ++k) {
            const float4 hv = *(const float4*)&hr[k][c4*4];
            acc[k] = fmaf(hv.x, w0, fmaf(hv.y, w1, fmaf(hv.z, w2, fmaf(hv.w, w3, acc[k]))));
        }
    }
    float s = 0.f, sq = 0.f;
    #pragma unroll
    for (int k = 0; k < 16; ++k) { s += acc[k]; sq = fmaf(acc[k], acc[k], sq); }
    atomicAdd(&stats[ST_G2_SUM + t], s);
    atomicAdd(&stats[ST_G2_SQ + t], sq);
}

__global__ __launch_bounds__(256, 2) void stage4_fp32(
    const float* __restrict__ qproj, const float* __restrict__ kproj,
    const float* __restrict__ vproj,
    const float* __restrict__ t3, const int* __restrict__ idx,
    const float* __restrict__ consts,
    const float* __restrict__ d2w, const float* __restrict__ d2b,
    const float* __restrict__ g1w, const float* __restrict__ g1b,
    const float* __restrict__ g2w, const float* __restrict__ g2b,
    float* __restrict__ out)
{
    const size_t pt = blockIdx.x;
    const int b = (int)(pt >> 12);
    const int t = threadIdx.x;
    __shared__ float a3[48];
    __shared__ int idxs[16];
    __shared__ __align__(16) float r2[16][256];
    if (t < 48) {
        const int j = t % 3;
        a3[t] = fmaxf(fmaf(t3[pt*48 + t], consts[CO_BND_S + j], consts[CO_BND_B + j]), 0.f);
    }
    if (t < 16) idxs[t] = idx[pt*16 + t];
    __syncthreads();
    const float g2s = consts[CO_G2_S + t], g2sh = consts[CO_G2_B + t];
    {
        __shared__ __align__(16) float hr[16][256];
        {
            const float d20 = d2w[t], d21 = d2w[CC + t], d22 = d2w[2*CC + t], d2bc = d2b[t];
            const float g1s = consts[CO_G1_S + t], g1sh = consts[CO_G1_B + t];
            const float qv = qproj[pt * CC + t];
            #pragma unroll
            for (int k = 0; k < 16; ++k) {
                const int mi = idxs[k];
                const float kv = kproj[((size_t)b * NN + mi) * CC + t];
                const float pe = fmaf(a3[k*3], d20, fmaf(a3[k*3+1], d21, fmaf(a3[k*3+2], d22, d2bc)));
                hr[k][t] = fmaxf(fmaf(qv - kv + pe, g1s, g1sh), 0.f);
            }
        }
        __syncthreads();
        float acc[16];
        const float gb = g1b[t];
        #pragma unroll
        for (int k = 0; k < 16; ++k) acc[k] = gb;
        #pragma unroll 4
        for (int c4 = 0; c4 < 64; ++c4) {
            const float* wp = g1w + (size_t)(c4*4) * AA + t;
            const float w0 = wp[0], w1 = wp[AA], w2 = wp[2*AA], w3 = wp[3*AA];
            #pragma unroll
            for (int k = 0; k < 16; ++k) {
                const float4 hv = *(const float4*)&hr[k][c4*4];
                acc[k] = fmaf(hv.x, w0, fmaf(hv.y, w1, fmaf(hv.z, w2, fmaf(hv.w, w3, acc[k]))));
            }
        }
        __syncthreads();
        #pragma unroll
        for (int k = 0; k < 16; ++k) r2[k][t] = fmaxf(fmaf(acc[k], g2s, g2sh), 0.f);
        __syncthreads();
    }
    float lg[16];
    const float gb2 = g2b[t];
    #pragma unroll
    for (int k = 0; k < 16; ++k) lg[k] = gb2;
    #pragma unroll 4
    for (int c4 = 0; c4 < 64; ++c4) {
        const float* wp = g2w + (size_t)(c4*4) * AA + t;
        const float w0 = wp[0], w1 = wp[AA], w2 = wp[2*AA], w3 = wp[3*AA];
        #pragma unroll
        for (int k = 0; k < 16; ++k) {
            const float4 hv = *(const float4*)&r2[k][c4*4];
            lg[k] = fmaf(hv.x, w0, fmaf(hv.y, w1, fmaf(hv.z, w2, fmaf(hv.w, w3, lg[k]))));
        }
    }
    float mx = lg[0];
    #pragma unroll
    for (int k = 1; k < 16; ++k) mx = fmaxf(mx, lg[k]);
    float sum = 0.f;
    #pragma unroll
    for (int k = 0; k < 16; ++k) { lg[k] = expf(lg[k] - mx); sum += lg[k]; }
    const float inv = 1.0f / sum;
    const float d20 = d2w[t], d21 = d2w[CC + t], d22 = d2w[2*CC + t], d2bc = d2b[t];
    float o = 0.f;
    #pragma unroll
    for (int k = 0; k < 16; ++k) {
        const int mi = idxs[k];
        const float vv = vproj[((size_t)b * NN + mi) * CC + t];
        const float pe = fmaf(a3[k*3], d20, fmaf(a3[k*3+1], d21, fmaf(a3[k*3+2], d22, d2bc)));
        o = fmaf(vv + pe, lg[k] * inv, o);
    }
    out[pt * CC + t] = o;
}

// ---------------- host ----------------
extern "C" void kernel_launch(void* const* d_in, const int* in_sizes, int n_in,
                              void* d_out, int out_size, void* d_ws, size_t ws_size,
                              hipStream_t stream)
{
    const float* xyz   = (const float*)d_in[0];
    const float* feat  = (const float*)d_in[1];
    const float* wq    = (const float*)d_in[2];
    const float* bq    = (const float*)d_in[3];
    const float* wk    = (const float*)d_in[4];
    const float* bk    = (const float*)d_in[5];
    const float* wv    = (const float*)d_in[6];
    const float* bv    = (const float*)d_in[7];
    const float* d1w   = (const float*)d_in[8];
    const float* d1b   = (const float*)d_in[9];
    const float* bndg  = (const float*)d_in[10];
    const float* bndb  = (const float*)d_in[11];
    const float* d2w   = (const float*)d_in[12];
    const float* d2b   = (const float*)d_in[13];
    const float* g1g   = (const float*)d_in[14];
    const float* g1bb  = (const float*)d_in[15];
    const float* g1w   = (const float*)d_in[16];
    const float* g1b   = (const float*)d_in[17];
    const float* g2g   = (const float*)d_in[18];
    const float* g2bb  = (const float*)d_in[19];
    const float* g2w   = (const float*)d_in[20];
    const float* g2b   = (const float*)d_in[21];
    float* out = (float*)d_out;

    // workspace layout
    float* qproj = (float*)d_ws;
    float* kproj = qproj + (size_t)NPTS * CC;
    float* vproj = kproj + (size_t)NPTS * CC;
    float* t3    = vproj + (size_t)NPTS * CC;
    float* stats = t3 + (size_t)BNKTOT * 3;
    float* consts = stats + 2048;
    int*   idxb  = (int*)(consts + 2048);
    u16*   wimg  = (u16*)(idxb + BNKTOT);          // 5 matrices: wq,wk,wv,g1w,g2w
    u16*   g1img = wimg + (size_t)3 * IMG_TOTAL;
    u16*   g2img = wimg + (size_t)4 * IMG_TOTAL;
    __hip_bfloat16* h2 = (__hip_bfloat16*)(wimg + (size_t)5 * IMG_TOTAL);
    const size_t need_store = (size_t)((char*)h2 - (char*)d_ws) + (size_t)BNKTOT * AA * 2;
    const bool store = ws_size >= need_store;

    hipMemsetAsync(stats, 0, 2048 * sizeof(float), stream);

    if (store) {
        prep_weights<<<dim3(8, 5), 256, 0, stream>>>(wq, wk, wv, g1w, g2w, wimg);
        qkv_mfma<<<dim3(NPTS / 64, 3), 256, 0, stream>>>(feat, wimg, bq, bk, bv,
                                                         qproj, kproj, vproj);
    } else {
        dim3 gq(NPTS / 64, 3);
        qkv_kernel<<<gq, 256, 0, stream>>>(feat, wq, bq, wk, bk, wv, bv, qproj, kproj, vproj);
    }

    knn_kernel<<<NPTS / 4, 256, 0, stream>>>(xyz, idxb);

    fc_delta_kernel<<<BNKTOT / 1024, 256, 0, stream>>>(xyz, idxb, d1w, d1b, t3, stats);

    finalize_bnd<<<1, 64, 0, stream>>>(stats, bndg, bndb, consts);

    bn1_stats_kernel<<<1024, 256, 0, stream>>>(qproj, kproj, t3, idxb, consts, d2w, d2b, stats);

    finalize_g<<<1, 256, 0, stream>>>(stats + ST_G1_SUM, stats + ST_G1_SQ, g1g, g1bb,
                                      consts + CO_G1_S, consts + CO_G1_B);

    if (store)
        stage3_mfma<<<NPTS / WPB, 256, 0, stream>>>(qproj, kproj, t3, idxb, consts, stats,
                                                    d2w, d2b, g1img, g1b, h2);
    else
        stage3_fp32<<<NPTS, 256, 0, stream>>>(qproj, kproj, t3, idxb, consts, stats,
                                              d2w, d2b, g1w, g1b);

    finalize_g<<<1, 256, 0, stream>>>(stats + ST_G2_SUM, stats + ST_G2_SQ, g2g, g2bb,
                                      consts + CO_G2_S, consts + CO_G2_B);

    if (store)
        stage4_mfma<<<NPTS / WPB, 256, 0, stream>>>(vproj, t3, idxb, consts,
                                                    d2w, d2b, g2img, g2b, h2, out);
    else
        stage4_fp32<<<NPTS, 256, 0, stream>>>(qproj, kproj, vproj, t3, idxb, consts,
                                              d2w, d2b, g1w, g1b, g2w, g2b, out);
}